// Round 1
// baseline (1205.982 us; speedup 1.0000x reference)
//
#include <hip/hip_runtime.h>
#include <math.h>

#define NCLS 80
#define PRE 1000
#define MAXD 100
#define NBUCK 4096
#define CAND 2048
#define THR_SCORE 0.05f

// ---------------- Kernel 1: per-class threshold + top-1000 (sorted) ----------------
// One block per class. Histogram over score buckets -> cutoff bucket containing the
// 1000th largest -> collect candidates -> bitonic sort 2048 64-bit keys (desc).
// Key = (float_bits(score) << 32) | ~index : descending key order == jax top_k order
// (desc value, ascending index on ties).
__global__ __launch_bounds__(256) void select_topk(
    const float* __restrict__ cls, int A,
    float* __restrict__ topscore, unsigned* __restrict__ topidx)
{
  const int c = blockIdx.x;
  const int t = threadIdx.x;
  __shared__ unsigned hist[NBUCK];
  __shared__ unsigned long long cand[CAND];
  __shared__ unsigned chunk[256];
  __shared__ int s_cb;
  __shared__ int s_cnt;

  for (int i = t; i < NBUCK; i += 256) hist[i] = 0u;
  if (t == 0) s_cnt = 0;
  __syncthreads();

  for (int a = t; a < A; a += 256) {
    float s = cls[(size_t)a * NCLS + c];
    if (s > THR_SCORE) {
      int b = (int)(s * (float)NBUCK);
      b = b < 0 ? 0 : (b > NBUCK - 1 ? NBUCK - 1 : b);
      atomicAdd(&hist[b], 1u);
    }
  }
  __syncthreads();

  { // per-thread chunk sums (16 buckets each)
    unsigned cs = 0;
    for (int i = 0; i < NBUCK / 256; i++) cs += hist[t * (NBUCK / 256) + i];
    chunk[t] = cs;
  }
  __syncthreads();

  if (t == 0) {
    unsigned acc = 0;
    int cb = 0;
    int ch;
    for (ch = 255; ch >= 0; ch--) {
      if (acc + chunk[ch] >= (unsigned)PRE) break;
      acc += chunk[ch];
    }
    if (ch < 0) {
      cb = 0; // fewer than PRE candidates total: take all
    } else {
      const int bpc = NBUCK / 256;
      int b = ch * bpc + bpc - 1;
      for (; b >= ch * bpc; b--) { acc += hist[b]; if (acc >= (unsigned)PRE) break; }
      if (b < ch * bpc) b = ch * bpc;
      cb = b;
      // overflow guard (pathological: >2048 candidates incl. cutoff bucket)
      while (acc > (unsigned)CAND && cb < NBUCK - 1) { acc -= hist[cb]; cb++; }
    }
    s_cb = cb;
  }
  __syncthreads();
  const int cb = s_cb;

  // collect candidates
  for (int a = t; a < A; a += 256) {
    float s = cls[(size_t)a * NCLS + c];
    if (s > THR_SCORE) {
      int b = (int)(s * (float)NBUCK);
      b = b < 0 ? 0 : (b > NBUCK - 1 ? NBUCK - 1 : b);
      if (b >= cb) {
        int p = atomicAdd(&s_cnt, 1);
        if (p < CAND) {
          cand[p] = ((unsigned long long)__float_as_uint(s) << 32)
                  | (unsigned long long)(~(unsigned)a);
        }
      }
    }
  }
  __syncthreads();
  int n = s_cnt < CAND ? s_cnt : CAND;
  for (int i = n + t; i < CAND; i += 256) cand[i] = 0ull;
  __syncthreads();

  // bitonic sort, descending
  for (int k = 2; k <= CAND; k <<= 1) {
    for (int j = k >> 1; j > 0; j >>= 1) {
      for (int i = t; i < CAND; i += 256) {
        int ixj = i ^ j;
        if (ixj > i) {
          unsigned long long va = cand[i], vb = cand[ixj];
          bool desc = ((i & k) == 0);
          bool sw = desc ? (va < vb) : (va > vb);
          if (sw) { cand[i] = vb; cand[ixj] = va; }
        }
      }
      __syncthreads();
    }
  }

  for (int k = t; k < PRE; k += 256) {
    unsigned long long key = cand[k];
    float sc; unsigned idx;
    if (key != 0ull) {
      sc = __uint_as_float((unsigned)(key >> 32));
      idx = ~((unsigned)(key & 0xFFFFFFFFull));
    } else {
      sc = -INFINITY; idx = 0u;
    }
    topscore[c * PRE + k] = sc;
    topidx[c * PRE + k] = idx;
  }
}

// ---------------- Kernel 2: decode + exact NMS scan + top-100 output ----------------
// One block per class. Decode 1000 boxes into LDS, build 1000x1024-bit suppression
// matrix (iou>0.5 && j>i) via 64-lane ballots, then a single wave performs the exact
// sequential scan with bitwise ANDs (16 u64 keep words). Output = first 100 kept.
__global__ __launch_bounds__(256) void nms_out(
    const float* __restrict__ anch, const float* __restrict__ reg,
    const float* __restrict__ dist,
    const float* __restrict__ topscore, const unsigned* __restrict__ topidx,
    const int* __restrict__ img_h_p, const int* __restrict__ img_w_p,
    float* __restrict__ out_s, float* __restrict__ out_id,
    float* __restrict__ out_b, float* __restrict__ out_d)
{
#pragma clang fp contract(off)
  const int c = blockIdx.x;
  const int t = threadIdx.x;
  __shared__ float bx[PRE], by[PRE], bX[PRE], bY[PRE], bar[PRE], ssc[PRE];
  __shared__ unsigned long long supm[PRE * 16];
  __shared__ unsigned long long keepw[16];
  __shared__ unsigned wpre[17];

  const float W = (float)img_w_p[0];
  const float H = (float)img_h_p[0];

  // decode gathered boxes (numpy op order, no FMA contraction, exp in double)
  for (int k = t; k < PRE; k += 256) {
    float sc = topscore[c * PRE + k];
    unsigned idx = topidx[c * PRE + k];
    ssc[k] = sc;
    float a0 = anch[(size_t)idx * 4 + 0], a1 = anch[(size_t)idx * 4 + 1];
    float a2 = anch[(size_t)idx * 4 + 2], a3 = anch[(size_t)idx * 4 + 3];
    float r0 = reg[(size_t)idx * 4 + 0], r1 = reg[(size_t)idx * 4 + 1];
    float r2 = reg[(size_t)idx * 4 + 2], r3 = reg[(size_t)idx * 4 + 3];
    float w = a2 - a0, h = a3 - a1;
    float cx = a0 + 0.5f * w, cy = a1 + 0.5f * h;
    float dx = r0 * 0.1f, dy = r1 * 0.1f, dw = r2 * 0.2f, dh = r3 * 0.2f;
    float pcx = cx + dx * w, pcy = cy + dy * h;
    float pw = (float)exp((double)dw) * w;
    float ph = (float)exp((double)dh) * h;
    float x1 = fminf(fmaxf(pcx - 0.5f * pw, 0.0f), W);
    float y1 = fminf(fmaxf(pcy - 0.5f * ph, 0.0f), H);
    float x2 = fminf(fmaxf(pcx + 0.5f * pw, 0.0f), W);
    float y2 = fminf(fmaxf(pcy + 0.5f * ph, 0.0f), H);
    bx[k] = x1; by[k] = y1; bX[k] = x2; bY[k] = y2;
    bar[k] = (x2 - x1) * (y2 - y1);
  }
  __syncthreads();

  // suppression bit matrix: bit j of row i set iff (j>i && iou(i,j)>0.5)
  const int wave = t >> 6, lane = t & 63;
  for (int i = wave; i < PRE; i += 4) {
    float x1 = bx[i], y1 = by[i], X1 = bX[i], Y1 = bY[i], ai = bar[i];
    for (int g = 0; g < 16; g++) {
      int j = g * 64 + lane;
      bool s = false;
      if (j > i && j < PRE) {
        float ltx = fmaxf(x1, bx[j]);
        float lty = fmaxf(y1, by[j]);
        float rbx = fminf(X1, bX[j]);
        float rby = fminf(Y1, bY[j]);
        float ww = fmaxf(rbx - ltx, 0.0f);
        float hh = fmaxf(rby - lty, 0.0f);
        float inter = ww * hh;
        float iou = inter / ((ai + bar[j]) - inter + 1e-8f);
        s = iou > 0.5f;
      }
      unsigned long long m = __ballot(s);
      if (lane == 0) supm[i * 16 + g] = m;
    }
  }
  __syncthreads();

  // exact sequential scan, one wave; lanes 0..15 hold the 16 keep words
  if (t < 64) {
    unsigned long long kw = 0ull;
    if (t < 16) {
      for (int b = 0; b < 64; b++) {
        int k = t * 64 + b;
        if (k < PRE && ssc[k] != -INFINITY) kw |= (1ull << b);
      }
    }
    for (int i = 0; i < PRE; i++) {
      unsigned long long ow = __shfl(kw, i >> 6);
      if ((ow >> (i & 63)) & 1ull) {
        if (t < 16) kw &= ~supm[i * 16 + t];
      }
    }
    if (t < 16) keepw[t] = kw;
  }
  __syncthreads();

  if (t == 0) {
    unsigned acc = 0;
    for (int w = 0; w < 16; w++) { wpre[w] = acc; acc += (unsigned)__popcll(keepw[w]); }
    wpre[16] = acc;
  }
  __syncthreads();
  const unsigned total = wpre[16];

  // kept entries in order = final top-100 (array already sorted desc)
  for (int k = t; k < PRE; k += 256) {
    int w = k >> 6, b = k & 63;
    unsigned long long kw = keepw[w];
    if ((kw >> b) & 1ull) {
      unsigned rank = wpre[w] + (unsigned)__popcll(kw & ((1ull << b) - 1ull));
      if (rank < MAXD) {
        int slot = c * MAXD + (int)rank;
        out_s[slot] = ssc[k];
        out_id[slot] = (float)c;
        out_b[slot * 4 + 0] = bx[k];
        out_b[slot * 4 + 1] = by[k];
        out_b[slot * 4 + 2] = bX[k];
        out_b[slot * 4 + 3] = bY[k];
        unsigned idx = topidx[c * PRE + k];
        out_d[slot] = dist[idx];
      }
    }
  }
  unsigned tk = total < MAXD ? total : MAXD;
  for (int r = (int)tk + t; r < MAXD; r += 256) {
    int slot = c * MAXD + r;
    out_s[slot] = 0.0f;
    out_id[slot] = -1.0f;
    out_b[slot * 4 + 0] = 0.0f; out_b[slot * 4 + 1] = 0.0f;
    out_b[slot * 4 + 2] = 0.0f; out_b[slot * 4 + 3] = 0.0f;
    out_d[slot] = 0.0f;
  }
}

extern "C" void kernel_launch(void* const* d_in, const int* in_sizes, int n_in,
                              void* d_out, int out_size, void* d_ws, size_t ws_size,
                              hipStream_t stream) {
  const float* cls  = (const float*)d_in[0];   // (1, A, 80)
  const float* reg  = (const float*)d_in[1];   // (1, A, 4)
  const float* dist = (const float*)d_in[2];   // (1, A, 1)
  const float* anch = (const float*)d_in[3];   // (1, A, 4)
  const int* img_h  = (const int*)d_in[4];
  const int* img_w  = (const int*)d_in[5];
  const int A = in_sizes[3] / 4;

  float* topscore = (float*)d_ws;                       // 80*1000 f32
  unsigned* topidx = (unsigned*)((char*)d_ws + NCLS * PRE * sizeof(float));

  float* o = (float*)d_out;
  float* out_s  = o;                      // 8000
  float* out_id = o + NCLS * MAXD;        // 8000
  float* out_b  = o + 2 * NCLS * MAXD;    // 32000
  float* out_d  = o + 6 * NCLS * MAXD;    // 8000

  select_topk<<<NCLS, 256, 0, stream>>>(cls, A, topscore, topidx);
  nms_out<<<NCLS, 256, 0, stream>>>(anch, reg, dist, topscore, topidx,
                                    img_h, img_w, out_s, out_id, out_b, out_d);
}

// Round 2
// 528.534 us; speedup vs baseline: 2.2818x; 2.2818x over previous
//
#include <hip/hip_runtime.h>
#include <math.h>

#define NCLS 80
#define PRE 1000
#define MAXD 100
#define THR_SCORE 0.05f

// ---- fast path config ----
#define NB 128                 // buckets per class
#define BINS (NCLS * NB)       // 10240
#define K1B 256                // histogram blocks
#define SUBS 16                // sub-lists per class (atomic spreading)
#define SUBCAP 512             // depth per sub-list
#define CSORT 4096             // sort capacity per class

typedef unsigned long long u64;

// =====================================================================
// FAST PATH
// =====================================================================

// K1: coalesced float4 pass over cls, per-block LDS hist (80x128), u16 partials out.
__global__ __launch_bounds__(256) void k1_hist(
    const float4* __restrict__ cls4, int total4, unsigned short* __restrict__ part)
{
  __shared__ unsigned h[BINS];
  const int t = threadIdx.x;
  for (int i = t; i < BINS; i += 256) h[i] = 0u;
  __syncthreads();
  const int stride = gridDim.x * 256;
  for (int q = blockIdx.x * 256 + t; q < total4; q += stride) {
    float4 v = cls4[q];
    int c0 = 4 * (q % 20);  // (4q) % 80
    float s;
    int b;
    s = v.x; if (s > THR_SCORE) { b = (int)(s * (float)NB); b = b < 0 ? 0 : (b > NB - 1 ? NB - 1 : b); atomicAdd(&h[(c0 + 0) * NB + b], 1u); }
    s = v.y; if (s > THR_SCORE) { b = (int)(s * (float)NB); b = b < 0 ? 0 : (b > NB - 1 ? NB - 1 : b); atomicAdd(&h[(c0 + 1) * NB + b], 1u); }
    s = v.z; if (s > THR_SCORE) { b = (int)(s * (float)NB); b = b < 0 ? 0 : (b > NB - 1 ? NB - 1 : b); atomicAdd(&h[(c0 + 2) * NB + b], 1u); }
    s = v.w; if (s > THR_SCORE) { b = (int)(s * (float)NB); b = b < 0 ? 0 : (b > NB - 1 ? NB - 1 : b); atomicAdd(&h[(c0 + 3) * NB + b], 1u); }
  }
  __syncthreads();
  unsigned short* p = part + (size_t)blockIdx.x * BINS;
  for (int i = t; i < BINS; i += 256) p[i] = (unsigned short)h[i];
}

// K2: reduce partial hists; each block covers 256 bins = exactly 2 classes ->
// compute per-class cutoff bucket in-block. Also zeroes the push counters.
__global__ __launch_bounds__(256) void k2_cutoff(
    const unsigned short* __restrict__ part, int* __restrict__ cb,
    unsigned* __restrict__ ccnt)
{
  const int t = threadIdx.x;
  const int bin = blockIdx.x * 256 + t;  // 40 blocks x 256 = 10240
  unsigned acc = 0;
  for (int p = 0; p < K1B; p++) acc += part[(size_t)p * BINS + bin];
  __shared__ unsigned lh[256];
  lh[t] = acc;
  if (bin < NCLS * SUBS) ccnt[bin] = 0u;
  __syncthreads();
  if ((t & 127) == 0) {
    const int base = t & 128;               // 0 or 128
    const int c = blockIdx.x * 2 + (t >> 7);
    unsigned a = 0;
    int cbv = 0;
    for (int b = NB - 1; b >= 0; b--) {
      a += lh[base + b];
      if (a >= (unsigned)PRE) { cbv = b; break; }
    }
    while (a > (unsigned)CSORT && cbv < NB - 1) { a -= lh[base + cbv]; cbv++; }
    cb[c] = cbv;
  }
}

// K3: coalesced float4 pass; push candidates above per-class cutoff into
// per-(class,sub) lists. key = score_bits<<32 | ~anchor (desc order == jax top_k).
__global__ __launch_bounds__(256) void k3_collect(
    const float4* __restrict__ cls4, int total4, const int* __restrict__ cb,
    unsigned* __restrict__ ccnt, u64* __restrict__ cand)
{
  __shared__ int scb[NCLS];
  const int t = threadIdx.x;
  if (t < NCLS) scb[t] = cb[t];
  __syncthreads();
  const int sub = blockIdx.x & (SUBS - 1);
  const int stride = gridDim.x * 256;
  for (int q = blockIdx.x * 256 + t; q < total4; q += stride) {
    float4 v = cls4[q];
    int c0 = 4 * (q % 20);
    unsigned a = (unsigned)(q / 20);
    float sv[4] = {v.x, v.y, v.z, v.w};
#pragma unroll
    for (int e = 0; e < 4; e++) {
      float s = sv[e];
      if (s > THR_SCORE) {
        int b = (int)(s * (float)NB);
        b = b < 0 ? 0 : (b > NB - 1 ? NB - 1 : b);
        int c = c0 + e;
        if (b >= scb[c]) {
          unsigned p = atomicAdd(&ccnt[c * SUBS + sub], 1u);
          if (p < SUBCAP)
            cand[((size_t)(c * SUBS + sub)) * SUBCAP + p] =
                ((u64)__float_as_uint(s) << 32) | (u64)(~a);
        }
      }
    }
  }
}

// K4: per-class concat sub-lists -> bitonic sort 4096 desc -> top-1000 + decode.
__global__ __launch_bounds__(512) void k4_sort_decode(
    const unsigned* __restrict__ ccnt, const u64* __restrict__ cand,
    const float* __restrict__ anch, const float* __restrict__ reg,
    const int* __restrict__ img_h_p, const int* __restrict__ img_w_p,
    float* __restrict__ ts, unsigned* __restrict__ ti, float* __restrict__ b5)
{
#pragma clang fp contract(off)
  const int c = blockIdx.x;
  const int t = threadIdx.x;
  __shared__ u64 L[CSORT];
  __shared__ unsigned base[SUBS];
  if (t == 0) {
    unsigned acc = 0;
    for (int s = 0; s < SUBS; s++) {
      unsigned n = ccnt[c * SUBS + s];
      if (n > SUBCAP) n = SUBCAP;
      base[s] = acc;
      acc += n;
    }
  }
  for (int i = t; i < CSORT; i += 512) L[i] = 0ull;
  __syncthreads();
  for (int s = 0; s < SUBS; s++) {
    unsigned n = ccnt[c * SUBS + s];
    if (n > SUBCAP) n = SUBCAP;
    unsigned bs = base[s];
    for (unsigned i = t; i < n; i += 512) {
      unsigned d = bs + i;
      if (d < CSORT) L[d] = cand[((size_t)(c * SUBS + s)) * SUBCAP + i];
    }
  }
  __syncthreads();
  for (int k = 2; k <= CSORT; k <<= 1) {
    for (int j = k >> 1; j > 0; j >>= 1) {
      for (int i = t; i < CSORT; i += 512) {
        int ixj = i ^ j;
        if (ixj > i) {
          u64 va = L[i], vb = L[ixj];
          bool desc = ((i & k) == 0);
          if (desc ? (va < vb) : (va > vb)) { L[i] = vb; L[ixj] = va; }
        }
      }
      __syncthreads();
    }
  }
  const float W = (float)img_w_p[0];
  const float H = (float)img_h_p[0];
  float* BX = b5;
  float* BY = b5 + NCLS * PRE;
  float* BX2 = b5 + 2 * NCLS * PRE;
  float* BY2 = b5 + 3 * NCLS * PRE;
  float* BAR = b5 + 4 * NCLS * PRE;
  const float4* a4 = (const float4*)anch;
  const float4* r4 = (const float4*)reg;
  for (int k = t; k < PRE; k += 512) {
    u64 key = L[k];
    float sc;
    unsigned idx;
    if (key != 0ull) {
      sc = __uint_as_float((unsigned)(key >> 32));
      idx = ~((unsigned)(key & 0xFFFFFFFFull));
    } else {
      sc = -INFINITY;
      idx = 0u;
    }
    ts[c * PRE + k] = sc;
    ti[c * PRE + k] = idx;
    float4 av = a4[idx];
    float4 rv = r4[idx];
    float w = av.z - av.x, h = av.w - av.y;
    float cx = av.x + 0.5f * w, cy = av.y + 0.5f * h;
    float dx = rv.x * 0.1f, dy = rv.y * 0.1f, dw = rv.z * 0.2f, dh = rv.w * 0.2f;
    float pcx = cx + dx * w, pcy = cy + dy * h;
    float pw = (float)exp((double)dw) * w;
    float ph = (float)exp((double)dh) * h;
    float x1 = fminf(fmaxf(pcx - 0.5f * pw, 0.0f), W);
    float y1 = fminf(fmaxf(pcy - 0.5f * ph, 0.0f), H);
    float x2 = fminf(fmaxf(pcx + 0.5f * pw, 0.0f), W);
    float y2 = fminf(fmaxf(pcy + 0.5f * ph, 0.0f), H);
    BX[c * PRE + k] = x1;
    BY[c * PRE + k] = y1;
    BX2[c * PRE + k] = x2;
    BY2[c * PRE + k] = y2;
    BAR[c * PRE + k] = (x2 - x1) * (y2 - y1);
  }
}

// K5: per-class NMS (supm bit-matrix skipping below-diagonal groups; pipelined
// serial scan) + top-100 output.
__global__ __launch_bounds__(512) void k5_nms(
    const float* __restrict__ ts, const unsigned* __restrict__ ti,
    const float* __restrict__ b5, const float* __restrict__ dist,
    float* __restrict__ out_s, float* __restrict__ out_id,
    float* __restrict__ out_b, float* __restrict__ out_d)
{
#pragma clang fp contract(off)
  const int c = blockIdx.x;
  const int t = threadIdx.x;
  __shared__ float bx[PRE], by[PRE], bX[PRE], bY[PRE], bar[PRE], ssc[PRE];
  __shared__ u64 supm[PRE * 16];
  __shared__ u64 keepw[16];
  __shared__ unsigned wpre[17];
  const float* BX = b5;
  const float* BY = b5 + NCLS * PRE;
  const float* BX2 = b5 + 2 * NCLS * PRE;
  const float* BY2 = b5 + 3 * NCLS * PRE;
  const float* BAR = b5 + 4 * NCLS * PRE;
  for (int k = t; k < PRE; k += 512) {
    bx[k] = BX[c * PRE + k];
    by[k] = BY[c * PRE + k];
    bX[k] = BX2[c * PRE + k];
    bY[k] = BY2[c * PRE + k];
    bar[k] = BAR[c * PRE + k];
    ssc[k] = ts[c * PRE + k];
  }
  for (int i = t; i < PRE * 16; i += 512) supm[i] = 0ull;
  __syncthreads();

  const int wave = t >> 6, lane = t & 63;
  for (int i = wave; i < PRE; i += 8) {
    float x1 = bx[i], y1 = by[i], X1 = bX[i], Y1 = bY[i], ai = bar[i];
    for (int g = (i >> 6); g < 16; g++) {
      int j = g * 64 + lane;
      bool s = false;
      if (j > i && j < PRE) {
        float ltx = fmaxf(x1, bx[j]);
        float lty = fmaxf(y1, by[j]);
        float rbx = fminf(X1, bX[j]);
        float rby = fminf(Y1, bY[j]);
        float ww = fmaxf(rbx - ltx, 0.0f);
        float hh = fmaxf(rby - lty, 0.0f);
        float inter = ww * hh;
        float iou = inter / ((ai + bar[j]) - inter + 1e-8f);
        s = iou > 0.5f;
      }
      u64 m = __ballot(s);
      if (lane == 0) supm[i * 16 + g] = m;
    }
  }
  __syncthreads();

  if (t < 64) {
    u64 kw = 0ull;
    if (t < 16) {
      for (int b = 0; b < 64; b++) {
        int k = t * 64 + b;
        if (k < PRE && ssc[k] != -INFINITY) kw |= (1ull << b);
      }
    }
    u64 nxt = (t < 16) ? supm[t] : 0ull;
    for (int i = 0; i < PRE; i++) {
      u64 cur = nxt;
      if (t < 16 && i + 1 < PRE) nxt = supm[(i + 1) * 16 + t];
      u64 ow = __shfl(kw, i >> 6);
      if ((ow >> (i & 63)) & 1ull) {
        if (t < 16) kw &= ~cur;
      }
    }
    if (t < 16) keepw[t] = kw;
  }
  __syncthreads();

  if (t == 0) {
    unsigned acc = 0;
    for (int w = 0; w < 16; w++) { wpre[w] = acc; acc += (unsigned)__popcll(keepw[w]); }
    wpre[16] = acc;
  }
  __syncthreads();
  const unsigned total = wpre[16];

  for (int k = t; k < PRE; k += 512) {
    int w = k >> 6, b = k & 63;
    u64 kw = keepw[w];
    if ((kw >> b) & 1ull) {
      unsigned rank = wpre[w] + (unsigned)__popcll(kw & ((1ull << b) - 1ull));
      if (rank < MAXD) {
        int slot = c * MAXD + (int)rank;
        out_s[slot] = ssc[k];
        out_id[slot] = (float)c;
        out_b[slot * 4 + 0] = bx[k];
        out_b[slot * 4 + 1] = by[k];
        out_b[slot * 4 + 2] = bX[k];
        out_b[slot * 4 + 3] = bY[k];
        out_d[slot] = dist[ti[c * PRE + k]];
      }
    }
  }
  unsigned tk = total < MAXD ? total : MAXD;
  for (int r = (int)tk + t; r < MAXD; r += 512) {
    int slot = c * MAXD + r;
    out_s[slot] = 0.0f;
    out_id[slot] = -1.0f;
    out_b[slot * 4 + 0] = 0.0f;
    out_b[slot * 4 + 1] = 0.0f;
    out_b[slot * 4 + 2] = 0.0f;
    out_b[slot * 4 + 3] = 0.0f;
    out_d[slot] = 0.0f;
  }
}

// =====================================================================
// FALLBACK PATH (round-1, proven correct; used only if ws is too small)
// =====================================================================
#define NBUCK 4096
#define CANDF 2048

__global__ __launch_bounds__(256) void select_topk(
    const float* __restrict__ cls, int A,
    float* __restrict__ topscore, unsigned* __restrict__ topidx)
{
  const int c = blockIdx.x;
  const int t = threadIdx.x;
  __shared__ unsigned hist[NBUCK];
  __shared__ u64 cand[CANDF];
  __shared__ unsigned chunk[256];
  __shared__ int s_cb;
  __shared__ int s_cnt;
  for (int i = t; i < NBUCK; i += 256) hist[i] = 0u;
  if (t == 0) s_cnt = 0;
  __syncthreads();
  for (int a = t; a < A; a += 256) {
    float s = cls[(size_t)a * NCLS + c];
    if (s > THR_SCORE) {
      int b = (int)(s * (float)NBUCK);
      b = b < 0 ? 0 : (b > NBUCK - 1 ? NBUCK - 1 : b);
      atomicAdd(&hist[b], 1u);
    }
  }
  __syncthreads();
  {
    unsigned cs = 0;
    for (int i = 0; i < NBUCK / 256; i++) cs += hist[t * (NBUCK / 256) + i];
    chunk[t] = cs;
  }
  __syncthreads();
  if (t == 0) {
    unsigned acc = 0;
    int cb = 0;
    int ch;
    for (ch = 255; ch >= 0; ch--) {
      if (acc + chunk[ch] >= (unsigned)PRE) break;
      acc += chunk[ch];
    }
    if (ch < 0) cb = 0;
    else {
      const int bpc = NBUCK / 256;
      int b = ch * bpc + bpc - 1;
      for (; b >= ch * bpc; b--) { acc += hist[b]; if (acc >= (unsigned)PRE) break; }
      if (b < ch * bpc) b = ch * bpc;
      cb = b;
      while (acc > (unsigned)CANDF && cb < NBUCK - 1) { acc -= hist[cb]; cb++; }
    }
    s_cb = cb;
  }
  __syncthreads();
  const int cb = s_cb;
  for (int a = t; a < A; a += 256) {
    float s = cls[(size_t)a * NCLS + c];
    if (s > THR_SCORE) {
      int b = (int)(s * (float)NBUCK);
      b = b < 0 ? 0 : (b > NBUCK - 1 ? NBUCK - 1 : b);
      if (b >= cb) {
        int p = atomicAdd(&s_cnt, 1);
        if (p < CANDF)
          cand[p] = ((u64)__float_as_uint(s) << 32) | (u64)(~(unsigned)a);
      }
    }
  }
  __syncthreads();
  int n = s_cnt < CANDF ? s_cnt : CANDF;
  for (int i = n + t; i < CANDF; i += 256) cand[i] = 0ull;
  __syncthreads();
  for (int k = 2; k <= CANDF; k <<= 1) {
    for (int j = k >> 1; j > 0; j >>= 1) {
      for (int i = t; i < CANDF; i += 256) {
        int ixj = i ^ j;
        if (ixj > i) {
          u64 va = cand[i], vb = cand[ixj];
          bool desc = ((i & k) == 0);
          if (desc ? (va < vb) : (va > vb)) { cand[i] = vb; cand[ixj] = va; }
        }
      }
      __syncthreads();
    }
  }
  for (int k = t; k < PRE; k += 256) {
    u64 key = cand[k];
    float sc; unsigned idx;
    if (key != 0ull) { sc = __uint_as_float((unsigned)(key >> 32)); idx = ~((unsigned)(key & 0xFFFFFFFFull)); }
    else { sc = -INFINITY; idx = 0u; }
    topscore[c * PRE + k] = sc;
    topidx[c * PRE + k] = idx;
  }
}

__global__ __launch_bounds__(256) void nms_out(
    const float* __restrict__ anch, const float* __restrict__ reg,
    const float* __restrict__ dist,
    const float* __restrict__ topscore, const unsigned* __restrict__ topidx,
    const int* __restrict__ img_h_p, const int* __restrict__ img_w_p,
    float* __restrict__ out_s, float* __restrict__ out_id,
    float* __restrict__ out_b, float* __restrict__ out_d)
{
#pragma clang fp contract(off)
  const int c = blockIdx.x;
  const int t = threadIdx.x;
  __shared__ float bx[PRE], by[PRE], bX[PRE], bY[PRE], bar[PRE], ssc[PRE];
  __shared__ u64 supm[PRE * 16];
  __shared__ u64 keepw[16];
  __shared__ unsigned wpre[17];
  const float W = (float)img_w_p[0];
  const float H = (float)img_h_p[0];
  for (int k = t; k < PRE; k += 256) {
    float sc = topscore[c * PRE + k];
    unsigned idx = topidx[c * PRE + k];
    ssc[k] = sc;
    float a0 = anch[(size_t)idx * 4 + 0], a1 = anch[(size_t)idx * 4 + 1];
    float a2 = anch[(size_t)idx * 4 + 2], a3 = anch[(size_t)idx * 4 + 3];
    float r0 = reg[(size_t)idx * 4 + 0], r1 = reg[(size_t)idx * 4 + 1];
    float r2 = reg[(size_t)idx * 4 + 2], r3 = reg[(size_t)idx * 4 + 3];
    float w = a2 - a0, h = a3 - a1;
    float cx = a0 + 0.5f * w, cy = a1 + 0.5f * h;
    float dx = r0 * 0.1f, dy = r1 * 0.1f, dw = r2 * 0.2f, dh = r3 * 0.2f;
    float pcx = cx + dx * w, pcy = cy + dy * h;
    float pw = (float)exp((double)dw) * w;
    float ph = (float)exp((double)dh) * h;
    float x1 = fminf(fmaxf(pcx - 0.5f * pw, 0.0f), W);
    float y1 = fminf(fmaxf(pcy - 0.5f * ph, 0.0f), H);
    float x2 = fminf(fmaxf(pcx + 0.5f * pw, 0.0f), W);
    float y2 = fminf(fmaxf(pcy + 0.5f * ph, 0.0f), H);
    bx[k] = x1; by[k] = y1; bX[k] = x2; bY[k] = y2;
    bar[k] = (x2 - x1) * (y2 - y1);
  }
  __syncthreads();
  const int wave = t >> 6, lane = t & 63;
  for (int i = wave; i < PRE; i += 4) {
    float x1 = bx[i], y1 = by[i], X1 = bX[i], Y1 = bY[i], ai = bar[i];
    for (int g = 0; g < 16; g++) {
      int j = g * 64 + lane;
      bool s = false;
      if (j > i && j < PRE) {
        float ltx = fmaxf(x1, bx[j]);
        float lty = fmaxf(y1, by[j]);
        float rbx = fminf(X1, bX[j]);
        float rby = fminf(Y1, bY[j]);
        float ww = fmaxf(rbx - ltx, 0.0f);
        float hh = fmaxf(rby - lty, 0.0f);
        float inter = ww * hh;
        float iou = inter / ((ai + bar[j]) - inter + 1e-8f);
        s = iou > 0.5f;
      }
      u64 m = __ballot(s);
      if (lane == 0) supm[i * 16 + g] = m;
    }
  }
  __syncthreads();
  if (t < 64) {
    u64 kw = 0ull;
    if (t < 16) {
      for (int b = 0; b < 64; b++) {
        int k = t * 64 + b;
        if (k < PRE && ssc[k] != -INFINITY) kw |= (1ull << b);
      }
    }
    for (int i = 0; i < PRE; i++) {
      u64 ow = __shfl(kw, i >> 6);
      if ((ow >> (i & 63)) & 1ull) {
        if (t < 16) kw &= ~supm[i * 16 + t];
      }
    }
    if (t < 16) keepw[t] = kw;
  }
  __syncthreads();
  if (t == 0) {
    unsigned acc = 0;
    for (int w = 0; w < 16; w++) { wpre[w] = acc; acc += (unsigned)__popcll(keepw[w]); }
    wpre[16] = acc;
  }
  __syncthreads();
  const unsigned total = wpre[16];
  for (int k = t; k < PRE; k += 256) {
    int w = k >> 6, b = k & 63;
    u64 kw = keepw[w];
    if ((kw >> b) & 1ull) {
      unsigned rank = wpre[w] + (unsigned)__popcll(kw & ((1ull << b) - 1ull));
      if (rank < MAXD) {
        int slot = c * MAXD + (int)rank;
        out_s[slot] = ssc[k];
        out_id[slot] = (float)c;
        out_b[slot * 4 + 0] = bx[k];
        out_b[slot * 4 + 1] = by[k];
        out_b[slot * 4 + 2] = bX[k];
        out_b[slot * 4 + 3] = bY[k];
        out_d[slot] = dist[topidx[c * PRE + k]];
      }
    }
  }
  unsigned tk = total < MAXD ? total : MAXD;
  for (int r = (int)tk + t; r < MAXD; r += 256) {
    int slot = c * MAXD + r;
    out_s[slot] = 0.0f;
    out_id[slot] = -1.0f;
    out_b[slot * 4 + 0] = 0.0f; out_b[slot * 4 + 1] = 0.0f;
    out_b[slot * 4 + 2] = 0.0f; out_b[slot * 4 + 3] = 0.0f;
    out_d[slot] = 0.0f;
  }
}

// =====================================================================

static inline size_t align512(size_t x) { return (x + 511) & ~(size_t)511; }

extern "C" void kernel_launch(void* const* d_in, const int* in_sizes, int n_in,
                              void* d_out, int out_size, void* d_ws, size_t ws_size,
                              hipStream_t stream) {
  const float* cls  = (const float*)d_in[0];   // (1, A, 80)
  const float* reg  = (const float*)d_in[1];   // (1, A, 4)
  const float* dist = (const float*)d_in[2];   // (1, A, 1)
  const float* anch = (const float*)d_in[3];   // (1, A, 4)
  const int* img_h  = (const int*)d_in[4];
  const int* img_w  = (const int*)d_in[5];
  const int A = in_sizes[3] / 4;

  float* o = (float*)d_out;
  float* out_s  = o;                      // 8000
  float* out_id = o + NCLS * MAXD;        // 8000
  float* out_b  = o + 2 * NCLS * MAXD;    // 32000
  float* out_d  = o + 6 * NCLS * MAXD;    // 8000

  // fast-path workspace layout
  size_t off = 0;
  size_t o_part = off; off += align512((size_t)K1B * BINS * sizeof(unsigned short));
  size_t o_cb   = off; off += align512(NCLS * sizeof(int));
  size_t o_ccnt = off; off += align512((size_t)NCLS * SUBS * sizeof(unsigned));
  size_t o_cand = off; off += align512((size_t)NCLS * SUBS * SUBCAP * sizeof(u64));
  size_t o_ts   = off; off += align512((size_t)NCLS * PRE * sizeof(float));
  size_t o_ti   = off; off += align512((size_t)NCLS * PRE * sizeof(unsigned));
  size_t o_b5   = off; off += align512((size_t)5 * NCLS * PRE * sizeof(float));
  const size_t needed = off;

  if (ws_size >= needed) {
    char* ws = (char*)d_ws;
    unsigned short* part = (unsigned short*)(ws + o_part);
    int* cb = (int*)(ws + o_cb);
    unsigned* ccnt = (unsigned*)(ws + o_ccnt);
    u64* cand = (u64*)(ws + o_cand);
    float* ts = (float*)(ws + o_ts);
    unsigned* ti = (unsigned*)(ws + o_ti);
    float* b5 = (float*)(ws + o_b5);
    const int total4 = A * 20;  // A*80/4

    k1_hist<<<K1B, 256, 0, stream>>>((const float4*)cls, total4, part);
    k2_cutoff<<<BINS / 256, 256, 0, stream>>>(part, cb, ccnt);
    k3_collect<<<256, 256, 0, stream>>>((const float4*)cls, total4, cb, ccnt, cand);
    k4_sort_decode<<<NCLS, 512, 0, stream>>>(ccnt, cand, anch, reg, img_h, img_w, ts, ti, b5);
    k5_nms<<<NCLS, 512, 0, stream>>>(ts, ti, b5, dist, out_s, out_id, out_b, out_d);
  } else {
    // fallback: proven round-1 path (needs only ~0.64 MB)
    float* topscore = (float*)d_ws;
    unsigned* topidx = (unsigned*)((char*)d_ws + NCLS * PRE * sizeof(float));
    select_topk<<<NCLS, 256, 0, stream>>>(cls, A, topscore, topidx);
    nms_out<<<NCLS, 256, 0, stream>>>(anch, reg, dist, topscore, topidx,
                                      img_h, img_w, out_s, out_id, out_b, out_d);
  }
}

// Round 3
// 389.268 us; speedup vs baseline: 3.0981x; 1.3578x over previous
//
#include <hip/hip_runtime.h>
#include <math.h>

#define NCLS 80
#define PRE 1000
#define MAXD 100
#define THR_SCORE 0.05f

// ---- fast path config ----
#define NB 256                 // buckets per class (fine cutoff -> <=2048 candidates)
#define BINS (NCLS * NB)       // 20480
#define K1B 256                // histogram blocks
#define SUBS 16                // sub-lists per class (atomic spreading)
#define SUBCAP 512             // depth per sub-list
#define CSORT 2048             // sort capacity per class

typedef unsigned long long u64;

// =====================================================================
// FAST PATH
// =====================================================================

// K1: coalesced float4 pass over cls, per-block LDS hist (80x256), u16 partials out.
__global__ __launch_bounds__(256) void k1_hist(
    const float4* __restrict__ cls4, int total4, unsigned short* __restrict__ part)
{
  __shared__ unsigned h[BINS];
  const int t = threadIdx.x;
  for (int i = t; i < BINS; i += 256) h[i] = 0u;
  __syncthreads();
  const int stride = gridDim.x * 256;
  for (int q = blockIdx.x * 256 + t; q < total4; q += stride) {
    float4 v = cls4[q];
    int c0 = 4 * (q % 20);  // (4q) % 80
    float s;
    int b;
    s = v.x; if (s > THR_SCORE) { b = (int)(s * (float)NB); b = b < 0 ? 0 : (b > NB - 1 ? NB - 1 : b); atomicAdd(&h[(c0 + 0) * NB + b], 1u); }
    s = v.y; if (s > THR_SCORE) { b = (int)(s * (float)NB); b = b < 0 ? 0 : (b > NB - 1 ? NB - 1 : b); atomicAdd(&h[(c0 + 1) * NB + b], 1u); }
    s = v.z; if (s > THR_SCORE) { b = (int)(s * (float)NB); b = b < 0 ? 0 : (b > NB - 1 ? NB - 1 : b); atomicAdd(&h[(c0 + 2) * NB + b], 1u); }
    s = v.w; if (s > THR_SCORE) { b = (int)(s * (float)NB); b = b < 0 ? 0 : (b > NB - 1 ? NB - 1 : b); atomicAdd(&h[(c0 + 3) * NB + b], 1u); }
  }
  __syncthreads();
  unsigned short* p = part + (size_t)blockIdx.x * BINS;
  for (int i = t; i < BINS; i += 256) p[i] = (unsigned short)h[i];
}

// K2: one block per class; reduce partial hists (256 bins) -> cutoff bucket.
// Also zeroes the push counters.
__global__ __launch_bounds__(256) void k2_cutoff(
    const unsigned short* __restrict__ part, int* __restrict__ cb,
    unsigned* __restrict__ ccnt)
{
  const int c = blockIdx.x;
  const int t = threadIdx.x;
  __shared__ unsigned lh[NB];
  unsigned acc = 0;
  for (int p = 0; p < K1B; p++) acc += part[(size_t)p * BINS + c * NB + t];
  lh[t] = acc;
  if (t < SUBS) ccnt[c * SUBS + t] = 0u;
  __syncthreads();
  if (t == 0) {
    unsigned a = 0;
    int cbv = 0;
    for (int b = NB - 1; b >= 0; b--) {
      a += lh[b];
      if (a >= (unsigned)PRE) { cbv = b; break; }
    }
    // overflow guard (pathological dense bucket)
    while (a > (unsigned)CSORT && cbv < NB - 1) { a -= lh[cbv]; cbv++; }
    cb[c] = cbv;
  }
}

// K3: coalesced float4 pass; push candidates above per-class cutoff into
// per-(class,sub) lists. key = score_bits<<32 | ~anchor (desc order == jax top_k).
__global__ __launch_bounds__(256) void k3_collect(
    const float4* __restrict__ cls4, int total4, const int* __restrict__ cb,
    unsigned* __restrict__ ccnt, u64* __restrict__ cand)
{
  __shared__ int scb[NCLS];
  const int t = threadIdx.x;
  if (t < NCLS) scb[t] = cb[t];
  __syncthreads();
  const int sub = blockIdx.x & (SUBS - 1);
  const int stride = gridDim.x * 256;
  for (int q = blockIdx.x * 256 + t; q < total4; q += stride) {
    float4 v = cls4[q];
    int c0 = 4 * (q % 20);
    unsigned a = (unsigned)(q / 20);
    float sv[4] = {v.x, v.y, v.z, v.w};
#pragma unroll
    for (int e = 0; e < 4; e++) {
      float s = sv[e];
      if (s > THR_SCORE) {
        int b = (int)(s * (float)NB);
        b = b < 0 ? 0 : (b > NB - 1 ? NB - 1 : b);
        int c = c0 + e;
        if (b >= scb[c]) {
          unsigned p = atomicAdd(&ccnt[c * SUBS + sub], 1u);
          if (p < SUBCAP)
            cand[((size_t)(c * SUBS + sub)) * SUBCAP + p] =
                ((u64)__float_as_uint(s) << 32) | (u64)(~a);
        }
      }
    }
  }
}

// K45: per-class sort(2048) + decode + supm build (columns in registers) +
// exact serial NMS scan + top-100 output. Sort buffer aliases supm LDS.
__global__ __launch_bounds__(512, 2) void k45_sort_nms(
    const unsigned* __restrict__ ccnt, const u64* __restrict__ cand,
    const float* __restrict__ anch, const float* __restrict__ reg,
    const float* __restrict__ dist,
    const int* __restrict__ img_h_p, const int* __restrict__ img_w_p,
    float* __restrict__ out_s, float* __restrict__ out_id,
    float* __restrict__ out_b, float* __restrict__ out_d)
{
#pragma clang fp contract(off)
  const int c = blockIdx.x;
  const int t = threadIdx.x;
  __shared__ u64 supm[PRE * 16];       // 128000 B; first CSORT u64 double as sort buf
  __shared__ float4 box4[1024];        // decoded boxes (+pad)
  __shared__ float area[1024];
  __shared__ float ssc[1024];
  __shared__ unsigned sidx[1024];
  __shared__ unsigned sbase[SUBS];
  __shared__ u64 keepw[16];
  __shared__ unsigned wpre[17];

  u64* L = supm;  // sort buffer alias

  // ---- gather candidates ----
  if (t == 0) {
    unsigned accq = 0;
    for (int s = 0; s < SUBS; s++) {
      unsigned n = ccnt[c * SUBS + s];
      if (n > SUBCAP) n = SUBCAP;
      sbase[s] = accq;
      accq += n;
    }
  }
  for (int i = t; i < CSORT; i += 512) L[i] = 0ull;
  __syncthreads();
  for (int s = 0; s < SUBS; s++) {
    unsigned n = ccnt[c * SUBS + s];
    if (n > SUBCAP) n = SUBCAP;
    unsigned bs = sbase[s];
    for (unsigned i = t; i < n; i += 512) {
      unsigned d = bs + i;
      if (d < CSORT) L[d] = cand[((size_t)(c * SUBS + s)) * SUBCAP + i];
    }
  }
  __syncthreads();

  // ---- bitonic sort descending (2048) ----
  for (int k = 2; k <= CSORT; k <<= 1) {
    for (int j = k >> 1; j > 0; j >>= 1) {
      for (int i = t; i < CSORT; i += 512) {
        int ixj = i ^ j;
        if (ixj > i) {
          u64 va = L[i], vb = L[ixj];
          bool desc = ((i & k) == 0);
          if (desc ? (va < vb) : (va > vb)) { L[i] = vb; L[ixj] = va; }
        }
      }
      __syncthreads();
    }
  }

  // ---- decode top-1000 into LDS (numpy op order, contract off, exp double) ----
  const float W = (float)img_w_p[0];
  const float H = (float)img_h_p[0];
  const float4* a4 = (const float4*)anch;
  const float4* r4 = (const float4*)reg;
  for (int k = t; k < 1024; k += 512) {
    if (k < PRE) {
      u64 key = L[k];
      float sc;
      unsigned idx;
      if (key != 0ull) {
        sc = __uint_as_float((unsigned)(key >> 32));
        idx = ~((unsigned)(key & 0xFFFFFFFFull));
      } else {
        sc = -INFINITY;
        idx = 0u;
      }
      float4 av = a4[idx];
      float4 rv = r4[idx];
      float w = av.z - av.x, h = av.w - av.y;
      float cx = av.x + 0.5f * w, cy = av.y + 0.5f * h;
      float dx = rv.x * 0.1f, dy = rv.y * 0.1f, dw = rv.z * 0.2f, dh = rv.w * 0.2f;
      float pcx = cx + dx * w, pcy = cy + dy * h;
      float pw = (float)exp((double)dw) * w;
      float ph = (float)exp((double)dh) * h;
      float x1 = fminf(fmaxf(pcx - 0.5f * pw, 0.0f), W);
      float y1 = fminf(fmaxf(pcy - 0.5f * ph, 0.0f), H);
      float x2 = fminf(fmaxf(pcx + 0.5f * pw, 0.0f), W);
      float y2 = fminf(fmaxf(pcy + 0.5f * ph, 0.0f), H);
      box4[k] = make_float4(x1, y1, x2, y2);
      area[k] = (x2 - x1) * (y2 - y1);
      ssc[k] = sc;
      sidx[k] = idx;
    } else {
      box4[k] = make_float4(0.f, 0.f, 0.f, 0.f);
      area[k] = 0.f;
      ssc[k] = -INFINITY;
      sidx[k] = 0u;
    }
  }
  __syncthreads();  // L (supm) free to overwrite after this point

  // ---- supm build: columns cached in registers ----
  const int wave = t >> 6, lane = t & 63;
  float4 cbx[16];
  float car[16];
#pragma unroll
  for (int g = 0; g < 16; g++) {
    cbx[g] = box4[g * 64 + lane];
    car[g] = area[g * 64 + lane];
  }
  // exact equivalent of fl32(inter/denom) > 0.5f :
  // (double)inter > (0.5*(1+2^-24)) * (double)denom   (product exact in double)
  const double MID = 0x1.000001p-1;
  for (int i = wave; i < PRE; i += 8) {
    float4 rb = box4[i];           // broadcast b128
    float ra = area[i];
    const int g0 = i >> 6;
    const int ib = i & 63;
    u64 mrow = 0ull;
#pragma unroll
    for (int g = 0; g < 16; g++) {
      if (g < g0) continue;        // wave-uniform skip
      float ltx = fmaxf(rb.x, cbx[g].x);
      float lty = fmaxf(rb.y, cbx[g].y);
      float rbx = fminf(rb.z, cbx[g].z);
      float rby = fminf(rb.w, cbx[g].w);
      float ww = fmaxf(rbx - ltx, 0.0f);
      float hh = fmaxf(rby - lty, 0.0f);
      float inter = ww * hh;
      float denom = ((ra + car[g]) - inter) + 1e-8f;
      bool io = (double)inter > MID * (double)denom;
      bool pred = (g > g0) | (lane > ib);
      bool inb = (g < 15) | (lane < PRE - 15 * 64);
      u64 m = __ballot(io & pred & inb);
      mrow = (lane == g) ? m : mrow;
    }
    if (lane < 16) supm[i * 16 + lane] = mrow;
  }
  __syncthreads();

  // ---- exact sequential scan (wave 0; lanes 0..15 hold keep words) ----
  if (t < 64) {
    u64 kw = 0ull;
    if (t < 16) {
      for (int b = 0; b < 64; b++) {
        int k = t * 64 + b;
        if (k < PRE && ssc[k] != -INFINITY) kw |= (1ull << b);
      }
    }
    u64 nxt = (t < 16) ? supm[t] : 0ull;
    for (int i = 0; i < PRE; i++) {
      u64 cur = nxt;
      if (t < 16 && i + 1 < PRE) nxt = supm[(i + 1) * 16 + t];
      u64 ow = __shfl(kw, i >> 6);
      if ((ow >> (i & 63)) & 1ull) {
        if (t < 16) kw &= ~cur;
      }
    }
    if (t < 16) keepw[t] = kw;
  }
  __syncthreads();

  if (t == 0) {
    unsigned acc = 0;
    for (int w = 0; w < 16; w++) { wpre[w] = acc; acc += (unsigned)__popcll(keepw[w]); }
    wpre[16] = acc;
  }
  __syncthreads();
  const unsigned total = wpre[16];

  // ---- output: kept entries in order == final top-100 ----
  for (int k = t; k < PRE; k += 512) {
    int w = k >> 6, b = k & 63;
    u64 kwv = keepw[w];
    if ((kwv >> b) & 1ull) {
      unsigned rank = wpre[w] + (unsigned)__popcll(kwv & ((1ull << b) - 1ull));
      if (rank < MAXD) {
        int slot = c * MAXD + (int)rank;
        out_s[slot] = ssc[k];
        out_id[slot] = (float)c;
        ((float4*)out_b)[slot] = box4[k];
        out_d[slot] = dist[sidx[k]];
      }
    }
  }
  unsigned tk = total < MAXD ? total : MAXD;
  for (int r = (int)tk + t; r < MAXD; r += 512) {
    int slot = c * MAXD + r;
    out_s[slot] = 0.0f;
    out_id[slot] = -1.0f;
    ((float4*)out_b)[slot] = make_float4(0.f, 0.f, 0.f, 0.f);
    out_d[slot] = 0.0f;
  }
}

// =====================================================================
// FALLBACK PATH (round-1, proven correct; used only if ws is too small)
// =====================================================================
#define NBUCK 4096
#define CANDF 2048

__global__ __launch_bounds__(256) void select_topk(
    const float* __restrict__ cls, int A,
    float* __restrict__ topscore, unsigned* __restrict__ topidx)
{
  const int c = blockIdx.x;
  const int t = threadIdx.x;
  __shared__ unsigned hist[NBUCK];
  __shared__ u64 cand[CANDF];
  __shared__ unsigned chunk[256];
  __shared__ int s_cb;
  __shared__ int s_cnt;
  for (int i = t; i < NBUCK; i += 256) hist[i] = 0u;
  if (t == 0) s_cnt = 0;
  __syncthreads();
  for (int a = t; a < A; a += 256) {
    float s = cls[(size_t)a * NCLS + c];
    if (s > THR_SCORE) {
      int b = (int)(s * (float)NBUCK);
      b = b < 0 ? 0 : (b > NBUCK - 1 ? NBUCK - 1 : b);
      atomicAdd(&hist[b], 1u);
    }
  }
  __syncthreads();
  {
    unsigned cs = 0;
    for (int i = 0; i < NBUCK / 256; i++) cs += hist[t * (NBUCK / 256) + i];
    chunk[t] = cs;
  }
  __syncthreads();
  if (t == 0) {
    unsigned acc = 0;
    int cb = 0;
    int ch;
    for (ch = 255; ch >= 0; ch--) {
      if (acc + chunk[ch] >= (unsigned)PRE) break;
      acc += chunk[ch];
    }
    if (ch < 0) cb = 0;
    else {
      const int bpc = NBUCK / 256;
      int b = ch * bpc + bpc - 1;
      for (; b >= ch * bpc; b--) { acc += hist[b]; if (acc >= (unsigned)PRE) break; }
      if (b < ch * bpc) b = ch * bpc;
      cb = b;
      while (acc > (unsigned)CANDF && cb < NBUCK - 1) { acc -= hist[cb]; cb++; }
    }
    s_cb = cb;
  }
  __syncthreads();
  const int cb = s_cb;
  for (int a = t; a < A; a += 256) {
    float s = cls[(size_t)a * NCLS + c];
    if (s > THR_SCORE) {
      int b = (int)(s * (float)NBUCK);
      b = b < 0 ? 0 : (b > NBUCK - 1 ? NBUCK - 1 : b);
      if (b >= cb) {
        int p = atomicAdd(&s_cnt, 1);
        if (p < CANDF)
          cand[p] = ((u64)__float_as_uint(s) << 32) | (u64)(~(unsigned)a);
      }
    }
  }
  __syncthreads();
  int n = s_cnt < CANDF ? s_cnt : CANDF;
  for (int i = n + t; i < CANDF; i += 256) cand[i] = 0ull;
  __syncthreads();
  for (int k = 2; k <= CANDF; k <<= 1) {
    for (int j = k >> 1; j > 0; j >>= 1) {
      for (int i = t; i < CANDF; i += 256) {
        int ixj = i ^ j;
        if (ixj > i) {
          u64 va = cand[i], vb = cand[ixj];
          bool desc = ((i & k) == 0);
          if (desc ? (va < vb) : (va > vb)) { cand[i] = vb; cand[ixj] = va; }
        }
      }
      __syncthreads();
    }
  }
  for (int k = t; k < PRE; k += 256) {
    u64 key = cand[k];
    float sc; unsigned idx;
    if (key != 0ull) { sc = __uint_as_float((unsigned)(key >> 32)); idx = ~((unsigned)(key & 0xFFFFFFFFull)); }
    else { sc = -INFINITY; idx = 0u; }
    topscore[c * PRE + k] = sc;
    topidx[c * PRE + k] = idx;
  }
}

__global__ __launch_bounds__(256) void nms_out(
    const float* __restrict__ anch, const float* __restrict__ reg,
    const float* __restrict__ dist,
    const float* __restrict__ topscore, const unsigned* __restrict__ topidx,
    const int* __restrict__ img_h_p, const int* __restrict__ img_w_p,
    float* __restrict__ out_s, float* __restrict__ out_id,
    float* __restrict__ out_b, float* __restrict__ out_d)
{
#pragma clang fp contract(off)
  const int c = blockIdx.x;
  const int t = threadIdx.x;
  __shared__ float bx[PRE], by[PRE], bX[PRE], bY[PRE], bar[PRE], ssc[PRE];
  __shared__ u64 supm[PRE * 16];
  __shared__ u64 keepw[16];
  __shared__ unsigned wpre[17];
  const float W = (float)img_w_p[0];
  const float H = (float)img_h_p[0];
  for (int k = t; k < PRE; k += 256) {
    float sc = topscore[c * PRE + k];
    unsigned idx = topidx[c * PRE + k];
    ssc[k] = sc;
    float a0 = anch[(size_t)idx * 4 + 0], a1 = anch[(size_t)idx * 4 + 1];
    float a2 = anch[(size_t)idx * 4 + 2], a3 = anch[(size_t)idx * 4 + 3];
    float r0 = reg[(size_t)idx * 4 + 0], r1 = reg[(size_t)idx * 4 + 1];
    float r2 = reg[(size_t)idx * 4 + 2], r3 = reg[(size_t)idx * 4 + 3];
    float w = a2 - a0, h = a3 - a1;
    float cx = a0 + 0.5f * w, cy = a1 + 0.5f * h;
    float dx = r0 * 0.1f, dy = r1 * 0.1f, dw = r2 * 0.2f, dh = r3 * 0.2f;
    float pcx = cx + dx * w, pcy = cy + dy * h;
    float pw = (float)exp((double)dw) * w;
    float ph = (float)exp((double)dh) * h;
    float x1 = fminf(fmaxf(pcx - 0.5f * pw, 0.0f), W);
    float y1 = fminf(fmaxf(pcy - 0.5f * ph, 0.0f), H);
    float x2 = fminf(fmaxf(pcx + 0.5f * pw, 0.0f), W);
    float y2 = fminf(fmaxf(pcy + 0.5f * ph, 0.0f), H);
    bx[k] = x1; by[k] = y1; bX[k] = x2; bY[k] = y2;
    bar[k] = (x2 - x1) * (y2 - y1);
  }
  __syncthreads();
  const int wave = t >> 6, lane = t & 63;
  for (int i = wave; i < PRE; i += 4) {
    float x1 = bx[i], y1 = by[i], X1 = bX[i], Y1 = bY[i], ai = bar[i];
    for (int g = 0; g < 16; g++) {
      int j = g * 64 + lane;
      bool s = false;
      if (j > i && j < PRE) {
        float ltx = fmaxf(x1, bx[j]);
        float lty = fmaxf(y1, by[j]);
        float rbx = fminf(X1, bX[j]);
        float rby = fminf(Y1, bY[j]);
        float ww = fmaxf(rbx - ltx, 0.0f);
        float hh = fmaxf(rby - lty, 0.0f);
        float inter = ww * hh;
        float iou = inter / ((ai + bar[j]) - inter + 1e-8f);
        s = iou > 0.5f;
      }
      u64 m = __ballot(s);
      if (lane == 0) supm[i * 16 + g] = m;
    }
  }
  __syncthreads();
  if (t < 64) {
    u64 kw = 0ull;
    if (t < 16) {
      for (int b = 0; b < 64; b++) {
        int k = t * 64 + b;
        if (k < PRE && ssc[k] != -INFINITY) kw |= (1ull << b);
      }
    }
    for (int i = 0; i < PRE; i++) {
      u64 ow = __shfl(kw, i >> 6);
      if ((ow >> (i & 63)) & 1ull) {
        if (t < 16) kw &= ~supm[i * 16 + t];
      }
    }
    if (t < 16) keepw[t] = kw;
  }
  __syncthreads();
  if (t == 0) {
    unsigned acc = 0;
    for (int w = 0; w < 16; w++) { wpre[w] = acc; acc += (unsigned)__popcll(keepw[w]); }
    wpre[16] = acc;
  }
  __syncthreads();
  const unsigned total = wpre[16];
  for (int k = t; k < PRE; k += 256) {
    int w = k >> 6, b = k & 63;
    u64 kw = keepw[w];
    if ((kw >> b) & 1ull) {
      unsigned rank = wpre[w] + (unsigned)__popcll(kw & ((1ull << b) - 1ull));
      if (rank < MAXD) {
        int slot = c * MAXD + (int)rank;
        out_s[slot] = ssc[k];
        out_id[slot] = (float)c;
        out_b[slot * 4 + 0] = bx[k];
        out_b[slot * 4 + 1] = by[k];
        out_b[slot * 4 + 2] = bX[k];
        out_b[slot * 4 + 3] = bY[k];
        out_d[slot] = dist[topidx[c * PRE + k]];
      }
    }
  }
  unsigned tk = total < MAXD ? total : MAXD;
  for (int r = (int)tk + t; r < MAXD; r += 256) {
    int slot = c * MAXD + r;
    out_s[slot] = 0.0f;
    out_id[slot] = -1.0f;
    out_b[slot * 4 + 0] = 0.0f; out_b[slot * 4 + 1] = 0.0f;
    out_b[slot * 4 + 2] = 0.0f; out_b[slot * 4 + 3] = 0.0f;
    out_d[slot] = 0.0f;
  }
}

// =====================================================================

static inline size_t align512(size_t x) { return (x + 511) & ~(size_t)511; }

extern "C" void kernel_launch(void* const* d_in, const int* in_sizes, int n_in,
                              void* d_out, int out_size, void* d_ws, size_t ws_size,
                              hipStream_t stream) {
  const float* cls  = (const float*)d_in[0];   // (1, A, 80)
  const float* reg  = (const float*)d_in[1];   // (1, A, 4)
  const float* dist = (const float*)d_in[2];   // (1, A, 1)
  const float* anch = (const float*)d_in[3];   // (1, A, 4)
  const int* img_h  = (const int*)d_in[4];
  const int* img_w  = (const int*)d_in[5];
  const int A = in_sizes[3] / 4;

  float* o = (float*)d_out;
  float* out_s  = o;                      // 8000
  float* out_id = o + NCLS * MAXD;        // 8000
  float* out_b  = o + 2 * NCLS * MAXD;    // 32000
  float* out_d  = o + 6 * NCLS * MAXD;    // 8000

  // ws layout: part (k1->k2) and cand (k3->k45) alias (part dead after k2)
  const size_t sz_part = (size_t)K1B * BINS * sizeof(unsigned short);       // 10.49 MB
  const size_t sz_cand = (size_t)NCLS * SUBS * SUBCAP * sizeof(u64);        // 5.24 MB
  size_t off = align512(sz_part > sz_cand ? sz_part : sz_cand);
  const size_t o_cb   = off; off += align512(NCLS * sizeof(int));
  const size_t o_ccnt = off; off += align512((size_t)NCLS * SUBS * sizeof(unsigned));
  const size_t needed = off;

  if (ws_size >= needed) {
    char* ws = (char*)d_ws;
    unsigned short* part = (unsigned short*)ws;
    u64* cand = (u64*)ws;
    int* cb = (int*)(ws + o_cb);
    unsigned* ccnt = (unsigned*)(ws + o_ccnt);
    const int total4 = A * 20;  // A*80/4

    k1_hist<<<K1B, 256, 0, stream>>>((const float4*)cls, total4, part);
    k2_cutoff<<<NCLS, 256, 0, stream>>>(part, cb, ccnt);
    k3_collect<<<256, 256, 0, stream>>>((const float4*)cls, total4, cb, ccnt, cand);
    k45_sort_nms<<<NCLS, 512, 0, stream>>>(ccnt, cand, anch, reg, dist,
                                           img_h, img_w, out_s, out_id, out_b, out_d);
  } else {
    // fallback: proven round-1 path (needs only ~0.64 MB)
    float* topscore = (float*)d_ws;
    unsigned* topidx = (unsigned*)((char*)d_ws + NCLS * PRE * sizeof(float));
    select_topk<<<NCLS, 256, 0, stream>>>(cls, A, topscore, topidx);
    nms_out<<<NCLS, 256, 0, stream>>>(anch, reg, dist, topscore, topidx,
                                      img_h, img_w, out_s, out_id, out_b, out_d);
  }
}

// Round 4
// 294.491 us; speedup vs baseline: 4.0951x; 1.3218x over previous
//
#include <hip/hip_runtime.h>
#include <math.h>

#define NCLS 80
#define PRE 1000
#define MAXD 100
#define THR_SCORE 0.05f

// ---- fast path config ----
#define NB 256                 // buckets per class
#define BINS (NCLS * NB)       // 20480
#define K1B 256                // histogram blocks
#define SUBS 16                // sub-lists per class
#define SUBCAP 512             // depth per sub-list
#define CSORT 2048             // sort capacity per class
#define RS 8                   // row-split blocks per class in kB
#define SUPM_STRIDE 16384      // 1024 rows x 16 words per class (padded)

typedef unsigned long long u64;

__device__ __forceinline__ u64 readlane64(u64 v, int l) {
  unsigned lo = (unsigned)__builtin_amdgcn_readlane((int)(unsigned)v, l);
  unsigned hi = (unsigned)__builtin_amdgcn_readlane((int)(unsigned)(v >> 32), l);
  return ((u64)hi << 32) | lo;
}

// =====================================================================
// K1: coalesced float4 pass over cls, per-block LDS hist (80x256), u16 partials.
__global__ __launch_bounds__(256) void k1_hist(
    const float4* __restrict__ cls4, int total4, unsigned short* __restrict__ part)
{
  __shared__ unsigned h[BINS];
  const int t = threadIdx.x;
  for (int i = t; i < BINS; i += 256) h[i] = 0u;
  __syncthreads();
  const int stride = gridDim.x * 256;
  for (int q = blockIdx.x * 256 + t; q < total4; q += stride) {
    float4 v = cls4[q];
    int c0 = 4 * (q % 20);  // (4q) % 80
    float s; int b;
    s = v.x; if (s > THR_SCORE) { b = (int)(s * (float)NB); b = b < 0 ? 0 : (b > NB - 1 ? NB - 1 : b); atomicAdd(&h[(c0 + 0) * NB + b], 1u); }
    s = v.y; if (s > THR_SCORE) { b = (int)(s * (float)NB); b = b < 0 ? 0 : (b > NB - 1 ? NB - 1 : b); atomicAdd(&h[(c0 + 1) * NB + b], 1u); }
    s = v.z; if (s > THR_SCORE) { b = (int)(s * (float)NB); b = b < 0 ? 0 : (b > NB - 1 ? NB - 1 : b); atomicAdd(&h[(c0 + 2) * NB + b], 1u); }
    s = v.w; if (s > THR_SCORE) { b = (int)(s * (float)NB); b = b < 0 ? 0 : (b > NB - 1 ? NB - 1 : b); atomicAdd(&h[(c0 + 3) * NB + b], 1u); }
  }
  __syncthreads();
  unsigned short* p = part + (size_t)blockIdx.x * BINS;
  for (int i = t; i < BINS; i += 256) p[i] = (unsigned short)h[i];
}

// K2: one block per class; reduce 256 partials -> cutoff bucket; zero counters.
__global__ __launch_bounds__(256) void k2_cutoff(
    const unsigned short* __restrict__ part, int* __restrict__ cb,
    unsigned* __restrict__ ccnt)
{
  const int c = blockIdx.x;
  const int t = threadIdx.x;
  __shared__ unsigned lh[NB];
  unsigned acc = 0;
  for (int p = 0; p < K1B; p++) acc += part[(size_t)p * BINS + c * NB + t];
  lh[t] = acc;
  if (t < SUBS) ccnt[c * SUBS + t] = 0u;
  __syncthreads();
  if (t == 0) {
    unsigned a = 0;
    int cbv = 0;
    for (int b = NB - 1; b >= 0; b--) {
      a += lh[b];
      if (a >= (unsigned)PRE) { cbv = b; break; }
    }
    while (a > (unsigned)CSORT && cbv < NB - 1) { a -= lh[cbv]; cbv++; }
    cb[c] = cbv;
  }
}

// K3: coalesced pass; push candidates above per-class cutoff into sub-lists.
__global__ __launch_bounds__(256) void k3_collect(
    const float4* __restrict__ cls4, int total4, const int* __restrict__ cb,
    unsigned* __restrict__ ccnt, u64* __restrict__ cand)
{
  __shared__ int scb[NCLS];
  const int t = threadIdx.x;
  if (t < NCLS) scb[t] = cb[t];
  __syncthreads();
  const int sub = blockIdx.x & (SUBS - 1);
  const int stride = gridDim.x * 256;
  for (int q = blockIdx.x * 256 + t; q < total4; q += stride) {
    float4 v = cls4[q];
    int c0 = 4 * (q % 20);
    unsigned a = (unsigned)(q / 20);
    float sv[4] = {v.x, v.y, v.z, v.w};
#pragma unroll
    for (int e = 0; e < 4; e++) {
      float s = sv[e];
      if (s > THR_SCORE) {
        int b = (int)(s * (float)NB);
        b = b < 0 ? 0 : (b > NB - 1 ? NB - 1 : b);
        int c = c0 + e;
        if (b >= scb[c]) {
          unsigned p = atomicAdd(&ccnt[c * SUBS + sub], 1u);
          if (p < SUBCAP)
            cand[((size_t)(c * SUBS + sub)) * SUBCAP + p] =
                ((u64)__float_as_uint(s) << 32) | (u64)(~a);
        }
      }
    }
  }
}

// kA: per-class bitonic sort (2048, 1024 threads) + decode -> global sorted arrays.
__global__ __launch_bounds__(1024) void kA_sort_decode(
    const unsigned* __restrict__ ccnt, const u64* __restrict__ cand,
    const float* __restrict__ anch, const float* __restrict__ reg,
    const int* __restrict__ img_h_p, const int* __restrict__ img_w_p,
    float4* __restrict__ sbox, float* __restrict__ sarea,
    float* __restrict__ sscore, unsigned* __restrict__ sidx)
{
#pragma clang fp contract(off)
  const int c = blockIdx.x;
  const int t = threadIdx.x;
  __shared__ u64 L[CSORT];
  __shared__ unsigned sbase[SUBS];
  if (t == 0) {
    unsigned a = 0;
    for (int s = 0; s < SUBS; s++) {
      unsigned n = ccnt[c * SUBS + s];
      if (n > SUBCAP) n = SUBCAP;
      sbase[s] = a;
      a += n;
    }
  }
  for (int i = t; i < CSORT; i += 1024) L[i] = 0ull;
  __syncthreads();
  for (int s = 0; s < SUBS; s++) {
    unsigned n = ccnt[c * SUBS + s];
    if (n > SUBCAP) n = SUBCAP;
    unsigned bs = sbase[s];
    for (unsigned i = t; i < n; i += 1024) {
      unsigned d = bs + i;
      if (d < CSORT) L[d] = cand[((size_t)(c * SUBS + s)) * SUBCAP + i];
    }
  }
  __syncthreads();
  for (int k = 2; k <= CSORT; k <<= 1) {
    for (int j = k >> 1; j > 0; j >>= 1) {
      for (int i = t; i < CSORT; i += 1024) {
        int ixj = i ^ j;
        if (ixj > i) {
          u64 va = L[i], vb = L[ixj];
          bool desc = ((i & k) == 0);
          if (desc ? (va < vb) : (va > vb)) { L[i] = vb; L[ixj] = va; }
        }
      }
      __syncthreads();
    }
  }
  // decode entry t (1024 threads, 1024 slots)
  const float W = (float)img_w_p[0];
  const float H = (float)img_h_p[0];
  const float4* a4 = (const float4*)anch;
  const float4* r4 = (const float4*)reg;
  const int k = t;
  if (k < PRE) {
    u64 key = L[k];
    float sc; unsigned idx;
    if (key != 0ull) {
      sc = __uint_as_float((unsigned)(key >> 32));
      idx = ~((unsigned)(key & 0xFFFFFFFFull));
    } else {
      sc = -INFINITY; idx = 0u;
    }
    float4 av = a4[idx];
    float4 rv = r4[idx];
    float w = av.z - av.x, h = av.w - av.y;
    float cx = av.x + 0.5f * w, cy = av.y + 0.5f * h;
    float dx = rv.x * 0.1f, dy = rv.y * 0.1f, dw = rv.z * 0.2f, dh = rv.w * 0.2f;
    float pcx = cx + dx * w, pcy = cy + dy * h;
    float pw = (float)exp((double)dw) * w;
    float ph = (float)exp((double)dh) * h;
    float x1 = fminf(fmaxf(pcx - 0.5f * pw, 0.0f), W);
    float y1 = fminf(fmaxf(pcy - 0.5f * ph, 0.0f), H);
    float x2 = fminf(fmaxf(pcx + 0.5f * pw, 0.0f), W);
    float y2 = fminf(fmaxf(pcy + 0.5f * ph, 0.0f), H);
    sbox[c * 1024 + k] = make_float4(x1, y1, x2, y2);
    sarea[c * 1024 + k] = (x2 - x1) * (y2 - y1);
    sscore[c * 1024 + k] = sc;
    sidx[c * 1024 + k] = idx;
  } else {
    sbox[c * 1024 + k] = make_float4(0.f, 0.f, 0.f, 0.f);
    sarea[c * 1024 + k] = 0.f;
    sscore[c * 1024 + k] = -INFINITY;
    sidx[c * 1024 + k] = 0u;
  }
}

// kB: supm build spread over RS blocks per class; columns in registers.
__global__ __launch_bounds__(256) void kB_build(
    const float4* __restrict__ sbox, const float* __restrict__ sarea,
    u64* __restrict__ supm)
{
#pragma clang fp contract(off)
  const int c = blockIdx.x >> 3;       // RS = 8
  const int r = blockIdx.x & (RS - 1);
  const int t = threadIdx.x;
  __shared__ float4 box4[1024];
  __shared__ float area[1024];
  for (int i = t; i < 1024; i += 256) {
    box4[i] = sbox[c * 1024 + i];
    area[i] = sarea[c * 1024 + i];
  }
  __syncthreads();
  const int wave = t >> 6, lane = t & 63;
  float4 cbx[16];
  float car[16];
#pragma unroll
  for (int g = 0; g < 16; g++) {
    cbx[g] = box4[g * 64 + lane];
    car[g] = area[g * 64 + lane];
  }
  u64* S = supm + (size_t)c * SUPM_STRIDE;
  // exact: fl32(inter/denom) > 0.5f  <=>  (double)inter > 0.5*(1+2^-24)*(double)denom
  const double MID = 0x1.000001p-1;
  for (int i = r * 4 + wave; i < PRE; i += 32) {
    float4 rb = box4[i];
    float ra = area[i];
    const int g0 = i >> 6;
    const int ib = i & 63;
    u64 mrow = 0ull;
#pragma unroll
    for (int g = 0; g < 16; g++) {
      if (g < g0) continue;
      float ltx = fmaxf(rb.x, cbx[g].x);
      float lty = fmaxf(rb.y, cbx[g].y);
      float rbx = fminf(rb.z, cbx[g].z);
      float rby = fminf(rb.w, cbx[g].w);
      float ww = fmaxf(rbx - ltx, 0.0f);
      float hh = fmaxf(rby - lty, 0.0f);
      float inter = ww * hh;
      float denom = ((ra + car[g]) - inter) + 1e-8f;
      bool io = (double)inter > MID * (double)denom;
      bool pred = (g > g0) | (lane > ib);
      bool inb = (g < 15) | (lane < PRE - 15 * 64);
      u64 m = __ballot(io & pred & inb);
      mrow = (lane == g) ? m : mrow;
    }
    if (lane < 16) S[i * 16 + lane] = mrow;
  }
}

// kC: exact serial NMS via scalar fire-resolution (readlane, no shuffle chain)
// + top-100 output. One wave per class.
__global__ __launch_bounds__(64) void kC_scan_out(
    const u64* __restrict__ supm, const float4* __restrict__ sbox,
    const float* __restrict__ sscore, const unsigned* __restrict__ sidx,
    const float* __restrict__ dist,
    float* __restrict__ out_s, float* __restrict__ out_id,
    float* __restrict__ out_b, float* __restrict__ out_d)
{
  const int c = blockIdx.x;
  const int lane = threadIdx.x;
  const u64* S = supm + (size_t)c * SUPM_STRIDE;
  __shared__ u64 keepw[16];
  __shared__ unsigned wpre[17];

  // init keep words (lane l < 16 holds word l)
  u64 klane = 0ull;
  for (int w = 0; w < 16; w++) {
    float v = sscore[c * 1024 + w * 64 + lane];
    u64 bal = __ballot(v != -INFINITY);
    klane = (lane == w) ? bal : klane;
  }

  unsigned acc = 0;
  for (int w = 0; w < 16; w++) {
    // diagonal word of each row in this window (lane = row-in-window)
    u64 Rw = S[(unsigned)((w * 64 + lane) * 16 + w)];
    u64 alive = readlane64(klane, w);
    u64 F = 0ull;
    while (alive) {
      int b = __builtin_ctzll(alive);
      F |= (1ull << b);
      u64 rb = readlane64(Rw, b);
      alive &= ~(rb | (1ull << b));
    }
    if (lane == 0) { keepw[w] = F; wpre[w] = acc; }
    acc += (unsigned)__builtin_popcountll(F);
    // apply fired rows' full masks to future words (8-deep batched loads)
    const u64* base = S + (size_t)(w * 64) * 16;
    u64 ff = F;
    while (ff) {
      u64 m0 = 0, m1 = 0, m2 = 0, m3 = 0, m4 = 0, m5 = 0, m6 = 0, m7 = 0;
      int b0 = __builtin_ctzll(ff); ff &= ff - 1;
      if (lane < 16) m0 = base[(size_t)b0 * 16 + lane];
      if (ff) { int b = __builtin_ctzll(ff); ff &= ff - 1; if (lane < 16) m1 = base[(size_t)b * 16 + lane];
      if (ff) { int b2 = __builtin_ctzll(ff); ff &= ff - 1; if (lane < 16) m2 = base[(size_t)b2 * 16 + lane];
      if (ff) { int b3 = __builtin_ctzll(ff); ff &= ff - 1; if (lane < 16) m3 = base[(size_t)b3 * 16 + lane];
      if (ff) { int b4 = __builtin_ctzll(ff); ff &= ff - 1; if (lane < 16) m4 = base[(size_t)b4 * 16 + lane];
      if (ff) { int b5 = __builtin_ctzll(ff); ff &= ff - 1; if (lane < 16) m5 = base[(size_t)b5 * 16 + lane];
      if (ff) { int b6 = __builtin_ctzll(ff); ff &= ff - 1; if (lane < 16) m6 = base[(size_t)b6 * 16 + lane];
      if (ff) { int b7 = __builtin_ctzll(ff); ff &= ff - 1; if (lane < 16) m7 = base[(size_t)b7 * 16 + lane];
      }}}}}}}
      klane &= ~(m0 | m1 | m2 | m3 | m4 | m5 | m6 | m7);
    }
  }
  if (lane == 0) wpre[16] = acc;
  __syncthreads();
  const unsigned total = wpre[16];

  for (int k = lane; k < PRE; k += 64) {
    int w = k >> 6, b = k & 63;
    u64 kw = keepw[w];
    if ((kw >> b) & 1ull) {
      unsigned rank = wpre[w] + (unsigned)__popcll(kw & ((1ull << b) - 1ull));
      if (rank < MAXD) {
        int slot = c * MAXD + (int)rank;
        out_s[slot] = sscore[c * 1024 + k];
        out_id[slot] = (float)c;
        ((float4*)out_b)[slot] = sbox[c * 1024 + k];
        out_d[slot] = dist[sidx[c * 1024 + k]];
      }
    }
  }
  unsigned tk = total < MAXD ? total : MAXD;
  for (int r = (int)tk + lane; r < MAXD; r += 64) {
    int slot = c * MAXD + r;
    out_s[slot] = 0.0f;
    out_id[slot] = -1.0f;
    ((float4*)out_b)[slot] = make_float4(0.f, 0.f, 0.f, 0.f);
    out_d[slot] = 0.0f;
  }
}

// =====================================================================
// FALLBACK PATH (round-1, proven correct; used only if ws is too small)
// =====================================================================
#define NBUCK 4096
#define CANDF 2048

__global__ __launch_bounds__(256) void select_topk(
    const float* __restrict__ cls, int A,
    float* __restrict__ topscore, unsigned* __restrict__ topidx)
{
  const int c = blockIdx.x;
  const int t = threadIdx.x;
  __shared__ unsigned hist[NBUCK];
  __shared__ u64 cand[CANDF];
  __shared__ unsigned chunk[256];
  __shared__ int s_cb;
  __shared__ int s_cnt;
  for (int i = t; i < NBUCK; i += 256) hist[i] = 0u;
  if (t == 0) s_cnt = 0;
  __syncthreads();
  for (int a = t; a < A; a += 256) {
    float s = cls[(size_t)a * NCLS + c];
    if (s > THR_SCORE) {
      int b = (int)(s * (float)NBUCK);
      b = b < 0 ? 0 : (b > NBUCK - 1 ? NBUCK - 1 : b);
      atomicAdd(&hist[b], 1u);
    }
  }
  __syncthreads();
  {
    unsigned cs = 0;
    for (int i = 0; i < NBUCK / 256; i++) cs += hist[t * (NBUCK / 256) + i];
    chunk[t] = cs;
  }
  __syncthreads();
  if (t == 0) {
    unsigned acc = 0;
    int cb = 0;
    int ch;
    for (ch = 255; ch >= 0; ch--) {
      if (acc + chunk[ch] >= (unsigned)PRE) break;
      acc += chunk[ch];
    }
    if (ch < 0) cb = 0;
    else {
      const int bpc = NBUCK / 256;
      int b = ch * bpc + bpc - 1;
      for (; b >= ch * bpc; b--) { acc += hist[b]; if (acc >= (unsigned)PRE) break; }
      if (b < ch * bpc) b = ch * bpc;
      cb = b;
      while (acc > (unsigned)CANDF && cb < NBUCK - 1) { acc -= hist[cb]; cb++; }
    }
    s_cb = cb;
  }
  __syncthreads();
  const int cb = s_cb;
  for (int a = t; a < A; a += 256) {
    float s = cls[(size_t)a * NCLS + c];
    if (s > THR_SCORE) {
      int b = (int)(s * (float)NBUCK);
      b = b < 0 ? 0 : (b > NBUCK - 1 ? NBUCK - 1 : b);
      if (b >= cb) {
        int p = atomicAdd(&s_cnt, 1);
        if (p < CANDF)
          cand[p] = ((u64)__float_as_uint(s) << 32) | (u64)(~(unsigned)a);
      }
    }
  }
  __syncthreads();
  int n = s_cnt < CANDF ? s_cnt : CANDF;
  for (int i = n + t; i < CANDF; i += 256) cand[i] = 0ull;
  __syncthreads();
  for (int k = 2; k <= CANDF; k <<= 1) {
    for (int j = k >> 1; j > 0; j >>= 1) {
      for (int i = t; i < CANDF; i += 256) {
        int ixj = i ^ j;
        if (ixj > i) {
          u64 va = cand[i], vb = cand[ixj];
          bool desc = ((i & k) == 0);
          if (desc ? (va < vb) : (va > vb)) { cand[i] = vb; cand[ixj] = va; }
        }
      }
      __syncthreads();
    }
  }
  for (int k = t; k < PRE; k += 256) {
    u64 key = cand[k];
    float sc; unsigned idx;
    if (key != 0ull) { sc = __uint_as_float((unsigned)(key >> 32)); idx = ~((unsigned)(key & 0xFFFFFFFFull)); }
    else { sc = -INFINITY; idx = 0u; }
    topscore[c * PRE + k] = sc;
    topidx[c * PRE + k] = idx;
  }
}

__global__ __launch_bounds__(256) void nms_out(
    const float* __restrict__ anch, const float* __restrict__ reg,
    const float* __restrict__ dist,
    const float* __restrict__ topscore, const unsigned* __restrict__ topidx,
    const int* __restrict__ img_h_p, const int* __restrict__ img_w_p,
    float* __restrict__ out_s, float* __restrict__ out_id,
    float* __restrict__ out_b, float* __restrict__ out_d)
{
#pragma clang fp contract(off)
  const int c = blockIdx.x;
  const int t = threadIdx.x;
  __shared__ float bx[PRE], by[PRE], bX[PRE], bY[PRE], bar[PRE], ssc[PRE];
  __shared__ u64 supm[PRE * 16];
  __shared__ u64 keepw[16];
  __shared__ unsigned wpre[17];
  const float W = (float)img_w_p[0];
  const float H = (float)img_h_p[0];
  for (int k = t; k < PRE; k += 256) {
    float sc = topscore[c * PRE + k];
    unsigned idx = topidx[c * PRE + k];
    ssc[k] = sc;
    float a0 = anch[(size_t)idx * 4 + 0], a1 = anch[(size_t)idx * 4 + 1];
    float a2 = anch[(size_t)idx * 4 + 2], a3 = anch[(size_t)idx * 4 + 3];
    float r0 = reg[(size_t)idx * 4 + 0], r1 = reg[(size_t)idx * 4 + 1];
    float r2 = reg[(size_t)idx * 4 + 2], r3 = reg[(size_t)idx * 4 + 3];
    float w = a2 - a0, h = a3 - a1;
    float cx = a0 + 0.5f * w, cy = a1 + 0.5f * h;
    float dx = r0 * 0.1f, dy = r1 * 0.1f, dw = r2 * 0.2f, dh = r3 * 0.2f;
    float pcx = cx + dx * w, pcy = cy + dy * h;
    float pw = (float)exp((double)dw) * w;
    float ph = (float)exp((double)dh) * h;
    float x1 = fminf(fmaxf(pcx - 0.5f * pw, 0.0f), W);
    float y1 = fminf(fmaxf(pcy - 0.5f * ph, 0.0f), H);
    float x2 = fminf(fmaxf(pcx + 0.5f * pw, 0.0f), W);
    float y2 = fminf(fmaxf(pcy + 0.5f * ph, 0.0f), H);
    bx[k] = x1; by[k] = y1; bX[k] = x2; bY[k] = y2;
    bar[k] = (x2 - x1) * (y2 - y1);
  }
  __syncthreads();
  const int wave = t >> 6, lane = t & 63;
  for (int i = wave; i < PRE; i += 4) {
    float x1 = bx[i], y1 = by[i], X1 = bX[i], Y1 = bY[i], ai = bar[i];
    for (int g = 0; g < 16; g++) {
      int j = g * 64 + lane;
      bool s = false;
      if (j > i && j < PRE) {
        float ltx = fmaxf(x1, bx[j]);
        float lty = fmaxf(y1, by[j]);
        float rbx = fminf(X1, bX[j]);
        float rby = fminf(Y1, bY[j]);
        float ww = fmaxf(rbx - ltx, 0.0f);
        float hh = fmaxf(rby - lty, 0.0f);
        float inter = ww * hh;
        float iou = inter / ((ai + bar[j]) - inter + 1e-8f);
        s = iou > 0.5f;
      }
      u64 m = __ballot(s);
      if (lane == 0) supm[i * 16 + g] = m;
    }
  }
  __syncthreads();
  if (t < 64) {
    u64 kw = 0ull;
    if (t < 16) {
      for (int b = 0; b < 64; b++) {
        int k = t * 64 + b;
        if (k < PRE && ssc[k] != -INFINITY) kw |= (1ull << b);
      }
    }
    for (int i = 0; i < PRE; i++) {
      u64 ow = __shfl(kw, i >> 6);
      if ((ow >> (i & 63)) & 1ull) {
        if (t < 16) kw &= ~supm[i * 16 + t];
      }
    }
    if (t < 16) keepw[t] = kw;
  }
  __syncthreads();
  if (t == 0) {
    unsigned acc = 0;
    for (int w = 0; w < 16; w++) { wpre[w] = acc; acc += (unsigned)__popcll(keepw[w]); }
    wpre[16] = acc;
  }
  __syncthreads();
  const unsigned total = wpre[16];
  for (int k = t; k < PRE; k += 256) {
    int w = k >> 6, b = k & 63;
    u64 kw = keepw[w];
    if ((kw >> b) & 1ull) {
      unsigned rank = wpre[w] + (unsigned)__popcll(kw & ((1ull << b) - 1ull));
      if (rank < MAXD) {
        int slot = c * MAXD + (int)rank;
        out_s[slot] = ssc[k];
        out_id[slot] = (float)c;
        out_b[slot * 4 + 0] = bx[k];
        out_b[slot * 4 + 1] = by[k];
        out_b[slot * 4 + 2] = bX[k];
        out_b[slot * 4 + 3] = bY[k];
        out_d[slot] = dist[topidx[c * PRE + k]];
      }
    }
  }
  unsigned tk = total < MAXD ? total : MAXD;
  for (int r = (int)tk + t; r < MAXD; r += 256) {
    int slot = c * MAXD + r;
    out_s[slot] = 0.0f;
    out_id[slot] = -1.0f;
    out_b[slot * 4 + 0] = 0.0f; out_b[slot * 4 + 1] = 0.0f;
    out_b[slot * 4 + 2] = 0.0f; out_b[slot * 4 + 3] = 0.0f;
    out_d[slot] = 0.0f;
  }
}

// =====================================================================

static inline size_t align512(size_t x) { return (x + 511) & ~(size_t)511; }

extern "C" void kernel_launch(void* const* d_in, const int* in_sizes, int n_in,
                              void* d_out, int out_size, void* d_ws, size_t ws_size,
                              hipStream_t stream) {
  const float* cls  = (const float*)d_in[0];   // (1, A, 80)
  const float* reg  = (const float*)d_in[1];   // (1, A, 4)
  const float* dist = (const float*)d_in[2];   // (1, A, 1)
  const float* anch = (const float*)d_in[3];   // (1, A, 4)
  const int* img_h  = (const int*)d_in[4];
  const int* img_w  = (const int*)d_in[5];
  const int A = in_sizes[3] / 4;

  float* o = (float*)d_out;
  float* out_s  = o;                      // 8000
  float* out_id = o + NCLS * MAXD;        // 8000
  float* out_b  = o + 2 * NCLS * MAXD;    // 32000
  float* out_d  = o + 6 * NCLS * MAXD;    // 8000

  // big region serves sequentially: part (k1->k2), cand (k3->kA), supm (kB->kC)
  const size_t sz_part = (size_t)K1B * BINS * sizeof(unsigned short);        // 10.49 MB
  const size_t sz_cand = (size_t)NCLS * SUBS * SUBCAP * sizeof(u64);         // 5.24 MB
  const size_t sz_supm = (size_t)NCLS * SUPM_STRIDE * sizeof(u64);           // 10.49 MB
  size_t sz_big = sz_part;
  if (sz_cand > sz_big) sz_big = sz_cand;
  if (sz_supm > sz_big) sz_big = sz_supm;
  size_t off = align512(sz_big);
  const size_t o_cb    = off; off += align512(NCLS * sizeof(int));
  const size_t o_ccnt  = off; off += align512((size_t)NCLS * SUBS * sizeof(unsigned));
  const size_t o_sbox  = off; off += align512((size_t)NCLS * 1024 * sizeof(float4));
  const size_t o_sarea = off; off += align512((size_t)NCLS * 1024 * sizeof(float));
  const size_t o_sscr  = off; off += align512((size_t)NCLS * 1024 * sizeof(float));
  const size_t o_sidx  = off; off += align512((size_t)NCLS * 1024 * sizeof(unsigned));
  const size_t needed = off;

  if (ws_size >= needed) {
    char* ws = (char*)d_ws;
    unsigned short* part = (unsigned short*)ws;
    u64* cand = (u64*)ws;
    u64* supm = (u64*)ws;
    int* cb = (int*)(ws + o_cb);
    unsigned* ccnt = (unsigned*)(ws + o_ccnt);
    float4* sbox = (float4*)(ws + o_sbox);
    float* sarea = (float*)(ws + o_sarea);
    float* sscr = (float*)(ws + o_sscr);
    unsigned* sidxp = (unsigned*)(ws + o_sidx);
    const int total4 = A * 20;  // A*80/4

    k1_hist<<<K1B, 256, 0, stream>>>((const float4*)cls, total4, part);
    k2_cutoff<<<NCLS, 256, 0, stream>>>(part, cb, ccnt);
    k3_collect<<<256, 256, 0, stream>>>((const float4*)cls, total4, cb, ccnt, cand);
    kA_sort_decode<<<NCLS, 1024, 0, stream>>>(ccnt, cand, anch, reg, img_h, img_w,
                                              sbox, sarea, sscr, sidxp);
    kB_build<<<NCLS * RS, 256, 0, stream>>>(sbox, sarea, supm);
    kC_scan_out<<<NCLS, 64, 0, stream>>>(supm, sbox, sscr, sidxp, dist,
                                         out_s, out_id, out_b, out_d);
  } else {
    // fallback: proven round-1 path (needs only ~0.64 MB)
    float* topscore = (float*)d_ws;
    unsigned* topidx = (unsigned*)((char*)d_ws + NCLS * PRE * sizeof(float));
    select_topk<<<NCLS, 256, 0, stream>>>(cls, A, topscore, topidx);
    nms_out<<<NCLS, 256, 0, stream>>>(anch, reg, dist, topscore, topidx,
                                      img_h, img_w, out_s, out_id, out_b, out_d);
  }
}

// Round 5
// 276.194 us; speedup vs baseline: 4.3664x; 1.0662x over previous
//
#include <hip/hip_runtime.h>
#include <math.h>

#define NCLS 80
#define PRE 1000
#define MAXD 100
#define THR_SCORE 0.05f

// ---- fast path config ----
#define NB 256                 // buckets per class
#define BINS (NCLS * NB)       // 20480
#define K1B 256                // histogram blocks
#define SUBS 16                // sub-lists per class
#define SUBCAP 512             // depth per sub-list
#define CSORT 2048             // max candidates per class
#define RS 8                   // row-split blocks per class in kB
#define SUPM_STRIDE 16384      // 1024 rows x 16 words per class (padded)

typedef unsigned long long u64;

__device__ __forceinline__ u64 readlane64(u64 v, int l) {
  unsigned lo = (unsigned)__builtin_amdgcn_readlane((int)(unsigned)v, l);
  unsigned hi = (unsigned)__builtin_amdgcn_readlane((int)(unsigned)(v >> 32), l);
  return ((u64)hi << 32) | lo;
}

// =====================================================================
// K1: coalesced float4 pass over cls, per-block LDS hist (80x256), u16 partials.
__global__ __launch_bounds__(256) void k1_hist(
    const float4* __restrict__ cls4, int total4, unsigned short* __restrict__ part)
{
  __shared__ unsigned h[BINS];
  const int t = threadIdx.x;
  for (int i = t; i < BINS; i += 256) h[i] = 0u;
  __syncthreads();
  const int stride = gridDim.x * 256;
  for (int q = blockIdx.x * 256 + t; q < total4; q += stride) {
    float4 v = cls4[q];
    int c0 = 4 * (q % 20);  // (4q) % 80
    float s; int b;
    s = v.x; if (s > THR_SCORE) { b = (int)(s * (float)NB); b = b < 0 ? 0 : (b > NB - 1 ? NB - 1 : b); atomicAdd(&h[(c0 + 0) * NB + b], 1u); }
    s = v.y; if (s > THR_SCORE) { b = (int)(s * (float)NB); b = b < 0 ? 0 : (b > NB - 1 ? NB - 1 : b); atomicAdd(&h[(c0 + 1) * NB + b], 1u); }
    s = v.z; if (s > THR_SCORE) { b = (int)(s * (float)NB); b = b < 0 ? 0 : (b > NB - 1 ? NB - 1 : b); atomicAdd(&h[(c0 + 2) * NB + b], 1u); }
    s = v.w; if (s > THR_SCORE) { b = (int)(s * (float)NB); b = b < 0 ? 0 : (b > NB - 1 ? NB - 1 : b); atomicAdd(&h[(c0 + 3) * NB + b], 1u); }
  }
  __syncthreads();
  unsigned short* p = part + (size_t)blockIdx.x * BINS;
  for (int i = t; i < BINS; i += 256) p[i] = (unsigned short)h[i];
}

// K2: one block per class; reduce 256 partials -> cutoff bucket; zero counters.
__global__ __launch_bounds__(256) void k2_cutoff(
    const unsigned short* __restrict__ part, int* __restrict__ cb,
    unsigned* __restrict__ ccnt)
{
  const int c = blockIdx.x;
  const int t = threadIdx.x;
  __shared__ unsigned lh[NB];
  unsigned acc = 0;
  for (int p = 0; p < K1B; p++) acc += part[(size_t)p * BINS + c * NB + t];
  lh[t] = acc;
  if (t < SUBS) ccnt[c * SUBS + t] = 0u;
  __syncthreads();
  if (t == 0) {
    unsigned a = 0;
    int cbv = 0;
    for (int b = NB - 1; b >= 0; b--) {
      a += lh[b];
      if (a >= (unsigned)PRE) { cbv = b; break; }
    }
    while (a > (unsigned)CSORT && cbv < NB - 1) { a -= lh[cbv]; cbv++; }
    cb[c] = cbv;
  }
}

// K3: coalesced pass; push candidates above per-class cutoff into sub-lists.
__global__ __launch_bounds__(256) void k3_collect(
    const float4* __restrict__ cls4, int total4, const int* __restrict__ cb,
    unsigned* __restrict__ ccnt, u64* __restrict__ cand)
{
  __shared__ int scb[NCLS];
  const int t = threadIdx.x;
  if (t < NCLS) scb[t] = cb[t];
  __syncthreads();
  const int sub = blockIdx.x & (SUBS - 1);
  const int stride = gridDim.x * 256;
  for (int q = blockIdx.x * 256 + t; q < total4; q += stride) {
    float4 v = cls4[q];
    int c0 = 4 * (q % 20);
    unsigned a = (unsigned)(q / 20);
    float sv[4] = {v.x, v.y, v.z, v.w};
#pragma unroll
    for (int e = 0; e < 4; e++) {
      float s = sv[e];
      if (s > THR_SCORE) {
        int b = (int)(s * (float)NB);
        b = b < 0 ? 0 : (b > NB - 1 ? NB - 1 : b);
        int c = c0 + e;
        if (b >= scb[c]) {
          unsigned p = atomicAdd(&ccnt[c * SUBS + sub], 1u);
          if (p < SUBCAP)
            cand[((size_t)(c * SUBS + sub)) * SUBCAP + p] =
                ((u64)__float_as_uint(s) << 32) | (u64)(~a);
        }
      }
    }
  }
}

// kA: per-class gather + refine-to-1024 + bitonic sort + decode.
__global__ __launch_bounds__(1024) void kA_sort_decode(
    const unsigned* __restrict__ ccnt, const u64* __restrict__ cand,
    const int* __restrict__ cbp,
    const float* __restrict__ anch, const float* __restrict__ reg,
    const int* __restrict__ img_h_p, const int* __restrict__ img_w_p,
    float4* __restrict__ sbox, float* __restrict__ sarea,
    float* __restrict__ sscore, unsigned* __restrict__ sidx)
{
#pragma clang fp contract(off)
  const int c = blockIdx.x;
  const int t = threadIdx.x;
  __shared__ u64 L[CSORT];
  __shared__ u64 M[1024];
  __shared__ unsigned sbase[SUBS];
  __shared__ unsigned h2[256];
  __shared__ unsigned s_above;
  __shared__ int s_rsub;
  __shared__ unsigned s_n2;
  __shared__ unsigned s_push;
  __shared__ unsigned s_n;

  if (t == 0) {
    unsigned a = 0;
    for (int s = 0; s < SUBS; s++) {
      unsigned n = ccnt[c * SUBS + s];
      if (n > SUBCAP) n = SUBCAP;
      sbase[s] = a;
      a += n;
    }
    s_n = a;
    s_above = 0;
    s_push = 0;
  }
  for (int i = t; i < CSORT; i += 1024) L[i] = 0ull;
  if (t < 1024) M[t] = 0ull;
  if (t < 256) h2[t] = 0u;
  __syncthreads();
  for (int s = 0; s < SUBS; s++) {
    unsigned n = ccnt[c * SUBS + s];
    if (n > SUBCAP) n = SUBCAP;
    unsigned bs = sbase[s];
    for (unsigned i = t; i < n; i += 1024) {
      unsigned d = bs + i;
      if (d < CSORT) L[d] = cand[((size_t)(c * SUBS + s)) * SUBCAP + i];
    }
  }
  __syncthreads();

  const unsigned n = s_n <= CSORT ? s_n : CSORT;
  const int scb = cbp[c];
  const u64* SA = L;
  int SS = CSORT;

  if (n <= 1024) {
    SS = 1024;
  } else {
    // refine: sub-bucket histogram of cutoff-bucket elements
    for (unsigned i = t; i < n; i += 1024) {
      float s = __uint_as_float((unsigned)(L[i] >> 32));
      int b = (int)(s * (float)NB);
      b = b < 0 ? 0 : (b > NB - 1 ? NB - 1 : b);
      if (b > scb) {
        atomicAdd(&s_above, 1u);
      } else {
        int sub = (int)(s * 65536.0f) - scb * 256;
        sub = sub < 0 ? 0 : (sub > 255 ? 255 : sub);
        atomicAdd(&h2[sub], 1u);
      }
    }
    __syncthreads();
    if (t == 0) {
      unsigned a = s_above;
      int r = 256;  // if already >= PRE with no cutoff-bucket elems (can't happen: n>=a)
      if (a >= (unsigned)PRE) {
        r = 256;
      } else {
        for (int b2 = 255; b2 >= 0; b2--) {
          a += h2[b2];
          if (a >= (unsigned)PRE) { r = b2; break; }
        }
        if (a < (unsigned)PRE) r = 0;  // take all
      }
      s_rsub = r;
      s_n2 = a;
    }
    __syncthreads();
    if (s_n2 <= 1024u) {
      const int rsub = s_rsub;
      for (unsigned i = t; i < n; i += 1024) {
        u64 key = L[i];
        float s = __uint_as_float((unsigned)(key >> 32));
        int b = (int)(s * (float)NB);
        b = b < 0 ? 0 : (b > NB - 1 ? NB - 1 : b);
        bool take;
        if (b > scb) take = true;
        else {
          int sub = (int)(s * 65536.0f) - scb * 256;
          sub = sub < 0 ? 0 : (sub > 255 ? 255 : sub);
          take = (sub >= rsub);
        }
        if (take) {
          unsigned p = atomicAdd(&s_push, 1u);
          if (p < 1024u) M[p] = key;
        }
      }
      __syncthreads();
      SA = M;
      SS = 1024;
    }
  }

  // bitonic sort descending over SA[0..SS)
  u64* SW = (u64*)SA;
  for (int k = 2; k <= SS; k <<= 1) {
    for (int j = k >> 1; j > 0; j >>= 1) {
      for (int i = t; i < SS; i += 1024) {
        int ixj = i ^ j;
        if (ixj > i) {
          u64 va = SW[i], vb = SW[ixj];
          bool desc = ((i & k) == 0);
          if (desc ? (va < vb) : (va > vb)) { SW[i] = vb; SW[ixj] = va; }
        }
      }
      __syncthreads();
    }
  }

  // decode entry t (1024 threads, 1024 slots)
  const float W = (float)img_w_p[0];
  const float H = (float)img_h_p[0];
  const float4* a4 = (const float4*)anch;
  const float4* r4 = (const float4*)reg;
  const int k = t;
  if (k < PRE) {
    u64 key = SW[k];
    float sc; unsigned idx;
    if (key != 0ull) {
      sc = __uint_as_float((unsigned)(key >> 32));
      idx = ~((unsigned)(key & 0xFFFFFFFFull));
    } else {
      sc = -INFINITY; idx = 0u;
    }
    float4 av = a4[idx];
    float4 rv = r4[idx];
    float w = av.z - av.x, h = av.w - av.y;
    float cx = av.x + 0.5f * w, cy = av.y + 0.5f * h;
    float dx = rv.x * 0.1f, dy = rv.y * 0.1f, dw = rv.z * 0.2f, dh = rv.w * 0.2f;
    float pcx = cx + dx * w, pcy = cy + dy * h;
    float pw = (float)exp((double)dw) * w;
    float ph = (float)exp((double)dh) * h;
    float x1 = fminf(fmaxf(pcx - 0.5f * pw, 0.0f), W);
    float y1 = fminf(fmaxf(pcy - 0.5f * ph, 0.0f), H);
    float x2 = fminf(fmaxf(pcx + 0.5f * pw, 0.0f), W);
    float y2 = fminf(fmaxf(pcy + 0.5f * ph, 0.0f), H);
    sbox[c * 1024 + k] = make_float4(x1, y1, x2, y2);
    sarea[c * 1024 + k] = (x2 - x1) * (y2 - y1);
    sscore[c * 1024 + k] = sc;
    sidx[c * 1024 + k] = idx;
  } else {
    sbox[c * 1024 + k] = make_float4(0.f, 0.f, 0.f, 0.f);
    sarea[c * 1024 + k] = 0.f;
    sscore[c * 1024 + k] = -INFINITY;
    sidx[c * 1024 + k] = 0u;
  }
}

// kB: supm build spread over RS blocks per class; columns in registers.
__global__ __launch_bounds__(256) void kB_build(
    const float4* __restrict__ sbox, const float* __restrict__ sarea,
    u64* __restrict__ supm)
{
#pragma clang fp contract(off)
  const int c = blockIdx.x >> 3;       // RS = 8
  const int r = blockIdx.x & (RS - 1);
  const int t = threadIdx.x;
  __shared__ float4 box4[1024];
  __shared__ float area[1024];
  for (int i = t; i < 1024; i += 256) {
    box4[i] = sbox[c * 1024 + i];
    area[i] = sarea[c * 1024 + i];
  }
  __syncthreads();
  const int wave = t >> 6, lane = t & 63;
  float4 cbx[16];
  float car[16];
#pragma unroll
  for (int g = 0; g < 16; g++) {
    cbx[g] = box4[g * 64 + lane];
    car[g] = area[g * 64 + lane];
  }
  u64* S = supm + (size_t)c * SUPM_STRIDE;
  // exact: fl32(inter/denom) > 0.5f  <=>  (double)inter > 0.5*(1+2^-24)*(double)denom
  const double MID = 0x1.000001p-1;
  for (int i = r * 4 + wave; i < PRE; i += 32) {
    float4 rb = box4[i];
    float ra = area[i];
    const int g0 = i >> 6;
    const int ib = i & 63;
    u64 mrow = 0ull;
#pragma unroll
    for (int g = 0; g < 16; g++) {
      if (g < g0) continue;
      float ltx = fmaxf(rb.x, cbx[g].x);
      float lty = fmaxf(rb.y, cbx[g].y);
      float rbx = fminf(rb.z, cbx[g].z);
      float rby = fminf(rb.w, cbx[g].w);
      float ww = fmaxf(rbx - ltx, 0.0f);
      float hh = fmaxf(rby - lty, 0.0f);
      float inter = ww * hh;
      float denom = ((ra + car[g]) - inter) + 1e-8f;
      bool io = (double)inter > MID * (double)denom;
      bool pred = (g > g0) | (lane > ib);
      bool inb = (g < 15) | (lane < PRE - 15 * 64);
      u64 m = __ballot(io & pred & inb);
      mrow = (lane == g) ? m : mrow;
    }
    if (lane < 16) S[i * 16 + lane] = mrow;
  }
}

// kC: stage per-class supm in LDS, then exact serial scan (wave 0) + output.
__global__ __launch_bounds__(512, 1) void kC_scan_out(
    const u64* __restrict__ supm, const float4* __restrict__ sbox,
    const float* __restrict__ sscore, const unsigned* __restrict__ sidx,
    const float* __restrict__ dist,
    float* __restrict__ out_s, float* __restrict__ out_id,
    float* __restrict__ out_b, float* __restrict__ out_d)
{
  const int c = blockIdx.x;
  const int t = threadIdx.x;
  __shared__ u64 ls[PRE * 16 + 384];   // 16384 words = 128 KB (padded to 1024 rows)
  __shared__ u64 keepw[16];
  __shared__ unsigned wpre[17];

  // stage supm -> LDS (16 iterations of 16B per thread)
  {
    const ulonglong2* S2 = (const ulonglong2*)(supm + (size_t)c * SUPM_STRIDE);
    ulonglong2* D2 = (ulonglong2*)ls;
    for (int i = t; i < SUPM_STRIDE / 2; i += 512) D2[i] = S2[i];
  }
  __syncthreads();

  if (t < 64) {
    const int lane = t;
    // init keep words (lane l < 16 holds word l)
    u64 klane = 0ull;
    for (int w = 0; w < 16; w++) {
      float v = sscore[c * 1024 + w * 64 + lane];
      u64 bal = __ballot(v != -INFINITY);
      klane = (lane == w) ? bal : klane;
    }

    unsigned acc = 0;
    for (int w = 0; w < 16; w++) {
      // diagonal word of each row in this window (lane = row-in-window)
      u64 Rw = ls[(unsigned)((w * 64 + lane) * 16 + w)];
      u64 alive = readlane64(klane, w);
      u64 F = 0ull;
      while (alive) {
        int b = __builtin_ctzll(alive);
        F |= (1ull << b);
        u64 rb = readlane64(Rw, b);
        alive &= ~(rb | (1ull << b));
      }
      if (lane == 0) { keepw[w] = F; wpre[w] = acc; }
      acc += (unsigned)__builtin_popcountll(F);
      // apply fired rows' full masks to future words (8-deep batched LDS loads)
      const u64* base = ls + (size_t)(w * 64) * 16;
      u64 ff = F;
      while (ff) {
        u64 m0 = 0, m1 = 0, m2 = 0, m3 = 0, m4 = 0, m5 = 0, m6 = 0, m7 = 0;
        int b0 = __builtin_ctzll(ff); ff &= ff - 1;
        if (lane < 16) m0 = base[(size_t)b0 * 16 + lane];
        if (ff) { int b = __builtin_ctzll(ff); ff &= ff - 1; if (lane < 16) m1 = base[(size_t)b * 16 + lane];
        if (ff) { int b2 = __builtin_ctzll(ff); ff &= ff - 1; if (lane < 16) m2 = base[(size_t)b2 * 16 + lane];
        if (ff) { int b3 = __builtin_ctzll(ff); ff &= ff - 1; if (lane < 16) m3 = base[(size_t)b3 * 16 + lane];
        if (ff) { int b4 = __builtin_ctzll(ff); ff &= ff - 1; if (lane < 16) m4 = base[(size_t)b4 * 16 + lane];
        if (ff) { int b5 = __builtin_ctzll(ff); ff &= ff - 1; if (lane < 16) m5 = base[(size_t)b5 * 16 + lane];
        if (ff) { int b6 = __builtin_ctzll(ff); ff &= ff - 1; if (lane < 16) m6 = base[(size_t)b6 * 16 + lane];
        if (ff) { int b7 = __builtin_ctzll(ff); ff &= ff - 1; if (lane < 16) m7 = base[(size_t)b7 * 16 + lane];
        }}}}}}}
        klane &= ~(m0 | m1 | m2 | m3 | m4 | m5 | m6 | m7);
      }
    }
    if (lane == 0) wpre[16] = acc;
  }
  __syncthreads();
  const unsigned total = wpre[16];

  for (int k = t; k < PRE; k += 512) {
    int w = k >> 6, b = k & 63;
    u64 kw = keepw[w];
    if ((kw >> b) & 1ull) {
      unsigned rank = wpre[w] + (unsigned)__popcll(kw & ((1ull << b) - 1ull));
      if (rank < MAXD) {
        int slot = c * MAXD + (int)rank;
        out_s[slot] = sscore[c * 1024 + k];
        out_id[slot] = (float)c;
        ((float4*)out_b)[slot] = sbox[c * 1024 + k];
        out_d[slot] = dist[sidx[c * 1024 + k]];
      }
    }
  }
  unsigned tk = total < MAXD ? total : MAXD;
  for (int r = (int)tk + t; r < MAXD; r += 512) {
    int slot = c * MAXD + r;
    out_s[slot] = 0.0f;
    out_id[slot] = -1.0f;
    ((float4*)out_b)[slot] = make_float4(0.f, 0.f, 0.f, 0.f);
    out_d[slot] = 0.0f;
  }
}

// =====================================================================
// FALLBACK PATH (round-1, proven correct; used only if ws is too small)
// =====================================================================
#define NBUCK 4096
#define CANDF 2048

__global__ __launch_bounds__(256) void select_topk(
    const float* __restrict__ cls, int A,
    float* __restrict__ topscore, unsigned* __restrict__ topidx)
{
  const int c = blockIdx.x;
  const int t = threadIdx.x;
  __shared__ unsigned hist[NBUCK];
  __shared__ u64 cand[CANDF];
  __shared__ unsigned chunk[256];
  __shared__ int s_cb;
  __shared__ int s_cnt;
  for (int i = t; i < NBUCK; i += 256) hist[i] = 0u;
  if (t == 0) s_cnt = 0;
  __syncthreads();
  for (int a = t; a < A; a += 256) {
    float s = cls[(size_t)a * NCLS + c];
    if (s > THR_SCORE) {
      int b = (int)(s * (float)NBUCK);
      b = b < 0 ? 0 : (b > NBUCK - 1 ? NBUCK - 1 : b);
      atomicAdd(&hist[b], 1u);
    }
  }
  __syncthreads();
  {
    unsigned cs = 0;
    for (int i = 0; i < NBUCK / 256; i++) cs += hist[t * (NBUCK / 256) + i];
    chunk[t] = cs;
  }
  __syncthreads();
  if (t == 0) {
    unsigned acc = 0;
    int cb = 0;
    int ch;
    for (ch = 255; ch >= 0; ch--) {
      if (acc + chunk[ch] >= (unsigned)PRE) break;
      acc += chunk[ch];
    }
    if (ch < 0) cb = 0;
    else {
      const int bpc = NBUCK / 256;
      int b = ch * bpc + bpc - 1;
      for (; b >= ch * bpc; b--) { acc += hist[b]; if (acc >= (unsigned)PRE) break; }
      if (b < ch * bpc) b = ch * bpc;
      cb = b;
      while (acc > (unsigned)CANDF && cb < NBUCK - 1) { acc -= hist[cb]; cb++; }
    }
    s_cb = cb;
  }
  __syncthreads();
  const int cb = s_cb;
  for (int a = t; a < A; a += 256) {
    float s = cls[(size_t)a * NCLS + c];
    if (s > THR_SCORE) {
      int b = (int)(s * (float)NBUCK);
      b = b < 0 ? 0 : (b > NBUCK - 1 ? NBUCK - 1 : b);
      if (b >= cb) {
        int p = atomicAdd(&s_cnt, 1);
        if (p < CANDF)
          cand[p] = ((u64)__float_as_uint(s) << 32) | (u64)(~(unsigned)a);
      }
    }
  }
  __syncthreads();
  int n = s_cnt < CANDF ? s_cnt : CANDF;
  for (int i = n + t; i < CANDF; i += 256) cand[i] = 0ull;
  __syncthreads();
  for (int k = 2; k <= CANDF; k <<= 1) {
    for (int j = k >> 1; j > 0; j >>= 1) {
      for (int i = t; i < CANDF; i += 256) {
        int ixj = i ^ j;
        if (ixj > i) {
          u64 va = cand[i], vb = cand[ixj];
          bool desc = ((i & k) == 0);
          if (desc ? (va < vb) : (va > vb)) { cand[i] = vb; cand[ixj] = va; }
        }
      }
      __syncthreads();
    }
  }
  for (int k = t; k < PRE; k += 256) {
    u64 key = cand[k];
    float sc; unsigned idx;
    if (key != 0ull) { sc = __uint_as_float((unsigned)(key >> 32)); idx = ~((unsigned)(key & 0xFFFFFFFFull)); }
    else { sc = -INFINITY; idx = 0u; }
    topscore[c * PRE + k] = sc;
    topidx[c * PRE + k] = idx;
  }
}

__global__ __launch_bounds__(256) void nms_out(
    const float* __restrict__ anch, const float* __restrict__ reg,
    const float* __restrict__ dist,
    const float* __restrict__ topscore, const unsigned* __restrict__ topidx,
    const int* __restrict__ img_h_p, const int* __restrict__ img_w_p,
    float* __restrict__ out_s, float* __restrict__ out_id,
    float* __restrict__ out_b, float* __restrict__ out_d)
{
#pragma clang fp contract(off)
  const int c = blockIdx.x;
  const int t = threadIdx.x;
  __shared__ float bx[PRE], by[PRE], bX[PRE], bY[PRE], bar[PRE], ssc[PRE];
  __shared__ u64 supm[PRE * 16];
  __shared__ u64 keepw[16];
  __shared__ unsigned wpre[17];
  const float W = (float)img_w_p[0];
  const float H = (float)img_h_p[0];
  for (int k = t; k < PRE; k += 256) {
    float sc = topscore[c * PRE + k];
    unsigned idx = topidx[c * PRE + k];
    ssc[k] = sc;
    float a0 = anch[(size_t)idx * 4 + 0], a1 = anch[(size_t)idx * 4 + 1];
    float a2 = anch[(size_t)idx * 4 + 2], a3 = anch[(size_t)idx * 4 + 3];
    float r0 = reg[(size_t)idx * 4 + 0], r1 = reg[(size_t)idx * 4 + 1];
    float r2 = reg[(size_t)idx * 4 + 2], r3 = reg[(size_t)idx * 4 + 3];
    float w = a2 - a0, h = a3 - a1;
    float cx = a0 + 0.5f * w, cy = a1 + 0.5f * h;
    float dx = r0 * 0.1f, dy = r1 * 0.1f, dw = r2 * 0.2f, dh = r3 * 0.2f;
    float pcx = cx + dx * w, pcy = cy + dy * h;
    float pw = (float)exp((double)dw) * w;
    float ph = (float)exp((double)dh) * h;
    float x1 = fminf(fmaxf(pcx - 0.5f * pw, 0.0f), W);
    float y1 = fminf(fmaxf(pcy - 0.5f * ph, 0.0f), H);
    float x2 = fminf(fmaxf(pcx + 0.5f * pw, 0.0f), W);
    float y2 = fminf(fmaxf(pcy + 0.5f * ph, 0.0f), H);
    bx[k] = x1; by[k] = y1; bX[k] = x2; bY[k] = y2;
    bar[k] = (x2 - x1) * (y2 - y1);
  }
  __syncthreads();
  const int wave = t >> 6, lane = t & 63;
  for (int i = wave; i < PRE; i += 4) {
    float x1 = bx[i], y1 = by[i], X1 = bX[i], Y1 = bY[i], ai = bar[i];
    for (int g = 0; g < 16; g++) {
      int j = g * 64 + lane;
      bool s = false;
      if (j > i && j < PRE) {
        float ltx = fmaxf(x1, bx[j]);
        float lty = fmaxf(y1, by[j]);
        float rbx = fminf(X1, bX[j]);
        float rby = fminf(Y1, bY[j]);
        float ww = fmaxf(rbx - ltx, 0.0f);
        float hh = fmaxf(rby - lty, 0.0f);
        float inter = ww * hh;
        float iou = inter / ((ai + bar[j]) - inter + 1e-8f);
        s = iou > 0.5f;
      }
      u64 m = __ballot(s);
      if (lane == 0) supm[i * 16 + g] = m;
    }
  }
  __syncthreads();
  if (t < 64) {
    u64 kw = 0ull;
    if (t < 16) {
      for (int b = 0; b < 64; b++) {
        int k = t * 64 + b;
        if (k < PRE && ssc[k] != -INFINITY) kw |= (1ull << b);
      }
    }
    for (int i = 0; i < PRE; i++) {
      u64 ow = __shfl(kw, i >> 6);
      if ((ow >> (i & 63)) & 1ull) {
        if (t < 16) kw &= ~supm[i * 16 + t];
      }
    }
    if (t < 16) keepw[t] = kw;
  }
  __syncthreads();
  if (t == 0) {
    unsigned acc = 0;
    for (int w = 0; w < 16; w++) { wpre[w] = acc; acc += (unsigned)__popcll(keepw[w]); }
    wpre[16] = acc;
  }
  __syncthreads();
  const unsigned total = wpre[16];
  for (int k = t; k < PRE; k += 256) {
    int w = k >> 6, b = k & 63;
    u64 kw = keepw[w];
    if ((kw >> b) & 1ull) {
      unsigned rank = wpre[w] + (unsigned)__popcll(kw & ((1ull << b) - 1ull));
      if (rank < MAXD) {
        int slot = c * MAXD + (int)rank;
        out_s[slot] = ssc[k];
        out_id[slot] = (float)c;
        out_b[slot * 4 + 0] = bx[k];
        out_b[slot * 4 + 1] = by[k];
        out_b[slot * 4 + 2] = bX[k];
        out_b[slot * 4 + 3] = bY[k];
        out_d[slot] = dist[topidx[c * PRE + k]];
      }
    }
  }
  unsigned tk = total < MAXD ? total : MAXD;
  for (int r = (int)tk + t; r < MAXD; r += 256) {
    int slot = c * MAXD + r;
    out_s[slot] = 0.0f;
    out_id[slot] = -1.0f;
    out_b[slot * 4 + 0] = 0.0f; out_b[slot * 4 + 1] = 0.0f;
    out_b[slot * 4 + 2] = 0.0f; out_b[slot * 4 + 3] = 0.0f;
    out_d[slot] = 0.0f;
  }
}

// =====================================================================

static inline size_t align512(size_t x) { return (x + 511) & ~(size_t)511; }

extern "C" void kernel_launch(void* const* d_in, const int* in_sizes, int n_in,
                              void* d_out, int out_size, void* d_ws, size_t ws_size,
                              hipStream_t stream) {
  const float* cls  = (const float*)d_in[0];   // (1, A, 80)
  const float* reg  = (const float*)d_in[1];   // (1, A, 4)
  const float* dist = (const float*)d_in[2];   // (1, A, 1)
  const float* anch = (const float*)d_in[3];   // (1, A, 4)
  const int* img_h  = (const int*)d_in[4];
  const int* img_w  = (const int*)d_in[5];
  const int A = in_sizes[3] / 4;

  float* o = (float*)d_out;
  float* out_s  = o;                      // 8000
  float* out_id = o + NCLS * MAXD;        // 8000
  float* out_b  = o + 2 * NCLS * MAXD;    // 32000
  float* out_d  = o + 6 * NCLS * MAXD;    // 8000

  // big region serves sequentially: part (k1->k2), cand (k3->kA), supm (kB->kC)
  const size_t sz_part = (size_t)K1B * BINS * sizeof(unsigned short);        // 10.49 MB
  const size_t sz_cand = (size_t)NCLS * SUBS * SUBCAP * sizeof(u64);         // 5.24 MB
  const size_t sz_supm = (size_t)NCLS * SUPM_STRIDE * sizeof(u64);           // 10.49 MB
  size_t sz_big = sz_part;
  if (sz_cand > sz_big) sz_big = sz_cand;
  if (sz_supm > sz_big) sz_big = sz_supm;
  size_t off = align512(sz_big);
  const size_t o_cb    = off; off += align512(NCLS * sizeof(int));
  const size_t o_ccnt  = off; off += align512((size_t)NCLS * SUBS * sizeof(unsigned));
  const size_t o_sbox  = off; off += align512((size_t)NCLS * 1024 * sizeof(float4));
  const size_t o_sarea = off; off += align512((size_t)NCLS * 1024 * sizeof(float));
  const size_t o_sscr  = off; off += align512((size_t)NCLS * 1024 * sizeof(float));
  const size_t o_sidx  = off; off += align512((size_t)NCLS * 1024 * sizeof(unsigned));
  const size_t needed = off;

  if (ws_size >= needed) {
    char* ws = (char*)d_ws;
    unsigned short* part = (unsigned short*)ws;
    u64* cand = (u64*)ws;
    u64* supm = (u64*)ws;
    int* cb = (int*)(ws + o_cb);
    unsigned* ccnt = (unsigned*)(ws + o_ccnt);
    float4* sbox = (float4*)(ws + o_sbox);
    float* sarea = (float*)(ws + o_sarea);
    float* sscr = (float*)(ws + o_sscr);
    unsigned* sidxp = (unsigned*)(ws + o_sidx);
    const int total4 = A * 20;  // A*80/4

    k1_hist<<<K1B, 256, 0, stream>>>((const float4*)cls, total4, part);
    k2_cutoff<<<NCLS, 256, 0, stream>>>(part, cb, ccnt);
    k3_collect<<<256, 256, 0, stream>>>((const float4*)cls, total4, cb, ccnt, cand);
    kA_sort_decode<<<NCLS, 1024, 0, stream>>>(ccnt, cand, cb, anch, reg, img_h, img_w,
                                              sbox, sarea, sscr, sidxp);
    kB_build<<<NCLS * RS, 256, 0, stream>>>(sbox, sarea, supm);
    kC_scan_out<<<NCLS, 512, 0, stream>>>(supm, sbox, sscr, sidxp, dist,
                                          out_s, out_id, out_b, out_d);
  } else {
    // fallback: proven round-1 path (needs only ~0.64 MB)
    float* topscore = (float*)d_ws;
    unsigned* topidx = (unsigned*)((char*)d_ws + NCLS * PRE * sizeof(float));
    select_topk<<<NCLS, 256, 0, stream>>>(cls, A, topscore, topidx);
    nms_out<<<NCLS, 256, 0, stream>>>(anch, reg, dist, topscore, topidx,
                                      img_h, img_w, out_s, out_id, out_b, out_d);
  }
}

// Round 6
// 263.385 us; speedup vs baseline: 4.5788x; 1.0486x over previous
//
#include <hip/hip_runtime.h>
#include <math.h>

#define NCLS 80
#define PRE 1000
#define MAXD 100
#define THR_SCORE 0.05f

// ---- fast path config ----
#define NB 128                 // buckets per class (coarse; refined in kA)
#define BINS (NCLS * NB)       // 10240
#define K1B 512                // histogram blocks (= partial count)
#define SUBS 16                // sub-lists per class
#define SUBCAP 512             // depth per sub-list
#define CSORT 4096             // max candidates per class
#define RS 8                   // row-split blocks per class in kB
#define SUPM_STRIDE 16384      // 1024 rows x 16 words per class (padded)
#define K3B 2048               // collect blocks

typedef unsigned long long u64;

__device__ __forceinline__ u64 readlane64(u64 v, int l) {
  unsigned lo = (unsigned)__builtin_amdgcn_readlane((int)(unsigned)v, l);
  unsigned hi = (unsigned)__builtin_amdgcn_readlane((int)(unsigned)(v >> 32), l);
  return ((u64)hi << 32) | lo;
}

// =====================================================================
// K1: coalesced float4 pass over cls, per-block LDS hist (80x128), u16 partials.
__global__ __launch_bounds__(256) void k1_hist(
    const float4* __restrict__ cls4, int total4, unsigned short* __restrict__ part)
{
  __shared__ unsigned h[BINS];
  const int t = threadIdx.x;
  for (int i = t; i < BINS; i += 256) h[i] = 0u;
  __syncthreads();
  const int stride = gridDim.x * 256;
  for (int q = blockIdx.x * 256 + t; q < total4; q += stride) {
    float4 v = cls4[q];
    int c0 = 4 * (q % 20);  // (4q) % 80
    float s; int b;
    s = v.x; if (s > THR_SCORE) { b = (int)(s * (float)NB); b = b < 0 ? 0 : (b > NB - 1 ? NB - 1 : b); atomicAdd(&h[(c0 + 0) * NB + b], 1u); }
    s = v.y; if (s > THR_SCORE) { b = (int)(s * (float)NB); b = b < 0 ? 0 : (b > NB - 1 ? NB - 1 : b); atomicAdd(&h[(c0 + 1) * NB + b], 1u); }
    s = v.z; if (s > THR_SCORE) { b = (int)(s * (float)NB); b = b < 0 ? 0 : (b > NB - 1 ? NB - 1 : b); atomicAdd(&h[(c0 + 2) * NB + b], 1u); }
    s = v.w; if (s > THR_SCORE) { b = (int)(s * (float)NB); b = b < 0 ? 0 : (b > NB - 1 ? NB - 1 : b); atomicAdd(&h[(c0 + 3) * NB + b], 1u); }
  }
  __syncthreads();
  unsigned short* p = part + (size_t)blockIdx.x * BINS;
  for (int i = t; i < BINS; i += 256) p[i] = (unsigned short)h[i];
}

// K2: one block per class; reduce K1B partials (128 bins) -> cutoff bucket;
// zero the push counters.
__global__ __launch_bounds__(256) void k2_cutoff(
    const unsigned short* __restrict__ part, int* __restrict__ cb,
    unsigned* __restrict__ ccnt)
{
  const int c = blockIdx.x;
  const int t = threadIdx.x;
  __shared__ unsigned lh[2][NB];
  const int b = t & (NB - 1);
  const int g = t >> 7;
  unsigned acc = 0;
  for (int p = g; p < K1B; p += 2) acc += part[(size_t)p * BINS + c * NB + b];
  lh[g][b] = acc;
  if (t < SUBS) ccnt[c * SUBS + t] = 0u;
  __syncthreads();
  if (t == 0) {
    unsigned a = 0;
    int cbv = 0;
    for (int bb = NB - 1; bb >= 0; bb--) {
      a += lh[0][bb] + lh[1][bb];
      if (a >= (unsigned)PRE) { cbv = bb; break; }
    }
    while (a > (unsigned)CSORT && cbv < NB - 1) { a -= lh[0][cbv] + lh[1][cbv]; cbv++; }
    cb[c] = cbv;
  }
}

// K3: coalesced pass (high occupancy); push candidates above per-class cutoff.
// Test: b >= cb  <=>  fl(s*128) >= (float)cb   (exact for s > THR, cb in [0,127]).
__global__ __launch_bounds__(256) void k3_collect(
    const float4* __restrict__ cls4, int total4, const int* __restrict__ cb,
    unsigned* __restrict__ ccnt, u64* __restrict__ cand)
{
  __shared__ float tcb[NCLS];
  const int t = threadIdx.x;
  if (t < NCLS) tcb[t] = (float)cb[t];
  __syncthreads();
  const int sub = blockIdx.x & (SUBS - 1);
  const int stride = gridDim.x * 256;
  for (int q = blockIdx.x * 256 + t; q < total4; q += stride) {
    float4 v = cls4[q];
    int c0 = 4 * (q % 20);
    unsigned a = (unsigned)(q / 20);
    float sv[4] = {v.x, v.y, v.z, v.w};
#pragma unroll
    for (int e = 0; e < 4; e++) {
      float s = sv[e];
      if (s > THR_SCORE && s * (float)NB >= tcb[c0 + e]) {
        int c = c0 + e;
        unsigned p = atomicAdd(&ccnt[c * SUBS + sub], 1u);
        if (p < SUBCAP)
          cand[((size_t)(c * SUBS + sub)) * SUBCAP + p] =
              ((u64)__float_as_uint(s) << 32) | (u64)(~a);
      }
    }
  }
}

// kA: per-class gather + refine-to-1024 + bitonic sort + decode.
__global__ __launch_bounds__(1024) void kA_sort_decode(
    const unsigned* __restrict__ ccnt, const u64* __restrict__ cand,
    const int* __restrict__ cbp,
    const float* __restrict__ anch, const float* __restrict__ reg,
    const int* __restrict__ img_h_p, const int* __restrict__ img_w_p,
    float4* __restrict__ sbox, float* __restrict__ sarea,
    float* __restrict__ sscore, unsigned* __restrict__ sidx)
{
#pragma clang fp contract(off)
  const int c = blockIdx.x;
  const int t = threadIdx.x;
  __shared__ u64 L[CSORT];
  __shared__ u64 M[1024];
  __shared__ unsigned sbase[SUBS];
  __shared__ unsigned h2[512];
  __shared__ unsigned s_above;
  __shared__ int s_rsub;
  __shared__ unsigned s_n2;
  __shared__ unsigned s_push;
  __shared__ unsigned s_n;

  if (t == 0) {
    unsigned a = 0;
    for (int s = 0; s < SUBS; s++) {
      unsigned n = ccnt[c * SUBS + s];
      if (n > SUBCAP) n = SUBCAP;
      sbase[s] = a;
      a += n;
    }
    s_n = a;
    s_above = 0;
    s_push = 0;
  }
  for (int i = t; i < CSORT; i += 1024) L[i] = 0ull;
  M[t] = 0ull;
  if (t < 512) h2[t] = 0u;
  __syncthreads();
  for (int s = 0; s < SUBS; s++) {
    unsigned n = ccnt[c * SUBS + s];
    if (n > SUBCAP) n = SUBCAP;
    unsigned bs = sbase[s];
    for (unsigned i = t; i < n; i += 1024) {
      unsigned d = bs + i;
      if (d < CSORT) L[d] = cand[((size_t)(c * SUBS + s)) * SUBCAP + i];
    }
  }
  __syncthreads();

  const unsigned n = s_n <= CSORT ? s_n : CSORT;
  const int scb = cbp[c];
  const u64* SA = L;
  int SS = CSORT;

  if (n <= 1024) {
    SS = 1024;
  } else {
    // refine: 512-wide sub-bucket histogram of cutoff-bucket elements
    for (unsigned i = t; i < n; i += 1024) {
      float s = __uint_as_float((unsigned)(L[i] >> 32));
      int b = (int)(s * (float)NB);
      b = b < 0 ? 0 : (b > NB - 1 ? NB - 1 : b);
      if (b > scb) {
        atomicAdd(&s_above, 1u);
      } else {
        int sub = (int)(s * 65536.0f) - scb * 512;
        sub = sub < 0 ? 0 : (sub > 511 ? 511 : sub);
        atomicAdd(&h2[sub], 1u);
      }
    }
    __syncthreads();
    if (t == 0) {
      unsigned a = s_above;
      int r = 512;
      if (a < (unsigned)PRE) {
        for (int b2 = 511; b2 >= 0; b2--) {
          a += h2[b2];
          if (a >= (unsigned)PRE) { r = b2; break; }
        }
        if (a < (unsigned)PRE) r = 0;  // take all
      }
      s_rsub = r;
      s_n2 = a;
    }
    __syncthreads();
    if (s_n2 <= 1024u) {
      const int rsub = s_rsub;
      for (unsigned i = t; i < n; i += 1024) {
        u64 key = L[i];
        float s = __uint_as_float((unsigned)(key >> 32));
        int b = (int)(s * (float)NB);
        b = b < 0 ? 0 : (b > NB - 1 ? NB - 1 : b);
        bool take;
        if (b > scb) take = true;
        else {
          int sub = (int)(s * 65536.0f) - scb * 512;
          sub = sub < 0 ? 0 : (sub > 511 ? 511 : sub);
          take = (sub >= rsub);
        }
        if (take) {
          unsigned p = atomicAdd(&s_push, 1u);
          if (p < 1024u) M[p] = key;
        }
      }
      __syncthreads();
      SA = M;
      SS = 1024;
    }
  }

  // bitonic sort descending over SA[0..SS)
  u64* SW = (u64*)SA;
  for (int k = 2; k <= SS; k <<= 1) {
    for (int j = k >> 1; j > 0; j >>= 1) {
      for (int i = t; i < SS; i += 1024) {
        int ixj = i ^ j;
        if (ixj > i) {
          u64 va = SW[i], vb = SW[ixj];
          bool desc = ((i & k) == 0);
          if (desc ? (va < vb) : (va > vb)) { SW[i] = vb; SW[ixj] = va; }
        }
      }
      __syncthreads();
    }
  }

  // decode entry t (1024 threads, 1024 slots)
  const float W = (float)img_w_p[0];
  const float H = (float)img_h_p[0];
  const float4* a4 = (const float4*)anch;
  const float4* r4 = (const float4*)reg;
  const int k = t;
  if (k < PRE) {
    u64 key = SW[k];
    float sc; unsigned idx;
    if (key != 0ull) {
      sc = __uint_as_float((unsigned)(key >> 32));
      idx = ~((unsigned)(key & 0xFFFFFFFFull));
    } else {
      sc = -INFINITY; idx = 0u;
    }
    float4 av = a4[idx];
    float4 rv = r4[idx];
    float w = av.z - av.x, h = av.w - av.y;
    float cx = av.x + 0.5f * w, cy = av.y + 0.5f * h;
    float dx = rv.x * 0.1f, dy = rv.y * 0.1f, dw = rv.z * 0.2f, dh = rv.w * 0.2f;
    float pcx = cx + dx * w, pcy = cy + dy * h;
    float pw = (float)exp((double)dw) * w;
    float ph = (float)exp((double)dh) * h;
    float x1 = fminf(fmaxf(pcx - 0.5f * pw, 0.0f), W);
    float y1 = fminf(fmaxf(pcy - 0.5f * ph, 0.0f), H);
    float x2 = fminf(fmaxf(pcx + 0.5f * pw, 0.0f), W);
    float y2 = fminf(fmaxf(pcy + 0.5f * ph, 0.0f), H);
    sbox[c * 1024 + k] = make_float4(x1, y1, x2, y2);
    sarea[c * 1024 + k] = (x2 - x1) * (y2 - y1);
    sscore[c * 1024 + k] = sc;
    sidx[c * 1024 + k] = idx;
  } else {
    sbox[c * 1024 + k] = make_float4(0.f, 0.f, 0.f, 0.f);
    sarea[c * 1024 + k] = 0.f;
    sscore[c * 1024 + k] = -INFINITY;
    sidx[c * 1024 + k] = 0u;
  }
}

// kB: supm build spread over RS blocks per class; columns in registers.
__global__ __launch_bounds__(256) void kB_build(
    const float4* __restrict__ sbox, const float* __restrict__ sarea,
    u64* __restrict__ supm)
{
#pragma clang fp contract(off)
  const int c = blockIdx.x >> 3;       // RS = 8
  const int r = blockIdx.x & (RS - 1);
  const int t = threadIdx.x;
  __shared__ float4 box4[1024];
  __shared__ float area[1024];
  for (int i = t; i < 1024; i += 256) {
    box4[i] = sbox[c * 1024 + i];
    area[i] = sarea[c * 1024 + i];
  }
  __syncthreads();
  const int wave = t >> 6, lane = t & 63;
  float4 cbx[16];
  float car[16];
#pragma unroll
  for (int g = 0; g < 16; g++) {
    cbx[g] = box4[g * 64 + lane];
    car[g] = area[g * 64 + lane];
  }
  u64* S = supm + (size_t)c * SUPM_STRIDE;
  // exact: fl32(inter/denom) > 0.5f  <=>  (double)inter > 0.5*(1+2^-24)*(double)denom
  const double MID = 0x1.000001p-1;
  for (int i = r * 4 + wave; i < PRE; i += 32) {
    float4 rb = box4[i];
    float ra = area[i];
    const int g0 = i >> 6;
    const int ib = i & 63;
    u64 mrow = 0ull;
#pragma unroll
    for (int g = 0; g < 16; g++) {
      if (g < g0) continue;
      float ltx = fmaxf(rb.x, cbx[g].x);
      float lty = fmaxf(rb.y, cbx[g].y);
      float rbx = fminf(rb.z, cbx[g].z);
      float rby = fminf(rb.w, cbx[g].w);
      float ww = fmaxf(rbx - ltx, 0.0f);
      float hh = fmaxf(rby - lty, 0.0f);
      float inter = ww * hh;
      float denom = ((ra + car[g]) - inter) + 1e-8f;
      bool io = (double)inter > MID * (double)denom;
      bool pred = (g > g0) | (lane > ib);
      bool inb = (g < 15) | (lane < PRE - 15 * 64);
      u64 m = __ballot(io & pred & inb);
      mrow = (lane == g) ? m : mrow;
    }
    if (lane < 16) S[i * 16 + lane] = mrow;
  }
}

// kC: stage per-class supm in LDS, then exact serial scan (wave 0) + output.
__global__ __launch_bounds__(512, 1) void kC_scan_out(
    const u64* __restrict__ supm, const float4* __restrict__ sbox,
    const float* __restrict__ sscore, const unsigned* __restrict__ sidx,
    const float* __restrict__ dist,
    float* __restrict__ out_s, float* __restrict__ out_id,
    float* __restrict__ out_b, float* __restrict__ out_d)
{
  const int c = blockIdx.x;
  const int t = threadIdx.x;
  __shared__ u64 ls[PRE * 16 + 384];   // 16384 words = 128 KB
  __shared__ u64 keepw[16];
  __shared__ unsigned wpre[17];

  {
    const ulonglong2* S2 = (const ulonglong2*)(supm + (size_t)c * SUPM_STRIDE);
    ulonglong2* D2 = (ulonglong2*)ls;
    for (int i = t; i < SUPM_STRIDE / 2; i += 512) D2[i] = S2[i];
  }
  __syncthreads();

  if (t < 64) {
    const int lane = t;
    u64 klane = 0ull;
    for (int w = 0; w < 16; w++) {
      float v = sscore[c * 1024 + w * 64 + lane];
      u64 bal = __ballot(v != -INFINITY);
      klane = (lane == w) ? bal : klane;
    }

    unsigned acc = 0;
    for (int w = 0; w < 16; w++) {
      u64 Rw = ls[(unsigned)((w * 64 + lane) * 16 + w)];
      u64 alive = readlane64(klane, w);
      u64 F = 0ull;
      while (alive) {
        int b = __builtin_ctzll(alive);
        F |= (1ull << b);
        u64 rb = readlane64(Rw, b);
        alive &= ~(rb | (1ull << b));
      }
      if (lane == 0) { keepw[w] = F; wpre[w] = acc; }
      acc += (unsigned)__builtin_popcountll(F);
      const u64* base = ls + (size_t)(w * 64) * 16;
      u64 ff = F;
      while (ff) {
        u64 m0 = 0, m1 = 0, m2 = 0, m3 = 0, m4 = 0, m5 = 0, m6 = 0, m7 = 0;
        int b0 = __builtin_ctzll(ff); ff &= ff - 1;
        if (lane < 16) m0 = base[(size_t)b0 * 16 + lane];
        if (ff) { int b = __builtin_ctzll(ff); ff &= ff - 1; if (lane < 16) m1 = base[(size_t)b * 16 + lane];
        if (ff) { int b2 = __builtin_ctzll(ff); ff &= ff - 1; if (lane < 16) m2 = base[(size_t)b2 * 16 + lane];
        if (ff) { int b3 = __builtin_ctzll(ff); ff &= ff - 1; if (lane < 16) m3 = base[(size_t)b3 * 16 + lane];
        if (ff) { int b4 = __builtin_ctzll(ff); ff &= ff - 1; if (lane < 16) m4 = base[(size_t)b4 * 16 + lane];
        if (ff) { int b5 = __builtin_ctzll(ff); ff &= ff - 1; if (lane < 16) m5 = base[(size_t)b5 * 16 + lane];
        if (ff) { int b6 = __builtin_ctzll(ff); ff &= ff - 1; if (lane < 16) m6 = base[(size_t)b6 * 16 + lane];
        if (ff) { int b7 = __builtin_ctzll(ff); ff &= ff - 1; if (lane < 16) m7 = base[(size_t)b7 * 16 + lane];
        }}}}}}}
        klane &= ~(m0 | m1 | m2 | m3 | m4 | m5 | m6 | m7);
      }
    }
    if (lane == 0) wpre[16] = acc;
  }
  __syncthreads();
  const unsigned total = wpre[16];

  for (int k = t; k < PRE; k += 512) {
    int w = k >> 6, b = k & 63;
    u64 kw = keepw[w];
    if ((kw >> b) & 1ull) {
      unsigned rank = wpre[w] + (unsigned)__popcll(kw & ((1ull << b) - 1ull));
      if (rank < MAXD) {
        int slot = c * MAXD + (int)rank;
        out_s[slot] = sscore[c * 1024 + k];
        out_id[slot] = (float)c;
        ((float4*)out_b)[slot] = sbox[c * 1024 + k];
        out_d[slot] = dist[sidx[c * 1024 + k]];
      }
    }
  }
  unsigned tk = total < MAXD ? total : MAXD;
  for (int r = (int)tk + t; r < MAXD; r += 512) {
    int slot = c * MAXD + r;
    out_s[slot] = 0.0f;
    out_id[slot] = -1.0f;
    ((float4*)out_b)[slot] = make_float4(0.f, 0.f, 0.f, 0.f);
    out_d[slot] = 0.0f;
  }
}

// =====================================================================
// FALLBACK PATH (round-1, proven correct; used only if ws is too small)
// =====================================================================
#define NBUCK 4096
#define CANDF 2048

__global__ __launch_bounds__(256) void select_topk(
    const float* __restrict__ cls, int A,
    float* __restrict__ topscore, unsigned* __restrict__ topidx)
{
  const int c = blockIdx.x;
  const int t = threadIdx.x;
  __shared__ unsigned hist[NBUCK];
  __shared__ u64 cand[CANDF];
  __shared__ unsigned chunk[256];
  __shared__ int s_cb;
  __shared__ int s_cnt;
  for (int i = t; i < NBUCK; i += 256) hist[i] = 0u;
  if (t == 0) s_cnt = 0;
  __syncthreads();
  for (int a = t; a < A; a += 256) {
    float s = cls[(size_t)a * NCLS + c];
    if (s > THR_SCORE) {
      int b = (int)(s * (float)NBUCK);
      b = b < 0 ? 0 : (b > NBUCK - 1 ? NBUCK - 1 : b);
      atomicAdd(&hist[b], 1u);
    }
  }
  __syncthreads();
  {
    unsigned cs = 0;
    for (int i = 0; i < NBUCK / 256; i++) cs += hist[t * (NBUCK / 256) + i];
    chunk[t] = cs;
  }
  __syncthreads();
  if (t == 0) {
    unsigned acc = 0;
    int cb = 0;
    int ch;
    for (ch = 255; ch >= 0; ch--) {
      if (acc + chunk[ch] >= (unsigned)PRE) break;
      acc += chunk[ch];
    }
    if (ch < 0) cb = 0;
    else {
      const int bpc = NBUCK / 256;
      int b = ch * bpc + bpc - 1;
      for (; b >= ch * bpc; b--) { acc += hist[b]; if (acc >= (unsigned)PRE) break; }
      if (b < ch * bpc) b = ch * bpc;
      cb = b;
      while (acc > (unsigned)CANDF && cb < NBUCK - 1) { acc -= hist[cb]; cb++; }
    }
    s_cb = cb;
  }
  __syncthreads();
  const int cb = s_cb;
  for (int a = t; a < A; a += 256) {
    float s = cls[(size_t)a * NCLS + c];
    if (s > THR_SCORE) {
      int b = (int)(s * (float)NBUCK);
      b = b < 0 ? 0 : (b > NBUCK - 1 ? NBUCK - 1 : b);
      if (b >= cb) {
        int p = atomicAdd(&s_cnt, 1);
        if (p < CANDF)
          cand[p] = ((u64)__float_as_uint(s) << 32) | (u64)(~(unsigned)a);
      }
    }
  }
  __syncthreads();
  int n = s_cnt < CANDF ? s_cnt : CANDF;
  for (int i = n + t; i < CANDF; i += 256) cand[i] = 0ull;
  __syncthreads();
  for (int k = 2; k <= CANDF; k <<= 1) {
    for (int j = k >> 1; j > 0; j >>= 1) {
      for (int i = t; i < CANDF; i += 256) {
        int ixj = i ^ j;
        if (ixj > i) {
          u64 va = cand[i], vb = cand[ixj];
          bool desc = ((i & k) == 0);
          if (desc ? (va < vb) : (va > vb)) { cand[i] = vb; cand[ixj] = va; }
        }
      }
      __syncthreads();
    }
  }
  for (int k = t; k < PRE; k += 256) {
    u64 key = cand[k];
    float sc; unsigned idx;
    if (key != 0ull) { sc = __uint_as_float((unsigned)(key >> 32)); idx = ~((unsigned)(key & 0xFFFFFFFFull)); }
    else { sc = -INFINITY; idx = 0u; }
    topscore[c * PRE + k] = sc;
    topidx[c * PRE + k] = idx;
  }
}

__global__ __launch_bounds__(256) void nms_out(
    const float* __restrict__ anch, const float* __restrict__ reg,
    const float* __restrict__ dist,
    const float* __restrict__ topscore, const unsigned* __restrict__ topidx,
    const int* __restrict__ img_h_p, const int* __restrict__ img_w_p,
    float* __restrict__ out_s, float* __restrict__ out_id,
    float* __restrict__ out_b, float* __restrict__ out_d)
{
#pragma clang fp contract(off)
  const int c = blockIdx.x;
  const int t = threadIdx.x;
  __shared__ float bx[PRE], by[PRE], bX[PRE], bY[PRE], bar[PRE], ssc[PRE];
  __shared__ u64 supm[PRE * 16];
  __shared__ u64 keepw[16];
  __shared__ unsigned wpre[17];
  const float W = (float)img_w_p[0];
  const float H = (float)img_h_p[0];
  for (int k = t; k < PRE; k += 256) {
    float sc = topscore[c * PRE + k];
    unsigned idx = topidx[c * PRE + k];
    ssc[k] = sc;
    float a0 = anch[(size_t)idx * 4 + 0], a1 = anch[(size_t)idx * 4 + 1];
    float a2 = anch[(size_t)idx * 4 + 2], a3 = anch[(size_t)idx * 4 + 3];
    float r0 = reg[(size_t)idx * 4 + 0], r1 = reg[(size_t)idx * 4 + 1];
    float r2 = reg[(size_t)idx * 4 + 2], r3 = reg[(size_t)idx * 4 + 3];
    float w = a2 - a0, h = a3 - a1;
    float cx = a0 + 0.5f * w, cy = a1 + 0.5f * h;
    float dx = r0 * 0.1f, dy = r1 * 0.1f, dw = r2 * 0.2f, dh = r3 * 0.2f;
    float pcx = cx + dx * w, pcy = cy + dy * h;
    float pw = (float)exp((double)dw) * w;
    float ph = (float)exp((double)dh) * h;
    float x1 = fminf(fmaxf(pcx - 0.5f * pw, 0.0f), W);
    float y1 = fminf(fmaxf(pcy - 0.5f * ph, 0.0f), H);
    float x2 = fminf(fmaxf(pcx + 0.5f * pw, 0.0f), W);
    float y2 = fminf(fmaxf(pcy + 0.5f * ph, 0.0f), H);
    bx[k] = x1; by[k] = y1; bX[k] = x2; bY[k] = y2;
    bar[k] = (x2 - x1) * (y2 - y1);
  }
  __syncthreads();
  const int wave = t >> 6, lane = t & 63;
  for (int i = wave; i < PRE; i += 4) {
    float x1 = bx[i], y1 = by[i], X1 = bX[i], Y1 = bY[i], ai = bar[i];
    for (int g = 0; g < 16; g++) {
      int j = g * 64 + lane;
      bool s = false;
      if (j > i && j < PRE) {
        float ltx = fmaxf(x1, bx[j]);
        float lty = fmaxf(y1, by[j]);
        float rbx = fminf(X1, bX[j]);
        float rby = fminf(Y1, bY[j]);
        float ww = fmaxf(rbx - ltx, 0.0f);
        float hh = fmaxf(rby - lty, 0.0f);
        float inter = ww * hh;
        float iou = inter / ((ai + bar[j]) - inter + 1e-8f);
        s = iou > 0.5f;
      }
      u64 m = __ballot(s);
      if (lane == 0) supm[i * 16 + g] = m;
    }
  }
  __syncthreads();
  if (t < 64) {
    u64 kw = 0ull;
    if (t < 16) {
      for (int b = 0; b < 64; b++) {
        int k = t * 64 + b;
        if (k < PRE && ssc[k] != -INFINITY) kw |= (1ull << b);
      }
    }
    for (int i = 0; i < PRE; i++) {
      u64 ow = __shfl(kw, i >> 6);
      if ((ow >> (i & 63)) & 1ull) {
        if (t < 16) kw &= ~supm[i * 16 + t];
      }
    }
    if (t < 16) keepw[t] = kw;
  }
  __syncthreads();
  if (t == 0) {
    unsigned acc = 0;
    for (int w = 0; w < 16; w++) { wpre[w] = acc; acc += (unsigned)__popcll(keepw[w]); }
    wpre[16] = acc;
  }
  __syncthreads();
  const unsigned total = wpre[16];
  for (int k = t; k < PRE; k += 256) {
    int w = k >> 6, b = k & 63;
    u64 kw = keepw[w];
    if ((kw >> b) & 1ull) {
      unsigned rank = wpre[w] + (unsigned)__popcll(kw & ((1ull << b) - 1ull));
      if (rank < MAXD) {
        int slot = c * MAXD + (int)rank;
        out_s[slot] = ssc[k];
        out_id[slot] = (float)c;
        out_b[slot * 4 + 0] = bx[k];
        out_b[slot * 4 + 1] = by[k];
        out_b[slot * 4 + 2] = bX[k];
        out_b[slot * 4 + 3] = bY[k];
        out_d[slot] = dist[topidx[c * PRE + k]];
      }
    }
  }
  unsigned tk = total < MAXD ? total : MAXD;
  for (int r = (int)tk + t; r < MAXD; r += 256) {
    int slot = c * MAXD + r;
    out_s[slot] = 0.0f;
    out_id[slot] = -1.0f;
    out_b[slot * 4 + 0] = 0.0f; out_b[slot * 4 + 1] = 0.0f;
    out_b[slot * 4 + 2] = 0.0f; out_b[slot * 4 + 3] = 0.0f;
    out_d[slot] = 0.0f;
  }
}

// =====================================================================

static inline size_t align512(size_t x) { return (x + 511) & ~(size_t)511; }

extern "C" void kernel_launch(void* const* d_in, const int* in_sizes, int n_in,
                              void* d_out, int out_size, void* d_ws, size_t ws_size,
                              hipStream_t stream) {
  const float* cls  = (const float*)d_in[0];   // (1, A, 80)
  const float* reg  = (const float*)d_in[1];   // (1, A, 4)
  const float* dist = (const float*)d_in[2];   // (1, A, 1)
  const float* anch = (const float*)d_in[3];   // (1, A, 4)
  const int* img_h  = (const int*)d_in[4];
  const int* img_w  = (const int*)d_in[5];
  const int A = in_sizes[3] / 4;

  float* o = (float*)d_out;
  float* out_s  = o;                      // 8000
  float* out_id = o + NCLS * MAXD;        // 8000
  float* out_b  = o + 2 * NCLS * MAXD;    // 32000
  float* out_d  = o + 6 * NCLS * MAXD;    // 8000

  // big region serves sequentially: part (k1->k2), cand (k3->kA), supm (kB->kC)
  const size_t sz_part = (size_t)K1B * BINS * sizeof(unsigned short);        // 10.49 MB
  const size_t sz_cand = (size_t)NCLS * SUBS * SUBCAP * sizeof(u64);         // 5.24 MB
  const size_t sz_supm = (size_t)NCLS * SUPM_STRIDE * sizeof(u64);           // 10.49 MB
  size_t sz_big = sz_part;
  if (sz_cand > sz_big) sz_big = sz_cand;
  if (sz_supm > sz_big) sz_big = sz_supm;
  size_t off = align512(sz_big);
  const size_t o_cb    = off; off += align512(NCLS * sizeof(int));
  const size_t o_ccnt  = off; off += align512((size_t)NCLS * SUBS * sizeof(unsigned));
  const size_t o_sbox  = off; off += align512((size_t)NCLS * 1024 * sizeof(float4));
  const size_t o_sarea = off; off += align512((size_t)NCLS * 1024 * sizeof(float));
  const size_t o_sscr  = off; off += align512((size_t)NCLS * 1024 * sizeof(float));
  const size_t o_sidx  = off; off += align512((size_t)NCLS * 1024 * sizeof(unsigned));
  const size_t needed = off;

  if (ws_size >= needed) {
    char* ws = (char*)d_ws;
    unsigned short* part = (unsigned short*)ws;
    u64* cand = (u64*)ws;
    u64* supm = (u64*)ws;
    int* cb = (int*)(ws + o_cb);
    unsigned* ccnt = (unsigned*)(ws + o_ccnt);
    float4* sbox = (float4*)(ws + o_sbox);
    float* sarea = (float*)(ws + o_sarea);
    float* sscr = (float*)(ws + o_sscr);
    unsigned* sidxp = (unsigned*)(ws + o_sidx);
    const int total4 = A * 20;  // A*80/4

    k1_hist<<<K1B, 256, 0, stream>>>((const float4*)cls, total4, part);
    k2_cutoff<<<NCLS, 256, 0, stream>>>(part, cb, ccnt);
    k3_collect<<<K3B, 256, 0, stream>>>((const float4*)cls, total4, cb, ccnt, cand);
    kA_sort_decode<<<NCLS, 1024, 0, stream>>>(ccnt, cand, cb, anch, reg, img_h, img_w,
                                              sbox, sarea, sscr, sidxp);
    kB_build<<<NCLS * RS, 256, 0, stream>>>(sbox, sarea, supm);
    kC_scan_out<<<NCLS, 512, 0, stream>>>(supm, sbox, sscr, sidxp, dist,
                                          out_s, out_id, out_b, out_d);
  } else {
    // fallback: proven round-1 path (needs only ~0.64 MB)
    float* topscore = (float*)d_ws;
    unsigned* topidx = (unsigned*)((char*)d_ws + NCLS * PRE * sizeof(float));
    select_topk<<<NCLS, 256, 0, stream>>>(cls, A, topscore, topidx);
    nms_out<<<NCLS, 256, 0, stream>>>(anch, reg, dist, topscore, topidx,
                                      img_h, img_w, out_s, out_id, out_b, out_d);
  }
}

// Round 7
// 164.552 us; speedup vs baseline: 7.3289x; 1.6006x over previous
//
#include <hip/hip_runtime.h>
#include <math.h>

#define NCLS 80
#define PRE 1000
#define MAXD 100
#define THR_SCORE 0.05f

// ---- fast path config ----
#define NB 128                 // buckets per class (coarse; refined in kA)
#define BINS (NCLS * NB)       // 10240
#define K1B 512                // histogram blocks (= partial count)
#define SUBS 16                // sub-lists per class
#define SUBCAP 512             // depth per sub-list
#define CSORT 4096             // max candidates per class
#define K3B 2048               // collect blocks

typedef unsigned long long u64;

__device__ __forceinline__ u64 readlane64(u64 v, int l) {
  unsigned lo = (unsigned)__builtin_amdgcn_readlane((int)(unsigned)v, l);
  unsigned hi = (unsigned)__builtin_amdgcn_readlane((int)(unsigned)(v >> 32), l);
  return ((u64)hi << 32) | lo;
}

// =====================================================================
// K1: coalesced float4 pass over cls, per-block LDS hist (80x128), u16 partials.
__global__ __launch_bounds__(256) void k1_hist(
    const float4* __restrict__ cls4, int total4, unsigned short* __restrict__ part)
{
  __shared__ unsigned h[BINS];
  const int t = threadIdx.x;
  for (int i = t; i < BINS; i += 256) h[i] = 0u;
  __syncthreads();
  const int stride = gridDim.x * 256;
  for (int q = blockIdx.x * 256 + t; q < total4; q += stride) {
    float4 v = cls4[q];
    int c0 = 4 * (q % 20);  // (4q) % 80
    float s; int b;
    s = v.x; if (s > THR_SCORE) { b = (int)(s * (float)NB); b = b < 0 ? 0 : (b > NB - 1 ? NB - 1 : b); atomicAdd(&h[(c0 + 0) * NB + b], 1u); }
    s = v.y; if (s > THR_SCORE) { b = (int)(s * (float)NB); b = b < 0 ? 0 : (b > NB - 1 ? NB - 1 : b); atomicAdd(&h[(c0 + 1) * NB + b], 1u); }
    s = v.z; if (s > THR_SCORE) { b = (int)(s * (float)NB); b = b < 0 ? 0 : (b > NB - 1 ? NB - 1 : b); atomicAdd(&h[(c0 + 2) * NB + b], 1u); }
    s = v.w; if (s > THR_SCORE) { b = (int)(s * (float)NB); b = b < 0 ? 0 : (b > NB - 1 ? NB - 1 : b); atomicAdd(&h[(c0 + 3) * NB + b], 1u); }
  }
  __syncthreads();
  unsigned short* p = part + (size_t)blockIdx.x * BINS;
  for (int i = t; i < BINS; i += 256) p[i] = (unsigned short)h[i];
}

// K2: one block per class; reduce K1B partials (128 bins) -> cutoff bucket;
// zero the push counters.
__global__ __launch_bounds__(256) void k2_cutoff(
    const unsigned short* __restrict__ part, int* __restrict__ cb,
    unsigned* __restrict__ ccnt)
{
  const int c = blockIdx.x;
  const int t = threadIdx.x;
  __shared__ unsigned lh[2][NB];
  const int b = t & (NB - 1);
  const int g = t >> 7;
  unsigned acc = 0;
  for (int p = g; p < K1B; p += 2) acc += part[(size_t)p * BINS + c * NB + b];
  lh[g][b] = acc;
  if (t < SUBS) ccnt[c * SUBS + t] = 0u;
  __syncthreads();
  if (t == 0) {
    unsigned a = 0;
    int cbv = 0;
    for (int bb = NB - 1; bb >= 0; bb--) {
      a += lh[0][bb] + lh[1][bb];
      if (a >= (unsigned)PRE) { cbv = bb; break; }
    }
    while (a > (unsigned)CSORT && cbv < NB - 1) { a -= lh[0][cbv] + lh[1][cbv]; cbv++; }
    cb[c] = cbv;
  }
}

// K3: coalesced pass (high occupancy); push candidates above per-class cutoff.
__global__ __launch_bounds__(256) void k3_collect(
    const float4* __restrict__ cls4, int total4, const int* __restrict__ cb,
    unsigned* __restrict__ ccnt, u64* __restrict__ cand)
{
  __shared__ float tcb[NCLS];
  const int t = threadIdx.x;
  if (t < NCLS) tcb[t] = (float)cb[t];
  __syncthreads();
  const int sub = blockIdx.x & (SUBS - 1);
  const int stride = gridDim.x * 256;
  for (int q = blockIdx.x * 256 + t; q < total4; q += stride) {
    float4 v = cls4[q];
    int c0 = 4 * (q % 20);
    unsigned a = (unsigned)(q / 20);
    float sv[4] = {v.x, v.y, v.z, v.w};
#pragma unroll
    for (int e = 0; e < 4; e++) {
      float s = sv[e];
      if (s > THR_SCORE && s * (float)NB >= tcb[c0 + e]) {
        int c = c0 + e;
        unsigned p = atomicAdd(&ccnt[c * SUBS + sub], 1u);
        if (p < SUBCAP)
          cand[((size_t)(c * SUBS + sub)) * SUBCAP + p] =
              ((u64)__float_as_uint(s) << 32) | (u64)(~a);
      }
    }
  }
}

// kA: per-class gather + refine-to-1024 + bitonic sort + decode.
__global__ __launch_bounds__(1024) void kA_sort_decode(
    const unsigned* __restrict__ ccnt, const u64* __restrict__ cand,
    const int* __restrict__ cbp,
    const float* __restrict__ anch, const float* __restrict__ reg,
    const int* __restrict__ img_h_p, const int* __restrict__ img_w_p,
    float4* __restrict__ sbox, float* __restrict__ sarea,
    float* __restrict__ sscore, unsigned* __restrict__ sidx)
{
#pragma clang fp contract(off)
  const int c = blockIdx.x;
  const int t = threadIdx.x;
  __shared__ u64 L[CSORT];
  __shared__ u64 M[1024];
  __shared__ unsigned sbase[SUBS];
  __shared__ unsigned h2[512];
  __shared__ unsigned s_above;
  __shared__ int s_rsub;
  __shared__ unsigned s_n2;
  __shared__ unsigned s_push;
  __shared__ unsigned s_n;

  if (t == 0) {
    unsigned a = 0;
    for (int s = 0; s < SUBS; s++) {
      unsigned n = ccnt[c * SUBS + s];
      if (n > SUBCAP) n = SUBCAP;
      sbase[s] = a;
      a += n;
    }
    s_n = a;
    s_above = 0;
    s_push = 0;
  }
  for (int i = t; i < CSORT; i += 1024) L[i] = 0ull;
  M[t] = 0ull;
  if (t < 512) h2[t] = 0u;
  __syncthreads();
  for (int s = 0; s < SUBS; s++) {
    unsigned n = ccnt[c * SUBS + s];
    if (n > SUBCAP) n = SUBCAP;
    unsigned bs = sbase[s];
    for (unsigned i = t; i < n; i += 1024) {
      unsigned d = bs + i;
      if (d < CSORT) L[d] = cand[((size_t)(c * SUBS + s)) * SUBCAP + i];
    }
  }
  __syncthreads();

  const unsigned n = s_n <= CSORT ? s_n : CSORT;
  const int scb = cbp[c];
  const u64* SA = L;
  int SS = CSORT;

  if (n <= 1024) {
    SS = 1024;
  } else {
    // refine: 512-wide sub-bucket histogram of cutoff-bucket elements
    for (unsigned i = t; i < n; i += 1024) {
      float s = __uint_as_float((unsigned)(L[i] >> 32));
      int b = (int)(s * (float)NB);
      b = b < 0 ? 0 : (b > NB - 1 ? NB - 1 : b);
      if (b > scb) {
        atomicAdd(&s_above, 1u);
      } else {
        int sub = (int)(s * 65536.0f) - scb * 512;
        sub = sub < 0 ? 0 : (sub > 511 ? 511 : sub);
        atomicAdd(&h2[sub], 1u);
      }
    }
    __syncthreads();
    if (t == 0) {
      unsigned a = s_above;
      int r = 512;
      if (a < (unsigned)PRE) {
        for (int b2 = 511; b2 >= 0; b2--) {
          a += h2[b2];
          if (a >= (unsigned)PRE) { r = b2; break; }
        }
        if (a < (unsigned)PRE) r = 0;  // take all
      }
      s_rsub = r;
      s_n2 = a;
    }
    __syncthreads();
    if (s_n2 <= 1024u) {
      const int rsub = s_rsub;
      for (unsigned i = t; i < n; i += 1024) {
        u64 key = L[i];
        float s = __uint_as_float((unsigned)(key >> 32));
        int b = (int)(s * (float)NB);
        b = b < 0 ? 0 : (b > NB - 1 ? NB - 1 : b);
        bool take;
        if (b > scb) take = true;
        else {
          int sub = (int)(s * 65536.0f) - scb * 512;
          sub = sub < 0 ? 0 : (sub > 511 ? 511 : sub);
          take = (sub >= rsub);
        }
        if (take) {
          unsigned p = atomicAdd(&s_push, 1u);
          if (p < 1024u) M[p] = key;
        }
      }
      __syncthreads();
      SA = M;
      SS = 1024;
    }
  }

  // bitonic sort descending over SA[0..SS)
  u64* SW = (u64*)SA;
  for (int k = 2; k <= SS; k <<= 1) {
    for (int j = k >> 1; j > 0; j >>= 1) {
      for (int i = t; i < SS; i += 1024) {
        int ixj = i ^ j;
        if (ixj > i) {
          u64 va = SW[i], vb = SW[ixj];
          bool desc = ((i & k) == 0);
          if (desc ? (va < vb) : (va > vb)) { SW[i] = vb; SW[ixj] = va; }
        }
      }
      __syncthreads();
    }
  }

  // decode entry t (1024 threads, 1024 slots)
  const float W = (float)img_w_p[0];
  const float H = (float)img_h_p[0];
  const float4* a4 = (const float4*)anch;
  const float4* r4 = (const float4*)reg;
  const int k = t;
  if (k < PRE) {
    u64 key = SW[k];
    float sc; unsigned idx;
    if (key != 0ull) {
      sc = __uint_as_float((unsigned)(key >> 32));
      idx = ~((unsigned)(key & 0xFFFFFFFFull));
    } else {
      sc = -INFINITY; idx = 0u;
    }
    float4 av = a4[idx];
    float4 rv = r4[idx];
    float w = av.z - av.x, h = av.w - av.y;
    float cx = av.x + 0.5f * w, cy = av.y + 0.5f * h;
    float dx = rv.x * 0.1f, dy = rv.y * 0.1f, dw = rv.z * 0.2f, dh = rv.w * 0.2f;
    float pcx = cx + dx * w, pcy = cy + dy * h;
    float pw = (float)exp((double)dw) * w;
    float ph = (float)exp((double)dh) * h;
    float x1 = fminf(fmaxf(pcx - 0.5f * pw, 0.0f), W);
    float y1 = fminf(fmaxf(pcy - 0.5f * ph, 0.0f), H);
    float x2 = fminf(fmaxf(pcx + 0.5f * pw, 0.0f), W);
    float y2 = fminf(fmaxf(pcy + 0.5f * ph, 0.0f), H);
    sbox[c * 1024 + k] = make_float4(x1, y1, x2, y2);
    sarea[c * 1024 + k] = (x2 - x1) * (y2 - y1);
    sscore[c * 1024 + k] = sc;
    sidx[c * 1024 + k] = idx;
  } else {
    sbox[c * 1024 + k] = make_float4(0.f, 0.f, 0.f, 0.f);
    sarea[c * 1024 + k] = 0.f;
    sscore[c * 1024 + k] = -INFINITY;
    sidx[c * 1024 + k] = 0u;
  }
}

// kD: fused on-the-fly NMS with early exit at MAXD kept. One wave per class.
// Per 64-row window: (1) lane-parallel suppression check vs kept list (LDS
// broadcast), (2) 64-ballot within-window diagonal block, (3) SALU serial
// resolve (no memory in chain), append kept, break at acc >= MAXD.
__global__ __launch_bounds__(64) void kD_nms_out(
    const float4* __restrict__ sbox, const float* __restrict__ sarea,
    const float* __restrict__ sscore, const unsigned* __restrict__ sidx,
    const float* __restrict__ dist,
    float* __restrict__ out_s, float* __restrict__ out_id,
    float* __restrict__ out_b, float* __restrict__ out_d)
{
#pragma clang fp contract(off)
  const int c = blockIdx.x;
  const int lane = threadIdx.x;
  __shared__ float fx[192], fy[192], fX[192], fY[192], fA[192];  // kept boxes
  __shared__ float wx[64], wy[64], wX[64], wY[64], wA[64];       // window stage
  __shared__ u64 s_keep[16];
  __shared__ unsigned s_pre[16];
  __shared__ unsigned s_total;

  if (lane < 16) { s_keep[lane] = 0ull; s_pre[lane] = 0u; }

  // exact: fl32(inter/denom) > 0.5f  <=>  (double)inter > 0.5*(1+2^-24)*(double)denom
  const double MID = 0x1.000001p-1;
  unsigned acc = 0;
  int nf = 0;

  for (int w = 0; w < 16; w++) {
    const int r = w * 64 + lane;
    const float4 rb = sbox[c * 1024 + r];
    const float ra = sarea[c * 1024 + r];
    const float sc = sscore[c * 1024 + r];
    bool dead = (sc == -INFINITY);
    // (1) suppression by previously-kept boxes
    for (int f = 0; f < nf; f++) {
      float ltx = fmaxf(rb.x, fx[f]);
      float lty = fmaxf(rb.y, fy[f]);
      float rbx = fminf(rb.z, fX[f]);
      float rby = fminf(rb.w, fY[f]);
      float ww = fmaxf(rbx - ltx, 0.0f);
      float hh = fmaxf(rby - lty, 0.0f);
      float inter = ww * hh;
      float denom = ((ra + fA[f]) - inter) + 1e-8f;
      dead = dead | ((double)inter > MID * (double)denom);
    }
    u64 alive = __ballot(!dead);
    u64 F = 0ull;
    if (alive) {
      // (2) stage window boxes, build diagonal block rows
      wx[lane] = rb.x; wy[lane] = rb.y; wX[lane] = rb.z; wY[lane] = rb.w; wA[lane] = ra;
      __syncthreads();
      u64 Rw = 0ull;
#pragma unroll 4
      for (int i = 0; i < 64; i++) {
        float ltx = fmaxf(wx[i], rb.x);
        float lty = fmaxf(wy[i], rb.y);
        float rbx = fminf(wX[i], rb.z);
        float rby = fminf(wY[i], rb.w);
        float ww = fmaxf(rbx - ltx, 0.0f);
        float hh = fmaxf(rby - lty, 0.0f);
        float inter = ww * hh;
        float denom = ((wA[i] + ra) - inter) + 1e-8f;
        bool io = (double)inter > MID * (double)denom;
        u64 m = __ballot(io & (lane > i));
        Rw = (lane == i) ? m : Rw;
      }
      // (3) serial resolve: fire rows in order, mask within-window overlaps
      while (alive) {
        int b = __builtin_ctzll(alive);
        F |= (1ull << b);
        u64 rbw = readlane64(Rw, b);
        alive &= ~(rbw | (1ull << b));
      }
      // append kept boxes to list
      if ((F >> lane) & 1ull) {
        int pos = nf + (int)__popcll(F & ((1ull << lane) - 1ull));
        if (pos < 192) {
          fx[pos] = rb.x; fy[pos] = rb.y; fX[pos] = rb.z; fY[pos] = rb.w; fA[pos] = ra;
        }
      }
      __syncthreads();
    }
    if (lane == 0) { s_keep[w] = F; s_pre[w] = acc; }
    acc += (unsigned)__popcll(F);
    nf += (int)__popcll(F);
    if (acc >= (unsigned)MAXD) break;   // early exit: first MAXD kept are final
  }
  if (lane == 0) s_total = acc;
  __syncthreads();

  // output: kept entries in sorted order == final top-100
  for (int k = lane; k < PRE; k += 64) {
    int w = k >> 6, b = k & 63;
    u64 kw = s_keep[w];
    if ((kw >> b) & 1ull) {
      unsigned rank = s_pre[w] + (unsigned)__popcll(kw & ((1ull << b) - 1ull));
      if (rank < MAXD) {
        int slot = c * MAXD + (int)rank;
        out_s[slot] = sscore[c * 1024 + k];
        out_id[slot] = (float)c;
        ((float4*)out_b)[slot] = sbox[c * 1024 + k];
        out_d[slot] = dist[sidx[c * 1024 + k]];
      }
    }
  }
  unsigned tk = s_total < (unsigned)MAXD ? s_total : (unsigned)MAXD;
  for (int r2 = (int)tk + lane; r2 < MAXD; r2 += 64) {
    int slot = c * MAXD + r2;
    out_s[slot] = 0.0f;
    out_id[slot] = -1.0f;
    ((float4*)out_b)[slot] = make_float4(0.f, 0.f, 0.f, 0.f);
    out_d[slot] = 0.0f;
  }
}

// =====================================================================
// FALLBACK PATH (round-1, proven correct; used only if ws is too small)
// =====================================================================
#define NBUCK 4096
#define CANDF 2048

__global__ __launch_bounds__(256) void select_topk(
    const float* __restrict__ cls, int A,
    float* __restrict__ topscore, unsigned* __restrict__ topidx)
{
  const int c = blockIdx.x;
  const int t = threadIdx.x;
  __shared__ unsigned hist[NBUCK];
  __shared__ u64 cand[CANDF];
  __shared__ unsigned chunk[256];
  __shared__ int s_cb;
  __shared__ int s_cnt;
  for (int i = t; i < NBUCK; i += 256) hist[i] = 0u;
  if (t == 0) s_cnt = 0;
  __syncthreads();
  for (int a = t; a < A; a += 256) {
    float s = cls[(size_t)a * NCLS + c];
    if (s > THR_SCORE) {
      int b = (int)(s * (float)NBUCK);
      b = b < 0 ? 0 : (b > NBUCK - 1 ? NBUCK - 1 : b);
      atomicAdd(&hist[b], 1u);
    }
  }
  __syncthreads();
  {
    unsigned cs = 0;
    for (int i = 0; i < NBUCK / 256; i++) cs += hist[t * (NBUCK / 256) + i];
    chunk[t] = cs;
  }
  __syncthreads();
  if (t == 0) {
    unsigned acc = 0;
    int cb = 0;
    int ch;
    for (ch = 255; ch >= 0; ch--) {
      if (acc + chunk[ch] >= (unsigned)PRE) break;
      acc += chunk[ch];
    }
    if (ch < 0) cb = 0;
    else {
      const int bpc = NBUCK / 256;
      int b = ch * bpc + bpc - 1;
      for (; b >= ch * bpc; b--) { acc += hist[b]; if (acc >= (unsigned)PRE) break; }
      if (b < ch * bpc) b = ch * bpc;
      cb = b;
      while (acc > (unsigned)CANDF && cb < NBUCK - 1) { acc -= hist[cb]; cb++; }
    }
    s_cb = cb;
  }
  __syncthreads();
  const int cb = s_cb;
  for (int a = t; a < A; a += 256) {
    float s = cls[(size_t)a * NCLS + c];
    if (s > THR_SCORE) {
      int b = (int)(s * (float)NBUCK);
      b = b < 0 ? 0 : (b > NBUCK - 1 ? NBUCK - 1 : b);
      if (b >= cb) {
        int p = atomicAdd(&s_cnt, 1);
        if (p < CANDF)
          cand[p] = ((u64)__float_as_uint(s) << 32) | (u64)(~(unsigned)a);
      }
    }
  }
  __syncthreads();
  int n = s_cnt < CANDF ? s_cnt : CANDF;
  for (int i = n + t; i < CANDF; i += 256) cand[i] = 0ull;
  __syncthreads();
  for (int k = 2; k <= CANDF; k <<= 1) {
    for (int j = k >> 1; j > 0; j >>= 1) {
      for (int i = t; i < CANDF; i += 256) {
        int ixj = i ^ j;
        if (ixj > i) {
          u64 va = cand[i], vb = cand[ixj];
          bool desc = ((i & k) == 0);
          if (desc ? (va < vb) : (va > vb)) { cand[i] = vb; cand[ixj] = va; }
        }
      }
      __syncthreads();
    }
  }
  for (int k = t; k < PRE; k += 256) {
    u64 key = cand[k];
    float sc; unsigned idx;
    if (key != 0ull) { sc = __uint_as_float((unsigned)(key >> 32)); idx = ~((unsigned)(key & 0xFFFFFFFFull)); }
    else { sc = -INFINITY; idx = 0u; }
    topscore[c * PRE + k] = sc;
    topidx[c * PRE + k] = idx;
  }
}

__global__ __launch_bounds__(256) void nms_out(
    const float* __restrict__ anch, const float* __restrict__ reg,
    const float* __restrict__ dist,
    const float* __restrict__ topscore, const unsigned* __restrict__ topidx,
    const int* __restrict__ img_h_p, const int* __restrict__ img_w_p,
    float* __restrict__ out_s, float* __restrict__ out_id,
    float* __restrict__ out_b, float* __restrict__ out_d)
{
#pragma clang fp contract(off)
  const int c = blockIdx.x;
  const int t = threadIdx.x;
  __shared__ float bx[PRE], by[PRE], bX[PRE], bY[PRE], bar[PRE], ssc[PRE];
  __shared__ u64 supm[PRE * 16];
  __shared__ u64 keepw[16];
  __shared__ unsigned wpre[17];
  const float W = (float)img_w_p[0];
  const float H = (float)img_h_p[0];
  for (int k = t; k < PRE; k += 256) {
    float sc = topscore[c * PRE + k];
    unsigned idx = topidx[c * PRE + k];
    ssc[k] = sc;
    float a0 = anch[(size_t)idx * 4 + 0], a1 = anch[(size_t)idx * 4 + 1];
    float a2 = anch[(size_t)idx * 4 + 2], a3 = anch[(size_t)idx * 4 + 3];
    float r0 = reg[(size_t)idx * 4 + 0], r1 = reg[(size_t)idx * 4 + 1];
    float r2 = reg[(size_t)idx * 4 + 2], r3 = reg[(size_t)idx * 4 + 3];
    float w = a2 - a0, h = a3 - a1;
    float cx = a0 + 0.5f * w, cy = a1 + 0.5f * h;
    float dx = r0 * 0.1f, dy = r1 * 0.1f, dw = r2 * 0.2f, dh = r3 * 0.2f;
    float pcx = cx + dx * w, pcy = cy + dy * h;
    float pw = (float)exp((double)dw) * w;
    float ph = (float)exp((double)dh) * h;
    float x1 = fminf(fmaxf(pcx - 0.5f * pw, 0.0f), W);
    float y1 = fminf(fmaxf(pcy - 0.5f * ph, 0.0f), H);
    float x2 = fminf(fmaxf(pcx + 0.5f * pw, 0.0f), W);
    float y2 = fminf(fmaxf(pcy + 0.5f * ph, 0.0f), H);
    bx[k] = x1; by[k] = y1; bX[k] = x2; bY[k] = y2;
    bar[k] = (x2 - x1) * (y2 - y1);
  }
  __syncthreads();
  const int wave = t >> 6, lane = t & 63;
  for (int i = wave; i < PRE; i += 4) {
    float x1 = bx[i], y1 = by[i], X1 = bX[i], Y1 = bY[i], ai = bar[i];
    for (int g = 0; g < 16; g++) {
      int j = g * 64 + lane;
      bool s = false;
      if (j > i && j < PRE) {
        float ltx = fmaxf(x1, bx[j]);
        float lty = fmaxf(y1, by[j]);
        float rbx = fminf(X1, bX[j]);
        float rby = fminf(Y1, bY[j]);
        float ww = fmaxf(rbx - ltx, 0.0f);
        float hh = fmaxf(rby - lty, 0.0f);
        float inter = ww * hh;
        float iou = inter / ((ai + bar[j]) - inter + 1e-8f);
        s = iou > 0.5f;
      }
      u64 m = __ballot(s);
      if (lane == 0) supm[i * 16 + g] = m;
    }
  }
  __syncthreads();
  if (t < 64) {
    u64 kw = 0ull;
    if (t < 16) {
      for (int b = 0; b < 64; b++) {
        int k = t * 64 + b;
        if (k < PRE && ssc[k] != -INFINITY) kw |= (1ull << b);
      }
    }
    for (int i = 0; i < PRE; i++) {
      u64 ow = __shfl(kw, i >> 6);
      if ((ow >> (i & 63)) & 1ull) {
        if (t < 16) kw &= ~supm[i * 16 + t];
      }
    }
    if (t < 16) keepw[t] = kw;
  }
  __syncthreads();
  if (t == 0) {
    unsigned acc = 0;
    for (int w = 0; w < 16; w++) { wpre[w] = acc; acc += (unsigned)__popcll(keepw[w]); }
    wpre[16] = acc;
  }
  __syncthreads();
  const unsigned total = wpre[16];
  for (int k = t; k < PRE; k += 256) {
    int w = k >> 6, b = k & 63;
    u64 kw = keepw[w];
    if ((kw >> b) & 1ull) {
      unsigned rank = wpre[w] + (unsigned)__popcll(kw & ((1ull << b) - 1ull));
      if (rank < MAXD) {
        int slot = c * MAXD + (int)rank;
        out_s[slot] = ssc[k];
        out_id[slot] = (float)c;
        out_b[slot * 4 + 0] = bx[k];
        out_b[slot * 4 + 1] = by[k];
        out_b[slot * 4 + 2] = bX[k];
        out_b[slot * 4 + 3] = bY[k];
        out_d[slot] = dist[topidx[c * PRE + k]];
      }
    }
  }
  unsigned tk = total < MAXD ? total : MAXD;
  for (int r = (int)tk + t; r < MAXD; r += 256) {
    int slot = c * MAXD + r;
    out_s[slot] = 0.0f;
    out_id[slot] = -1.0f;
    out_b[slot * 4 + 0] = 0.0f; out_b[slot * 4 + 1] = 0.0f;
    out_b[slot * 4 + 2] = 0.0f; out_b[slot * 4 + 3] = 0.0f;
    out_d[slot] = 0.0f;
  }
}

// =====================================================================

static inline size_t align512(size_t x) { return (x + 511) & ~(size_t)511; }

extern "C" void kernel_launch(void* const* d_in, const int* in_sizes, int n_in,
                              void* d_out, int out_size, void* d_ws, size_t ws_size,
                              hipStream_t stream) {
  const float* cls  = (const float*)d_in[0];   // (1, A, 80)
  const float* reg  = (const float*)d_in[1];   // (1, A, 4)
  const float* dist = (const float*)d_in[2];   // (1, A, 1)
  const float* anch = (const float*)d_in[3];   // (1, A, 4)
  const int* img_h  = (const int*)d_in[4];
  const int* img_w  = (const int*)d_in[5];
  const int A = in_sizes[3] / 4;

  float* o = (float*)d_out;
  float* out_s  = o;                      // 8000
  float* out_id = o + NCLS * MAXD;        // 8000
  float* out_b  = o + 2 * NCLS * MAXD;    // 32000
  float* out_d  = o + 6 * NCLS * MAXD;    // 8000

  // big region serves sequentially: part (k1->k2), cand (k3->kA)
  const size_t sz_part = (size_t)K1B * BINS * sizeof(unsigned short);        // 10.49 MB
  const size_t sz_cand = (size_t)NCLS * SUBS * SUBCAP * sizeof(u64);         // 5.24 MB
  size_t sz_big = sz_part > sz_cand ? sz_part : sz_cand;
  size_t off = align512(sz_big);
  const size_t o_cb    = off; off += align512(NCLS * sizeof(int));
  const size_t o_ccnt  = off; off += align512((size_t)NCLS * SUBS * sizeof(unsigned));
  const size_t o_sbox  = off; off += align512((size_t)NCLS * 1024 * sizeof(float4));
  const size_t o_sarea = off; off += align512((size_t)NCLS * 1024 * sizeof(float));
  const size_t o_sscr  = off; off += align512((size_t)NCLS * 1024 * sizeof(float));
  const size_t o_sidx  = off; off += align512((size_t)NCLS * 1024 * sizeof(unsigned));
  const size_t needed = off;

  if (ws_size >= needed) {
    char* ws = (char*)d_ws;
    unsigned short* part = (unsigned short*)ws;
    u64* cand = (u64*)ws;
    int* cb = (int*)(ws + o_cb);
    unsigned* ccnt = (unsigned*)(ws + o_ccnt);
    float4* sbox = (float4*)(ws + o_sbox);
    float* sarea = (float*)(ws + o_sarea);
    float* sscr = (float*)(ws + o_sscr);
    unsigned* sidxp = (unsigned*)(ws + o_sidx);
    const int total4 = A * 20;  // A*80/4

    k1_hist<<<K1B, 256, 0, stream>>>((const float4*)cls, total4, part);
    k2_cutoff<<<NCLS, 256, 0, stream>>>(part, cb, ccnt);
    k3_collect<<<K3B, 256, 0, stream>>>((const float4*)cls, total4, cb, ccnt, cand);
    kA_sort_decode<<<NCLS, 1024, 0, stream>>>(ccnt, cand, cb, anch, reg, img_h, img_w,
                                              sbox, sarea, sscr, sidxp);
    kD_nms_out<<<NCLS, 64, 0, stream>>>(sbox, sarea, sscr, sidxp, dist,
                                        out_s, out_id, out_b, out_d);
  } else {
    // fallback: proven round-1 path (needs only ~0.64 MB)
    float* topscore = (float*)d_ws;
    unsigned* topidx = (unsigned*)((char*)d_ws + NCLS * PRE * sizeof(float));
    select_topk<<<NCLS, 256, 0, stream>>>(cls, A, topscore, topidx);
    nms_out<<<NCLS, 256, 0, stream>>>(anch, reg, dist, topscore, topidx,
                                      img_h, img_w, out_s, out_id, out_b, out_d);
  }
}

// Round 9
// 149.379 us; speedup vs baseline: 8.0733x; 1.1016x over previous
//
#include <hip/hip_runtime.h>
#include <math.h>

#define NCLS 80
#define PRE 1000
#define MAXD 100
#define THR_SCORE 0.05f

// ---- fast path config ----
#define NB 128                 // buckets per class (coarse; refined in kAD)
#define BINS (NCLS * NB)       // 10240
#define K1B 512                // histogram blocks (= partial count)
#define SUBS 16                // sub-lists per class
#define SUBCAP 512             // depth per sub-list
#define CSORT 4096             // max candidates per class
#define K3B 2048               // collect blocks

typedef unsigned long long u64;

__device__ __forceinline__ u64 readlane64(u64 v, int l) {
  unsigned lo = (unsigned)__builtin_amdgcn_readlane((int)(unsigned)v, l);
  unsigned hi = (unsigned)__builtin_amdgcn_readlane((int)(unsigned)(v >> 32), l);
  return ((u64)hi << 32) | lo;
}

// =====================================================================
// K1: coalesced float4 pass over cls, per-block LDS hist (80x128), u16 partials.
__global__ __launch_bounds__(256) void k1_hist(
    const float4* __restrict__ cls4, int total4, unsigned short* __restrict__ part)
{
  __shared__ unsigned h[BINS];
  const int t = threadIdx.x;
  for (int i = t; i < BINS; i += 256) h[i] = 0u;
  __syncthreads();
  const int stride = gridDim.x * 256;
  for (int q = blockIdx.x * 256 + t; q < total4; q += stride) {
    float4 v = cls4[q];
    int c0 = 4 * (q % 20);  // (4q) % 80
    float s; int b;
    s = v.x; if (s > THR_SCORE) { b = (int)(s * (float)NB); b = b < 0 ? 0 : (b > NB - 1 ? NB - 1 : b); atomicAdd(&h[(c0 + 0) * NB + b], 1u); }
    s = v.y; if (s > THR_SCORE) { b = (int)(s * (float)NB); b = b < 0 ? 0 : (b > NB - 1 ? NB - 1 : b); atomicAdd(&h[(c0 + 1) * NB + b], 1u); }
    s = v.z; if (s > THR_SCORE) { b = (int)(s * (float)NB); b = b < 0 ? 0 : (b > NB - 1 ? NB - 1 : b); atomicAdd(&h[(c0 + 2) * NB + b], 1u); }
    s = v.w; if (s > THR_SCORE) { b = (int)(s * (float)NB); b = b < 0 ? 0 : (b > NB - 1 ? NB - 1 : b); atomicAdd(&h[(c0 + 3) * NB + b], 1u); }
  }
  __syncthreads();
  unsigned short* p = part + (size_t)blockIdx.x * BINS;
  for (int i = t; i < BINS; i += 256) p[i] = (unsigned short)h[i];
}

// K2: one block per class; reduce K1B partials (128 bins) -> cutoff bucket;
// zero the push counters.
__global__ __launch_bounds__(256) void k2_cutoff(
    const unsigned short* __restrict__ part, int* __restrict__ cb,
    unsigned* __restrict__ ccnt)
{
  const int c = blockIdx.x;
  const int t = threadIdx.x;
  __shared__ unsigned lh[2][NB];
  const int b = t & (NB - 1);
  const int g = t >> 7;
  unsigned acc = 0;
  for (int p = g; p < K1B; p += 2) acc += part[(size_t)p * BINS + c * NB + b];
  lh[g][b] = acc;
  if (t < SUBS) ccnt[c * SUBS + t] = 0u;
  __syncthreads();
  if (t == 0) {
    unsigned a = 0;
    int cbv = 0;
    for (int bb = NB - 1; bb >= 0; bb--) {
      a += lh[0][bb] + lh[1][bb];
      if (a >= (unsigned)PRE) { cbv = bb; break; }
    }
    while (a > (unsigned)CSORT && cbv < NB - 1) { a -= lh[0][cbv] + lh[1][cbv]; cbv++; }
    cb[c] = cbv;
  }
}

// K3: coalesced pass (high occupancy); push candidates above per-class cutoff.
__global__ __launch_bounds__(256) void k3_collect(
    const float4* __restrict__ cls4, int total4, const int* __restrict__ cb,
    unsigned* __restrict__ ccnt, u64* __restrict__ cand)
{
  __shared__ float tcb[NCLS];
  const int t = threadIdx.x;
  if (t < NCLS) tcb[t] = (float)cb[t];
  __syncthreads();
  const int sub = blockIdx.x & (SUBS - 1);
  const int stride = gridDim.x * 256;
  for (int q = blockIdx.x * 256 + t; q < total4; q += stride) {
    float4 v = cls4[q];
    int c0 = 4 * (q % 20);
    unsigned a = (unsigned)(q / 20);
    float sv[4] = {v.x, v.y, v.z, v.w};
#pragma unroll
    for (int e = 0; e < 4; e++) {
      float s = sv[e];
      if (s > THR_SCORE && s * (float)NB >= tcb[c0 + e]) {
        int c = c0 + e;
        unsigned p = atomicAdd(&ccnt[c * SUBS + sub], 1u);
        if (p < SUBCAP)
          cand[((size_t)(c * SUBS + sub)) * SUBCAP + p] =
              ((u64)__float_as_uint(s) << 32) | (u64)(~a);
      }
    }
  }
}

// kAD: per-class gather + refine + hybrid sort + decode (LDS) + early-exit NMS
// + output. One block of 1024 per class.
__global__ __launch_bounds__(1024) void kAD_sort_nms(
    const unsigned* __restrict__ ccnt, const u64* __restrict__ cand,
    const int* __restrict__ cbp,
    const float* __restrict__ anch, const float* __restrict__ reg,
    const float* __restrict__ dist,
    const int* __restrict__ img_h_p, const int* __restrict__ img_w_p,
    float* __restrict__ out_s, float* __restrict__ out_id,
    float* __restrict__ out_b, float* __restrict__ out_d)
{
#pragma clang fp contract(off)
  const int c = blockIdx.x;
  const int t = threadIdx.x;
  const int lane = t & 63;
  __shared__ u64 L[CSORT];             // 32 KB
  __shared__ u64 M[1024];              // 8 KB
  __shared__ float4 box4[1024];        // 16 KB
  __shared__ float area[1024];         // 4 KB
  __shared__ float ssc[1024];          // 4 KB
  __shared__ unsigned sidb[1024];      // 4 KB
  __shared__ unsigned scnt[SUBS];
  __shared__ unsigned sbase[SUBS + 1];
  __shared__ unsigned h2[512];
  __shared__ unsigned s_above;
  __shared__ int s_rsub;
  __shared__ unsigned s_n2;
  __shared__ unsigned s_push;
  __shared__ float fx[192], fy[192], fX[192], fY[192], fA[192];
  __shared__ float wx[64], wy[64], wX[64], wY[64], wA[64];
  __shared__ u64 s_keep[16];
  __shared__ unsigned s_pre[16];
  __shared__ unsigned s_total;

  if (t < SUBS) {
    unsigned n = ccnt[c * SUBS + t];
    scnt[t] = n > SUBCAP ? SUBCAP : n;
  }
  if (t == 0) { s_above = 0; s_push = 0; }
  if (t < 16) { s_keep[t] = 0ull; s_pre[t] = 0u; }
  for (int i = t; i < CSORT; i += 1024) L[i] = 0ull;
  M[t] = 0ull;
  if (t < 512) h2[t] = 0u;
  __syncthreads();
  if (t == 0) {
    unsigned a = 0;
    for (int s = 0; s < SUBS; s++) { sbase[s] = a; a += scnt[s]; }
    sbase[SUBS] = a;
  }
  __syncthreads();
  const unsigned n = sbase[SUBS] <= CSORT ? sbase[SUBS] : CSORT;

  // flat gather of all sub-lists
  for (unsigned g = t; g < n; g += 1024) {
    int s = 0;
    while (g >= sbase[s + 1]) s++;
    L[g] = cand[((size_t)(c * SUBS + s)) * SUBCAP + (g - sbase[s])];
  }
  __syncthreads();

  const int scb = cbp[c];
  u64* SW = L;
  bool fast = true;

  if (n > 1024) {
    // refine: 512-wide sub-bucket histogram of cutoff-bucket elements
    for (unsigned i = t; i < n; i += 1024) {
      float s = __uint_as_float((unsigned)(L[i] >> 32));
      int b = (int)(s * (float)NB);
      b = b < 0 ? 0 : (b > NB - 1 ? NB - 1 : b);
      bool abv = (b > scb);
      u64 mask = __ballot(abv);
      if (abv) {
        if (lane == __builtin_ctzll(mask)) atomicAdd(&s_above, (unsigned)__popcll(mask));
      } else {
        int sub = (int)(s * 65536.0f) - scb * 512;
        sub = sub < 0 ? 0 : (sub > 511 ? 511 : sub);
        atomicAdd(&h2[sub], 1u);
      }
    }
    __syncthreads();
    if (t == 0) {
      unsigned a = s_above;
      int r = 512;
      if (a < (unsigned)PRE) {
        for (int b2 = 511; b2 >= 0; b2--) {
          a += h2[b2];
          if (a >= (unsigned)PRE) { r = b2; break; }
        }
        if (a < (unsigned)PRE) r = 0;  // take all
      }
      s_rsub = r;
      s_n2 = a;
    }
    __syncthreads();
    if (s_n2 <= 1024u) {
      const int rsub = s_rsub;
      for (unsigned i = t; i < n; i += 1024) {
        u64 key = L[i];
        float s = __uint_as_float((unsigned)(key >> 32));
        int b = (int)(s * (float)NB);
        b = b < 0 ? 0 : (b > NB - 1 ? NB - 1 : b);
        bool take;
        if (b > scb) take = true;
        else {
          int sub = (int)(s * 65536.0f) - scb * 512;
          sub = sub < 0 ? 0 : (sub > 511 ? 511 : sub);
          take = (sub >= rsub);
        }
        u64 mask = __ballot(take);
        if (take) {
          unsigned base;
          int leader = __builtin_ctzll(mask);
          if (lane == leader) base = atomicAdd(&s_push, (unsigned)__popcll(mask));
          base = (unsigned)__shfl((int)base, leader);
          unsigned p = base + (unsigned)__popcll(mask & ((1ull << lane) - 1ull));
          if (p < 1024u) M[p] = key;
        }
      }
      __syncthreads();
      SW = M;
    } else {
      fast = false;  // adversarial: full 4096 sort
    }
  }

  if (fast) {
    // ---- hybrid bitonic sort of 1024, descending ----
    // phase 0: per-wave register sort of each 64-run.
    // NOTE: direction must come from the GLOBAL index t (not lane) so the
    // k=64 level alternates per 64-block — required for the k=128 merge input
    // to be bitonic (round-8 bug: used lane, every run sorted descending).
    u64 v = SW[t];
#pragma unroll
    for (int k = 2; k <= 64; k <<= 1) {
#pragma unroll
      for (int j = k >> 1; j > 0; j >>= 1) {
        u64 p = __shfl_xor(v, j);
        bool iLower = (lane & j) == 0;
        bool desc = (t & k) == 0;
        bool keepMax = (iLower == desc);
        bool pGreater = p > v;
        v = (keepMax == pGreater) ? p : v;
      }
    }
    SW[t] = v;
    __syncthreads();
    // merge levels k=128..1024
    for (int k = 128; k <= 1024; k <<= 1) {
      for (int j = k >> 1; j >= 64; j >>= 1) {
        if ((t & j) == 0) {
          u64 a = SW[t], b = SW[t ^ j];
          bool desc = ((t & k) == 0);
          if (desc ? (a < b) : (a > b)) { SW[t] = b; SW[t ^ j] = a; }
        }
        __syncthreads();
      }
      u64 v2 = SW[t];
      bool desc = ((t & k) == 0);  // wave-uniform (k >= 128)
#pragma unroll
      for (int j = 32; j > 0; j >>= 1) {
        u64 p = __shfl_xor(v2, j);
        bool iLower = (lane & j) == 0;
        bool keepMax = (iLower == desc);
        bool pGreater = p > v2;
        v2 = (keepMax == pGreater) ? p : v2;
      }
      SW[t] = v2;
      __syncthreads();
    }
  } else {
    // legacy full bitonic over CSORT
    for (int k = 2; k <= CSORT; k <<= 1) {
      for (int j = k >> 1; j > 0; j >>= 1) {
        for (int i = t; i < CSORT; i += 1024) {
          int ixj = i ^ j;
          if (ixj > i) {
            u64 va = SW[i], vb = SW[ixj];
            bool desc = ((i & k) == 0);
            if (desc ? (va < vb) : (va > vb)) { SW[i] = vb; SW[ixj] = va; }
          }
        }
        __syncthreads();
      }
    }
  }

  // ---- decode into LDS ----
  const float W = (float)img_w_p[0];
  const float H = (float)img_h_p[0];
  const float4* a4 = (const float4*)anch;
  const float4* r4 = (const float4*)reg;
  if (t < PRE) {
    u64 key = SW[t];
    float sc; unsigned idx;
    if (key != 0ull) {
      sc = __uint_as_float((unsigned)(key >> 32));
      idx = ~((unsigned)(key & 0xFFFFFFFFull));
    } else {
      sc = -INFINITY; idx = 0u;
    }
    float4 av = a4[idx];
    float4 rv = r4[idx];
    float w = av.z - av.x, h = av.w - av.y;
    float cx = av.x + 0.5f * w, cy = av.y + 0.5f * h;
    float dx = rv.x * 0.1f, dy = rv.y * 0.1f, dw = rv.z * 0.2f, dh = rv.w * 0.2f;
    float pcx = cx + dx * w, pcy = cy + dy * h;
    float pw = (float)exp((double)dw) * w;
    float ph = (float)exp((double)dh) * h;
    float x1 = fminf(fmaxf(pcx - 0.5f * pw, 0.0f), W);
    float y1 = fminf(fmaxf(pcy - 0.5f * ph, 0.0f), H);
    float x2 = fminf(fmaxf(pcx + 0.5f * pw, 0.0f), W);
    float y2 = fminf(fmaxf(pcy + 0.5f * ph, 0.0f), H);
    box4[t] = make_float4(x1, y1, x2, y2);
    area[t] = (x2 - x1) * (y2 - y1);
    ssc[t] = sc;
    sidb[t] = idx;
  } else {
    box4[t] = make_float4(0.f, 0.f, 0.f, 0.f);
    area[t] = 0.f;
    ssc[t] = -INFINITY;
    sidb[t] = 0u;
  }
  __syncthreads();

  // ---- NMS with early exit (wave 0 only; no barriers: single-wave LDS order) ----
  if (t < 64) {
    const double MID = 0x1.000001p-1;
    unsigned acc = 0;
    int nf = 0;
    for (int w = 0; w < 16; w++) {
      const int r = w * 64 + lane;
      const float4 rb = box4[r];
      const float ra = area[r];
      bool dead = (ssc[r] == -INFINITY);
      for (int f = 0; f < nf; f++) {
        float ltx = fmaxf(rb.x, fx[f]);
        float lty = fmaxf(rb.y, fy[f]);
        float rbx = fminf(rb.z, fX[f]);
        float rby = fminf(rb.w, fY[f]);
        float ww = fmaxf(rbx - ltx, 0.0f);
        float hh = fmaxf(rby - lty, 0.0f);
        float inter = ww * hh;
        float denom = ((ra + fA[f]) - inter) + 1e-8f;
        dead = dead | ((double)inter > MID * (double)denom);
      }
      u64 alive = __ballot(!dead);
      u64 F = 0ull;
      if (alive) {
        wx[lane] = rb.x; wy[lane] = rb.y; wX[lane] = rb.z; wY[lane] = rb.w; wA[lane] = ra;
        u64 Rw = 0ull;
#pragma unroll 4
        for (int i = 0; i < 64; i++) {
          float ltx = fmaxf(wx[i], rb.x);
          float lty = fmaxf(wy[i], rb.y);
          float rbx = fminf(wX[i], rb.z);
          float rby = fminf(wY[i], rb.w);
          float ww = fmaxf(rbx - ltx, 0.0f);
          float hh = fmaxf(rby - lty, 0.0f);
          float inter = ww * hh;
          float denom = ((wA[i] + ra) - inter) + 1e-8f;
          bool io = (double)inter > MID * (double)denom;
          u64 m = __ballot(io & (lane > i));
          Rw = (lane == i) ? m : Rw;
        }
        while (alive) {
          int b = __builtin_ctzll(alive);
          F |= (1ull << b);
          u64 rbw = readlane64(Rw, b);
          alive &= ~(rbw | (1ull << b));
        }
        if ((F >> lane) & 1ull) {
          int pos = nf + (int)__popcll(F & ((1ull << lane) - 1ull));
          if (pos < 192) {
            fx[pos] = rb.x; fy[pos] = rb.y; fX[pos] = rb.z; fY[pos] = rb.w; fA[pos] = ra;
          }
        }
      }
      if (lane == 0) { s_keep[w] = F; s_pre[w] = acc; }
      acc += (unsigned)__popcll(F);
      nf += (int)__popcll(F);
      if (acc >= (unsigned)MAXD) break;
    }
    if (lane == 0) s_total = acc;
  }
  __syncthreads();

  // ---- output ----
  const unsigned total = s_total;
  if (t < PRE) {
    int w = t >> 6, b = t & 63;
    u64 kw = s_keep[w];
    if ((kw >> b) & 1ull) {
      unsigned rank = s_pre[w] + (unsigned)__popcll(kw & ((1ull << b) - 1ull));
      if (rank < MAXD) {
        int slot = c * MAXD + (int)rank;
        out_s[slot] = ssc[t];
        out_id[slot] = (float)c;
        ((float4*)out_b)[slot] = box4[t];
        out_d[slot] = dist[sidb[t]];
      }
    }
  }
  unsigned tk = total < (unsigned)MAXD ? total : (unsigned)MAXD;
  for (int r2 = (int)tk + t; r2 < MAXD; r2 += 1024) {
    int slot = c * MAXD + r2;
    out_s[slot] = 0.0f;
    out_id[slot] = -1.0f;
    ((float4*)out_b)[slot] = make_float4(0.f, 0.f, 0.f, 0.f);
    out_d[slot] = 0.0f;
  }
}

// =====================================================================
// FALLBACK PATH (round-1, proven correct; used only if ws is too small)
// =====================================================================
#define NBUCK 4096
#define CANDF 2048

__global__ __launch_bounds__(256) void select_topk(
    const float* __restrict__ cls, int A,
    float* __restrict__ topscore, unsigned* __restrict__ topidx)
{
  const int c = blockIdx.x;
  const int t = threadIdx.x;
  __shared__ unsigned hist[NBUCK];
  __shared__ u64 cand[CANDF];
  __shared__ unsigned chunk[256];
  __shared__ int s_cb;
  __shared__ int s_cnt;
  for (int i = t; i < NBUCK; i += 256) hist[i] = 0u;
  if (t == 0) s_cnt = 0;
  __syncthreads();
  for (int a = t; a < A; a += 256) {
    float s = cls[(size_t)a * NCLS + c];
    if (s > THR_SCORE) {
      int b = (int)(s * (float)NBUCK);
      b = b < 0 ? 0 : (b > NBUCK - 1 ? NBUCK - 1 : b);
      atomicAdd(&hist[b], 1u);
    }
  }
  __syncthreads();
  {
    unsigned cs = 0;
    for (int i = 0; i < NBUCK / 256; i++) cs += hist[t * (NBUCK / 256) + i];
    chunk[t] = cs;
  }
  __syncthreads();
  if (t == 0) {
    unsigned acc = 0;
    int cb = 0;
    int ch;
    for (ch = 255; ch >= 0; ch--) {
      if (acc + chunk[ch] >= (unsigned)PRE) break;
      acc += chunk[ch];
    }
    if (ch < 0) cb = 0;
    else {
      const int bpc = NBUCK / 256;
      int b = ch * bpc + bpc - 1;
      for (; b >= ch * bpc; b--) { acc += hist[b]; if (acc >= (unsigned)PRE) break; }
      if (b < ch * bpc) b = ch * bpc;
      cb = b;
      while (acc > (unsigned)CANDF && cb < NBUCK - 1) { acc -= hist[cb]; cb++; }
    }
    s_cb = cb;
  }
  __syncthreads();
  const int cb = s_cb;
  for (int a = t; a < A; a += 256) {
    float s = cls[(size_t)a * NCLS + c];
    if (s > THR_SCORE) {
      int b = (int)(s * (float)NBUCK);
      b = b < 0 ? 0 : (b > NBUCK - 1 ? NBUCK - 1 : b);
      if (b >= cb) {
        int p = atomicAdd(&s_cnt, 1);
        if (p < CANDF)
          cand[p] = ((u64)__float_as_uint(s) << 32) | (u64)(~(unsigned)a);
      }
    }
  }
  __syncthreads();
  int n = s_cnt < CANDF ? s_cnt : CANDF;
  for (int i = n + t; i < CANDF; i += 256) cand[i] = 0ull;
  __syncthreads();
  for (int k = 2; k <= CANDF; k <<= 1) {
    for (int j = k >> 1; j > 0; j >>= 1) {
      for (int i = t; i < CANDF; i += 256) {
        int ixj = i ^ j;
        if (ixj > i) {
          u64 va = cand[i], vb = cand[ixj];
          bool desc = ((i & k) == 0);
          if (desc ? (va < vb) : (va > vb)) { cand[i] = vb; cand[ixj] = va; }
        }
      }
      __syncthreads();
    }
  }
  for (int k = t; k < PRE; k += 256) {
    u64 key = cand[k];
    float sc; unsigned idx;
    if (key != 0ull) { sc = __uint_as_float((unsigned)(key >> 32)); idx = ~((unsigned)(key & 0xFFFFFFFFull)); }
    else { sc = -INFINITY; idx = 0u; }
    topscore[c * PRE + k] = sc;
    topidx[c * PRE + k] = idx;
  }
}

__global__ __launch_bounds__(256) void nms_out(
    const float* __restrict__ anch, const float* __restrict__ reg,
    const float* __restrict__ dist,
    const float* __restrict__ topscore, const unsigned* __restrict__ topidx,
    const int* __restrict__ img_h_p, const int* __restrict__ img_w_p,
    float* __restrict__ out_s, float* __restrict__ out_id,
    float* __restrict__ out_b, float* __restrict__ out_d)
{
#pragma clang fp contract(off)
  const int c = blockIdx.x;
  const int t = threadIdx.x;
  __shared__ float bx[PRE], by[PRE], bX[PRE], bY[PRE], bar[PRE], ssc[PRE];
  __shared__ u64 supm[PRE * 16];
  __shared__ u64 keepw[16];
  __shared__ unsigned wpre[17];
  const float W = (float)img_w_p[0];
  const float H = (float)img_h_p[0];
  for (int k = t; k < PRE; k += 256) {
    float sc = topscore[c * PRE + k];
    unsigned idx = topidx[c * PRE + k];
    ssc[k] = sc;
    float a0 = anch[(size_t)idx * 4 + 0], a1 = anch[(size_t)idx * 4 + 1];
    float a2 = anch[(size_t)idx * 4 + 2], a3 = anch[(size_t)idx * 4 + 3];
    float r0 = reg[(size_t)idx * 4 + 0], r1 = reg[(size_t)idx * 4 + 1];
    float r2 = reg[(size_t)idx * 4 + 2], r3 = reg[(size_t)idx * 4 + 3];
    float w = a2 - a0, h = a3 - a1;
    float cx = a0 + 0.5f * w, cy = a1 + 0.5f * h;
    float dx = r0 * 0.1f, dy = r1 * 0.1f, dw = r2 * 0.2f, dh = r3 * 0.2f;
    float pcx = cx + dx * w, pcy = cy + dy * h;
    float pw = (float)exp((double)dw) * w;
    float ph = (float)exp((double)dh) * h;
    float x1 = fminf(fmaxf(pcx - 0.5f * pw, 0.0f), W);
    float y1 = fminf(fmaxf(pcy - 0.5f * ph, 0.0f), H);
    float x2 = fminf(fmaxf(pcx + 0.5f * pw, 0.0f), W);
    float y2 = fminf(fmaxf(pcy + 0.5f * ph, 0.0f), H);
    bx[k] = x1; by[k] = y1; bX[k] = x2; bY[k] = y2;
    bar[k] = (x2 - x1) * (y2 - y1);
  }
  __syncthreads();
  const int wave = t >> 6, lane = t & 63;
  for (int i = wave; i < PRE; i += 4) {
    float x1 = bx[i], y1 = by[i], X1 = bX[i], Y1 = bY[i], ai = bar[i];
    for (int g = 0; g < 16; g++) {
      int j = g * 64 + lane;
      bool s = false;
      if (j > i && j < PRE) {
        float ltx = fmaxf(x1, bx[j]);
        float lty = fmaxf(y1, by[j]);
        float rbx = fminf(X1, bX[j]);
        float rby = fminf(Y1, bY[j]);
        float ww = fmaxf(rbx - ltx, 0.0f);
        float hh = fmaxf(rby - lty, 0.0f);
        float inter = ww * hh;
        float iou = inter / ((ai + bar[j]) - inter + 1e-8f);
        s = iou > 0.5f;
      }
      u64 m = __ballot(s);
      if (lane == 0) supm[i * 16 + g] = m;
    }
  }
  __syncthreads();
  if (t < 64) {
    u64 kw = 0ull;
    if (t < 16) {
      for (int b = 0; b < 64; b++) {
        int k = t * 64 + b;
        if (k < PRE && ssc[k] != -INFINITY) kw |= (1ull << b);
      }
    }
    for (int i = 0; i < PRE; i++) {
      u64 ow = __shfl(kw, i >> 6);
      if ((ow >> (i & 63)) & 1ull) {
        if (t < 16) kw &= ~supm[i * 16 + t];
      }
    }
    if (t < 16) keepw[t] = kw;
  }
  __syncthreads();
  if (t == 0) {
    unsigned acc = 0;
    for (int w = 0; w < 16; w++) { wpre[w] = acc; acc += (unsigned)__popcll(keepw[w]); }
    wpre[16] = acc;
  }
  __syncthreads();
  const unsigned total = wpre[16];
  for (int k = t; k < PRE; k += 256) {
    int w = k >> 6, b = k & 63;
    u64 kw = keepw[w];
    if ((kw >> b) & 1ull) {
      unsigned rank = wpre[w] + (unsigned)__popcll(kw & ((1ull << b) - 1ull));
      if (rank < MAXD) {
        int slot = c * MAXD + (int)rank;
        out_s[slot] = ssc[k];
        out_id[slot] = (float)c;
        out_b[slot * 4 + 0] = bx[k];
        out_b[slot * 4 + 1] = by[k];
        out_b[slot * 4 + 2] = bX[k];
        out_b[slot * 4 + 3] = bY[k];
        out_d[slot] = dist[topidx[c * PRE + k]];
      }
    }
  }
  unsigned tk = total < MAXD ? total : MAXD;
  for (int r = (int)tk + t; r < MAXD; r += 256) {
    int slot = c * MAXD + r;
    out_s[slot] = 0.0f;
    out_id[slot] = -1.0f;
    out_b[slot * 4 + 0] = 0.0f; out_b[slot * 4 + 1] = 0.0f;
    out_b[slot * 4 + 2] = 0.0f; out_b[slot * 4 + 3] = 0.0f;
    out_d[slot] = 0.0f;
  }
}

// =====================================================================

static inline size_t align512(size_t x) { return (x + 511) & ~(size_t)511; }

extern "C" void kernel_launch(void* const* d_in, const int* in_sizes, int n_in,
                              void* d_out, int out_size, void* d_ws, size_t ws_size,
                              hipStream_t stream) {
  const float* cls  = (const float*)d_in[0];   // (1, A, 80)
  const float* reg  = (const float*)d_in[1];   // (1, A, 4)
  const float* dist = (const float*)d_in[2];   // (1, A, 1)
  const float* anch = (const float*)d_in[3];   // (1, A, 4)
  const int* img_h  = (const int*)d_in[4];
  const int* img_w  = (const int*)d_in[5];
  const int A = in_sizes[3] / 4;

  float* o = (float*)d_out;
  float* out_s  = o;                      // 8000
  float* out_id = o + NCLS * MAXD;        // 8000
  float* out_b  = o + 2 * NCLS * MAXD;    // 32000
  float* out_d  = o + 6 * NCLS * MAXD;    // 8000

  // big region serves sequentially: part (k1->k2), cand (k3->kAD)
  const size_t sz_part = (size_t)K1B * BINS * sizeof(unsigned short);        // 10.49 MB
  const size_t sz_cand = (size_t)NCLS * SUBS * SUBCAP * sizeof(u64);         // 5.24 MB
  size_t sz_big = sz_part > sz_cand ? sz_part : sz_cand;
  size_t off = align512(sz_big);
  const size_t o_cb    = off; off += align512(NCLS * sizeof(int));
  const size_t o_ccnt  = off; off += align512((size_t)NCLS * SUBS * sizeof(unsigned));
  const size_t needed = off;

  if (ws_size >= needed) {
    char* ws = (char*)d_ws;
    unsigned short* part = (unsigned short*)ws;
    u64* cand = (u64*)ws;
    int* cb = (int*)(ws + o_cb);
    unsigned* ccnt = (unsigned*)(ws + o_ccnt);
    const int total4 = A * 20;  // A*80/4

    k1_hist<<<K1B, 256, 0, stream>>>((const float4*)cls, total4, part);
    k2_cutoff<<<NCLS, 256, 0, stream>>>(part, cb, ccnt);
    k3_collect<<<K3B, 256, 0, stream>>>((const float4*)cls, total4, cb, ccnt, cand);
    kAD_sort_nms<<<NCLS, 1024, 0, stream>>>(ccnt, cand, cb, anch, reg, dist,
                                            img_h, img_w, out_s, out_id, out_b, out_d);
  } else {
    // fallback: proven round-1 path (needs only ~0.64 MB)
    float* topscore = (float*)d_ws;
    unsigned* topidx = (unsigned*)((char*)d_ws + NCLS * PRE * sizeof(float));
    select_topk<<<NCLS, 256, 0, stream>>>(cls, A, topscore, topidx);
    nms_out<<<NCLS, 256, 0, stream>>>(anch, reg, dist, topscore, topidx,
                                      img_h, img_w, out_s, out_id, out_b, out_d);
  }
}

// Round 10
// 128.635 us; speedup vs baseline: 9.3752x; 1.1613x over previous
//
#include <hip/hip_runtime.h>
#include <math.h>

#define NCLS 80
#define PRE 1000
#define MAXD 100
#define THR_SCORE 0.05f

// ---- fast path config ----
#define NB 128                 // buckets per class (coarse; refined in kAD)
#define BINS (NCLS * NB)       // 10240
#define K1B 512                // histogram blocks (= partial count)
#define SUBS 16                // sub-lists per class
#define SUBCAP 512             // depth per sub-list
#define CSORT 4096             // max candidates per class
#define K3B 2048               // collect blocks
#define BT 512                 // kAD block threads

typedef unsigned long long u64;

__device__ __forceinline__ u64 readlane64(u64 v, int l) {
  unsigned lo = (unsigned)__builtin_amdgcn_readlane((int)(unsigned)v, l);
  unsigned hi = (unsigned)__builtin_amdgcn_readlane((int)(unsigned)(v >> 32), l);
  return ((u64)hi << 32) | lo;
}

// =====================================================================
// K1: coalesced float4 pass over cls, per-block LDS hist (80x128), u16 partials.
__global__ __launch_bounds__(256) void k1_hist(
    const float4* __restrict__ cls4, int total4, unsigned short* __restrict__ part)
{
  __shared__ unsigned h[BINS];
  const int t = threadIdx.x;
  for (int i = t; i < BINS; i += 256) h[i] = 0u;
  __syncthreads();
  const int stride = gridDim.x * 256;
  for (int q = blockIdx.x * 256 + t; q < total4; q += stride) {
    float4 v = cls4[q];
    int c0 = 4 * (q % 20);  // (4q) % 80
    float s; int b;
    s = v.x; if (s > THR_SCORE) { b = (int)(s * (float)NB); b = b < 0 ? 0 : (b > NB - 1 ? NB - 1 : b); atomicAdd(&h[(c0 + 0) * NB + b], 1u); }
    s = v.y; if (s > THR_SCORE) { b = (int)(s * (float)NB); b = b < 0 ? 0 : (b > NB - 1 ? NB - 1 : b); atomicAdd(&h[(c0 + 1) * NB + b], 1u); }
    s = v.z; if (s > THR_SCORE) { b = (int)(s * (float)NB); b = b < 0 ? 0 : (b > NB - 1 ? NB - 1 : b); atomicAdd(&h[(c0 + 2) * NB + b], 1u); }
    s = v.w; if (s > THR_SCORE) { b = (int)(s * (float)NB); b = b < 0 ? 0 : (b > NB - 1 ? NB - 1 : b); atomicAdd(&h[(c0 + 3) * NB + b], 1u); }
  }
  __syncthreads();
  unsigned short* p = part + (size_t)blockIdx.x * BINS;
  for (int i = t; i < BINS; i += 256) p[i] = (unsigned short)h[i];
}

// K2: one block per class; reduce K1B partials (128 bins) -> cutoff bucket;
// zero the push counters.
__global__ __launch_bounds__(256) void k2_cutoff(
    const unsigned short* __restrict__ part, int* __restrict__ cb,
    unsigned* __restrict__ ccnt)
{
  const int c = blockIdx.x;
  const int t = threadIdx.x;
  __shared__ unsigned lh[2][NB];
  const int b = t & (NB - 1);
  const int g = t >> 7;
  unsigned acc = 0;
  for (int p = g; p < K1B; p += 2) acc += part[(size_t)p * BINS + c * NB + b];
  lh[g][b] = acc;
  if (t < SUBS) ccnt[c * SUBS + t] = 0u;
  __syncthreads();
  if (t == 0) {
    unsigned a = 0;
    int cbv = 0;
    for (int bb = NB - 1; bb >= 0; bb--) {
      a += lh[0][bb] + lh[1][bb];
      if (a >= (unsigned)PRE) { cbv = bb; break; }
    }
    while (a > (unsigned)CSORT && cbv < NB - 1) { a -= lh[0][cbv] + lh[1][cbv]; cbv++; }
    cb[c] = cbv;
  }
}

// K3: coalesced pass (high occupancy); push candidates above per-class cutoff.
__global__ __launch_bounds__(256) void k3_collect(
    const float4* __restrict__ cls4, int total4, const int* __restrict__ cb,
    unsigned* __restrict__ ccnt, u64* __restrict__ cand)
{
  __shared__ float tcb[NCLS];
  const int t = threadIdx.x;
  if (t < NCLS) tcb[t] = (float)cb[t];
  __syncthreads();
  const int sub = blockIdx.x & (SUBS - 1);
  const int stride = gridDim.x * 256;
  for (int q = blockIdx.x * 256 + t; q < total4; q += stride) {
    float4 v = cls4[q];
    int c0 = 4 * (q % 20);
    unsigned a = (unsigned)(q / 20);
    float sv[4] = {v.x, v.y, v.z, v.w};
#pragma unroll
    for (int e = 0; e < 4; e++) {
      float s = sv[e];
      if (s > THR_SCORE && s * (float)NB >= tcb[c0 + e]) {
        int c = c0 + e;
        unsigned p = atomicAdd(&ccnt[c * SUBS + sub], 1u);
        if (p < SUBCAP)
          cand[((size_t)(c * SUBS + sub)) * SUBCAP + p] =
              ((u64)__float_as_uint(s) << 32) | (u64)(~a);
      }
    }
  }
}

// NMS over sorted rows in LDS; wave 0 of the block (caller guards t<64).
__device__ __forceinline__ void nms_scan64(
    int windows, const float4* box4, const float* area, const float* ssc,
    float* fx, float* fy, float* fXX, float* fYY, float* fAA,
    float* wx, float* wy, float* wXX, float* wYY, float* wAA,
    u64* s_keep, unsigned* s_pre, unsigned* s_total, int lane)
{
#pragma clang fp contract(off)
  const double MID = 0x1.000001p-1;
  unsigned acc = 0;
  int nf = 0;
  for (int w = 0; w < windows; w++) {
    const int r = w * 64 + lane;
    const float4 rb = box4[r];
    const float ra = area[r];
    bool dead = (ssc[r] == -INFINITY);
    for (int f = 0; f < nf; f++) {
      float ltx = fmaxf(rb.x, fx[f]);
      float lty = fmaxf(rb.y, fy[f]);
      float rbx = fminf(rb.z, fXX[f]);
      float rby = fminf(rb.w, fYY[f]);
      float ww = fmaxf(rbx - ltx, 0.0f);
      float hh = fmaxf(rby - lty, 0.0f);
      float inter = ww * hh;
      float denom = ((ra + fAA[f]) - inter) + 1e-8f;
      dead = dead | ((double)inter > MID * (double)denom);
    }
    u64 alive = __ballot(!dead);
    u64 F = 0ull;
    if (alive) {
      wx[lane] = rb.x; wy[lane] = rb.y; wXX[lane] = rb.z; wYY[lane] = rb.w; wAA[lane] = ra;
      u64 Rw = 0ull;
#pragma unroll 4
      for (int i = 0; i < 64; i++) {
        float ltx = fmaxf(wx[i], rb.x);
        float lty = fmaxf(wy[i], rb.y);
        float rbx = fminf(wXX[i], rb.z);
        float rby = fminf(wYY[i], rb.w);
        float ww = fmaxf(rbx - ltx, 0.0f);
        float hh = fmaxf(rby - lty, 0.0f);
        float inter = ww * hh;
        float denom = ((wAA[i] + ra) - inter) + 1e-8f;
        bool io = (double)inter > MID * (double)denom;
        u64 m = __ballot(io & (lane > i));
        Rw = (lane == i) ? m : Rw;
      }
      while (alive) {
        int b = __builtin_ctzll(alive);
        F |= (1ull << b);
        u64 rbw = readlane64(Rw, b);
        alive &= ~(rbw | (1ull << b));
      }
      if ((F >> lane) & 1ull) {
        int pos = nf + (int)__popcll(F & ((1ull << lane) - 1ull));
        if (pos < 192) {
          fx[pos] = rb.x; fy[pos] = rb.y; fXX[pos] = rb.z; fYY[pos] = rb.w; fAA[pos] = ra;
        }
      }
    }
    if (lane == 0) { s_keep[w] = F; s_pre[w] = acc; }
    acc += (unsigned)__popcll(F);
    nf += (int)__popcll(F);
    if (acc >= (unsigned)MAXD) break;
  }
  if (lane == 0) *s_total = acc;
}

// kAD: gather + exact top-prefix (bit-hist) + sort-512 + decode + early-exit NMS,
// with full-path fallback (refine-1024 / legacy-4096) when the prefix is not
// provably sufficient. One block of 512 per class.
__global__ __launch_bounds__(BT) void kAD_sort_nms(
    const unsigned* __restrict__ ccnt, const u64* __restrict__ cand,
    const int* __restrict__ cbp,
    const float* __restrict__ anch, const float* __restrict__ reg,
    const float* __restrict__ dist,
    const int* __restrict__ img_h_p, const int* __restrict__ img_w_p,
    float* __restrict__ out_s, float* __restrict__ out_id,
    float* __restrict__ out_b, float* __restrict__ out_d)
{
#pragma clang fp contract(off)
  const int c = blockIdx.x;
  const int t = threadIdx.x;
  const int lane = t & 63;
  __shared__ u64 L[CSORT];             // 32 KB
  __shared__ u64 M[1024];              // 8 KB
  __shared__ float4 box4[1024];        // 16 KB
  __shared__ float area[1024];
  __shared__ float ssc[1024];
  __shared__ unsigned sidb[1024];
  __shared__ unsigned scnt[SUBS];
  __shared__ unsigned sbase[SUBS + 1];
  __shared__ unsigned h2[512];
  __shared__ unsigned s_above;
  __shared__ int s_rsub;
  __shared__ unsigned s_n2;
  __shared__ unsigned s_push;
  __shared__ int s_mode;               // 0 = fast over L (n<=512), 1 = fast over M, 2 = full
  __shared__ unsigned s_thr;           // u-bit threshold for mode 1
  __shared__ unsigned s_rows;          // real rows in fast prefix
  __shared__ float fx[192], fy[192], fX[192], fY[192], fA[192];
  __shared__ float wx[64], wy[64], wX[64], wY[64], wA[64];
  __shared__ u64 s_keep[16];
  __shared__ unsigned s_pre[16];
  __shared__ unsigned s_total;

  if (t < SUBS) {
    unsigned nn = ccnt[c * SUBS + t];
    scnt[t] = nn > SUBCAP ? SUBCAP : nn;
  }
  if (t == 0) { s_above = 0; s_push = 0; }
  if (t < 16) { s_keep[t] = 0ull; s_pre[t] = 0u; }
  for (int i = t; i < CSORT; i += BT) L[i] = 0ull;
  for (int i = t; i < 1024; i += BT) M[i] = 0ull;
  h2[t] = 0u;
  __syncthreads();
  if (t == 0) {
    unsigned a = 0;
    for (int s = 0; s < SUBS; s++) { sbase[s] = a; a += scnt[s]; }
    sbase[SUBS] = a;
  }
  __syncthreads();
  const unsigned n = sbase[SUBS] <= CSORT ? sbase[SUBS] : CSORT;

  // flat gather of all sub-lists
  for (unsigned g = t; g < n; g += BT) {
    int s = 0;
    while (g >= sbase[s + 1]) s++;
    L[g] = cand[((size_t)(c * SUBS + s)) * SUBCAP + (g - sbase[s])];
  }
  __syncthreads();

  // ---- mode decision ----
  if (n <= 512) {
    if (t == 0) { s_mode = 0; s_rows = n; }
  } else {
    // integer histogram on float bits: u in [0x3F600000, 0x3F800000) -> 512 bins
    for (unsigned i = t; i < n; i += BT) {
      unsigned u = (unsigned)(L[i] >> 32);
      if (u >= 0x3F800000u) atomicAdd(&s_above, 1u);
      else if (u >= 0x3F600000u) atomicAdd(&h2[(u - 0x3F600000u) >> 12], 1u);
    }
    __syncthreads();
    if (t == 0) {
      unsigned a = s_above;
      int r = 512;
      if (a < 256u) {
        for (int b = 511; b >= 0; b--) {
          a += h2[b];
          if (a >= 256u) { r = b; break; }
        }
        if (a < 256u) r = 0;
      }
      s_thr = 0x3F600000u + ((unsigned)r << 12);
      s_rows = a;                            // count with u >= s_thr
      s_mode = (a > 0u && a <= 512u) ? 1 : 2;
    }
  }
  __syncthreads();
  const int mode = s_mode;
  bool done = false;

  const float W = (float)img_w_p[0];
  const float H = (float)img_h_p[0];
  const float4* a4 = (const float4*)anch;
  const float4* r4 = (const float4*)reg;

  if (mode < 2) {
    u64* SW = (mode == 0) ? L : M;
    if (mode == 1) {
      const unsigned thr = s_thr;
      for (unsigned i = t; i < n; i += BT) {
        u64 key = L[i];
        if ((unsigned)(key >> 32) >= thr) {
          unsigned p = atomicAdd(&s_push, 1u);
          if (p < 1024u) M[p] = key;        // p < s_rows <= 512
        }
      }
      __syncthreads();
    }
    // ---- hybrid bitonic sort of 512 descending (1 elem/thread) ----
    {
      u64 v = SW[t];
#pragma unroll
      for (int k = 2; k <= 64; k <<= 1) {
#pragma unroll
        for (int j = k >> 1; j > 0; j >>= 1) {
          u64 p = __shfl_xor(v, j);
          bool iLower = (lane & j) == 0;
          bool desc = (t & k) == 0;
          bool keepMax = (iLower == desc);
          bool pGreater = p > v;
          v = (keepMax == pGreater) ? p : v;
        }
      }
      SW[t] = v;
      __syncthreads();
      for (int k = 128; k <= 512; k <<= 1) {
        for (int j = k >> 1; j >= 64; j >>= 1) {
          if ((t & j) == 0) {
            u64 a = SW[t], b = SW[t ^ j];
            bool desc = ((t & k) == 0);
            if (desc ? (a < b) : (a > b)) { SW[t] = b; SW[t ^ j] = a; }
          }
          __syncthreads();
        }
        u64 v2 = SW[t];
        bool desc = ((t & k) == 0);
#pragma unroll
        for (int j = 32; j > 0; j >>= 1) {
          u64 p = __shfl_xor(v2, j);
          bool iLower = (lane & j) == 0;
          bool keepMax = (iLower == desc);
          bool pGreater = p > v2;
          v2 = (keepMax == pGreater) ? p : v2;
        }
        SW[t] = v2;
        __syncthreads();
      }
    }
    // ---- decode rows [0,512): thread t decodes row t ----
    {
      u64 key = SW[t];
      float sc; unsigned idx;
      if (key != 0ull) {
        sc = __uint_as_float((unsigned)(key >> 32));
        idx = ~((unsigned)(key & 0xFFFFFFFFull));
      } else {
        sc = -INFINITY; idx = 0u;
      }
      float4 av = a4[idx];
      float4 rv = r4[idx];
      float w = av.z - av.x, h = av.w - av.y;
      float cx = av.x + 0.5f * w, cy = av.y + 0.5f * h;
      float dx = rv.x * 0.1f, dy = rv.y * 0.1f, dw = rv.z * 0.2f, dh = rv.w * 0.2f;
      float pcx = cx + dx * w, pcy = cy + dy * h;
      float pw = (float)exp((double)dw) * w;
      float ph = (float)exp((double)dh) * h;
      float x1 = fminf(fmaxf(pcx - 0.5f * pw, 0.0f), W);
      float y1 = fminf(fmaxf(pcy - 0.5f * ph, 0.0f), H);
      float x2 = fminf(fmaxf(pcx + 0.5f * pw, 0.0f), W);
      float y2 = fminf(fmaxf(pcy + 0.5f * ph, 0.0f), H);
      box4[t] = make_float4(x1, y1, x2, y2);
      area[t] = (x2 - x1) * (y2 - y1);
      ssc[t] = (key != 0ull) ? sc : -INFINITY;
      sidb[t] = idx;
    }
    __syncthreads();
    if (t < 64)
      nms_scan64(8, box4, area, ssc, fx, fy, fX, fY, fA, wx, wy, wX, wY, wA,
                 s_keep, s_pre, &s_total, lane);
    __syncthreads();
    done = (s_total >= (unsigned)MAXD) || (s_rows >= n);
  }

  if (!done) {
    // ---- FULL path (proven round-7 logic, strided to BT) ----
    for (int i = t; i < 1024; i += BT) M[i] = 0ull;
    h2[t] = 0u;
    if (t == 0) { s_above = 0; s_push = 0; }
    if (t < 16) { s_keep[t] = 0ull; s_pre[t] = 0u; }
    __syncthreads();

    const int scb = cbp[c];
    u64* SW = L;
    int SS = CSORT;
    bool fast = true;

    if (n > 1024) {
      for (unsigned i = t; i < n; i += BT) {
        float s = __uint_as_float((unsigned)(L[i] >> 32));
        int b = (int)(s * (float)NB);
        b = b < 0 ? 0 : (b > NB - 1 ? NB - 1 : b);
        if (b > scb) {
          atomicAdd(&s_above, 1u);
        } else {
          int sub = (int)(s * 65536.0f) - scb * 512;
          sub = sub < 0 ? 0 : (sub > 511 ? 511 : sub);
          atomicAdd(&h2[sub], 1u);
        }
      }
      __syncthreads();
      if (t == 0) {
        unsigned a = s_above;
        int r = 512;
        if (a < (unsigned)PRE) {
          for (int b2 = 511; b2 >= 0; b2--) {
            a += h2[b2];
            if (a >= (unsigned)PRE) { r = b2; break; }
          }
          if (a < (unsigned)PRE) r = 0;
        }
        s_rsub = r;
        s_n2 = a;
      }
      __syncthreads();
      if (s_n2 <= 1024u) {
        const int rsub = s_rsub;
        for (unsigned i = t; i < n; i += BT) {
          u64 key = L[i];
          float s = __uint_as_float((unsigned)(key >> 32));
          int b = (int)(s * (float)NB);
          b = b < 0 ? 0 : (b > NB - 1 ? NB - 1 : b);
          bool take;
          if (b > scb) take = true;
          else {
            int sub = (int)(s * 65536.0f) - scb * 512;
            sub = sub < 0 ? 0 : (sub > 511 ? 511 : sub);
            take = (sub >= rsub);
          }
          if (take) {
            unsigned p = atomicAdd(&s_push, 1u);
            if (p < 1024u) M[p] = key;
          }
        }
        __syncthreads();
        SW = M;
        SS = 1024;
      } else {
        fast = false;
      }
    } else {
      SW = L;
      SS = 1024;   // n <= 1024: L[n..1024) are 0
    }
    (void)fast;

    // legacy strided bitonic over SS (1024 or 4096), descending
    for (int k = 2; k <= SS; k <<= 1) {
      for (int j = k >> 1; j > 0; j >>= 1) {
        for (int i = t; i < SS; i += BT) {
          int ixj = i ^ j;
          if (ixj > i) {
            u64 va = SW[i], vb = SW[ixj];
            bool desc = ((i & k) == 0);
            if (desc ? (va < vb) : (va > vb)) { SW[i] = vb; SW[ixj] = va; }
          }
        }
        __syncthreads();
      }
    }

    // decode first 1024 rows (only t<PRE real)
    for (int i = t; i < 1024; i += BT) {
      if (i < PRE) {
        u64 key = SW[i];
        float sc; unsigned idx;
        if (key != 0ull) {
          sc = __uint_as_float((unsigned)(key >> 32));
          idx = ~((unsigned)(key & 0xFFFFFFFFull));
        } else {
          sc = -INFINITY; idx = 0u;
        }
        float4 av = a4[idx];
        float4 rv = r4[idx];
        float w = av.z - av.x, h = av.w - av.y;
        float cx = av.x + 0.5f * w, cy = av.y + 0.5f * h;
        float dx = rv.x * 0.1f, dy = rv.y * 0.1f, dw = rv.z * 0.2f, dh = rv.w * 0.2f;
        float pcx = cx + dx * w, pcy = cy + dy * h;
        float pw = (float)exp((double)dw) * w;
        float ph = (float)exp((double)dh) * h;
        float x1 = fminf(fmaxf(pcx - 0.5f * pw, 0.0f), W);
        float y1 = fminf(fmaxf(pcy - 0.5f * ph, 0.0f), H);
        float x2 = fminf(fmaxf(pcx + 0.5f * pw, 0.0f), W);
        float y2 = fminf(fmaxf(pcy + 0.5f * ph, 0.0f), H);
        box4[i] = make_float4(x1, y1, x2, y2);
        area[i] = (x2 - x1) * (y2 - y1);
        ssc[i] = sc;
        sidb[i] = idx;
      } else {
        box4[i] = make_float4(0.f, 0.f, 0.f, 0.f);
        area[i] = 0.f;
        ssc[i] = -INFINITY;
        sidb[i] = 0u;
      }
    }
    __syncthreads();
    if (t < 64)
      nms_scan64(16, box4, area, ssc, fx, fy, fX, fY, fA, wx, wy, wX, wY, wA,
                 s_keep, s_pre, &s_total, lane);
    __syncthreads();
  }

  // ---- output ----
  const unsigned total = s_total;
  for (int k = t; k < PRE; k += BT) {
    int w = k >> 6, b = k & 63;
    u64 kw = s_keep[w];
    if ((kw >> b) & 1ull) {
      unsigned rank = s_pre[w] + (unsigned)__popcll(kw & ((1ull << b) - 1ull));
      if (rank < MAXD) {
        int slot = c * MAXD + (int)rank;
        out_s[slot] = ssc[k];
        out_id[slot] = (float)c;
        ((float4*)out_b)[slot] = box4[k];
        out_d[slot] = dist[sidb[k]];
      }
    }
  }
  unsigned tk = total < (unsigned)MAXD ? total : (unsigned)MAXD;
  for (int r2 = (int)tk + t; r2 < MAXD; r2 += BT) {
    int slot = c * MAXD + r2;
    out_s[slot] = 0.0f;
    out_id[slot] = -1.0f;
    ((float4*)out_b)[slot] = make_float4(0.f, 0.f, 0.f, 0.f);
    out_d[slot] = 0.0f;
  }
}

// =====================================================================
// FALLBACK PATH (round-1, proven correct; used only if ws is too small)
// =====================================================================
#define NBUCK 4096
#define CANDF 2048

__global__ __launch_bounds__(256) void select_topk(
    const float* __restrict__ cls, int A,
    float* __restrict__ topscore, unsigned* __restrict__ topidx)
{
  const int c = blockIdx.x;
  const int t = threadIdx.x;
  __shared__ unsigned hist[NBUCK];
  __shared__ u64 cand[CANDF];
  __shared__ unsigned chunk[256];
  __shared__ int s_cb;
  __shared__ int s_cnt;
  for (int i = t; i < NBUCK; i += 256) hist[i] = 0u;
  if (t == 0) s_cnt = 0;
  __syncthreads();
  for (int a = t; a < A; a += 256) {
    float s = cls[(size_t)a * NCLS + c];
    if (s > THR_SCORE) {
      int b = (int)(s * (float)NBUCK);
      b = b < 0 ? 0 : (b > NBUCK - 1 ? NBUCK - 1 : b);
      atomicAdd(&hist[b], 1u);
    }
  }
  __syncthreads();
  {
    unsigned cs = 0;
    for (int i = 0; i < NBUCK / 256; i++) cs += hist[t * (NBUCK / 256) + i];
    chunk[t] = cs;
  }
  __syncthreads();
  if (t == 0) {
    unsigned acc = 0;
    int cb = 0;
    int ch;
    for (ch = 255; ch >= 0; ch--) {
      if (acc + chunk[ch] >= (unsigned)PRE) break;
      acc += chunk[ch];
    }
    if (ch < 0) cb = 0;
    else {
      const int bpc = NBUCK / 256;
      int b = ch * bpc + bpc - 1;
      for (; b >= ch * bpc; b--) { acc += hist[b]; if (acc >= (unsigned)PRE) break; }
      if (b < ch * bpc) b = ch * bpc;
      cb = b;
      while (acc > (unsigned)CANDF && cb < NBUCK - 1) { acc -= hist[cb]; cb++; }
    }
    s_cb = cb;
  }
  __syncthreads();
  const int cb = s_cb;
  for (int a = t; a < A; a += 256) {
    float s = cls[(size_t)a * NCLS + c];
    if (s > THR_SCORE) {
      int b = (int)(s * (float)NBUCK);
      b = b < 0 ? 0 : (b > NBUCK - 1 ? NBUCK - 1 : b);
      if (b >= cb) {
        int p = atomicAdd(&s_cnt, 1);
        if (p < CANDF)
          cand[p] = ((u64)__float_as_uint(s) << 32) | (u64)(~(unsigned)a);
      }
    }
  }
  __syncthreads();
  int n = s_cnt < CANDF ? s_cnt : CANDF;
  for (int i = n + t; i < CANDF; i += 256) cand[i] = 0ull;
  __syncthreads();
  for (int k = 2; k <= CANDF; k <<= 1) {
    for (int j = k >> 1; j > 0; j >>= 1) {
      for (int i = t; i < CANDF; i += 256) {
        int ixj = i ^ j;
        if (ixj > i) {
          u64 va = cand[i], vb = cand[ixj];
          bool desc = ((i & k) == 0);
          if (desc ? (va < vb) : (va > vb)) { cand[i] = vb; cand[ixj] = va; }
        }
      }
      __syncthreads();
    }
  }
  for (int k = t; k < PRE; k += 256) {
    u64 key = cand[k];
    float sc; unsigned idx;
    if (key != 0ull) { sc = __uint_as_float((unsigned)(key >> 32)); idx = ~((unsigned)(key & 0xFFFFFFFFull)); }
    else { sc = -INFINITY; idx = 0u; }
    topscore[c * PRE + k] = sc;
    topidx[c * PRE + k] = idx;
  }
}

__global__ __launch_bounds__(256) void nms_out(
    const float* __restrict__ anch, const float* __restrict__ reg,
    const float* __restrict__ dist,
    const float* __restrict__ topscore, const unsigned* __restrict__ topidx,
    const int* __restrict__ img_h_p, const int* __restrict__ img_w_p,
    float* __restrict__ out_s, float* __restrict__ out_id,
    float* __restrict__ out_b, float* __restrict__ out_d)
{
#pragma clang fp contract(off)
  const int c = blockIdx.x;
  const int t = threadIdx.x;
  __shared__ float bx[PRE], by[PRE], bX[PRE], bY[PRE], bar[PRE], ssc[PRE];
  __shared__ u64 supm[PRE * 16];
  __shared__ u64 keepw[16];
  __shared__ unsigned wpre[17];
  const float W = (float)img_w_p[0];
  const float H = (float)img_h_p[0];
  for (int k = t; k < PRE; k += 256) {
    float sc = topscore[c * PRE + k];
    unsigned idx = topidx[c * PRE + k];
    ssc[k] = sc;
    float a0 = anch[(size_t)idx * 4 + 0], a1 = anch[(size_t)idx * 4 + 1];
    float a2 = anch[(size_t)idx * 4 + 2], a3 = anch[(size_t)idx * 4 + 3];
    float r0 = reg[(size_t)idx * 4 + 0], r1 = reg[(size_t)idx * 4 + 1];
    float r2 = reg[(size_t)idx * 4 + 2], r3 = reg[(size_t)idx * 4 + 3];
    float w = a2 - a0, h = a3 - a1;
    float cx = a0 + 0.5f * w, cy = a1 + 0.5f * h;
    float dx = r0 * 0.1f, dy = r1 * 0.1f, dw = r2 * 0.2f, dh = r3 * 0.2f;
    float pcx = cx + dx * w, pcy = cy + dy * h;
    float pw = (float)exp((double)dw) * w;
    float ph = (float)exp((double)dh) * h;
    float x1 = fminf(fmaxf(pcx - 0.5f * pw, 0.0f), W);
    float y1 = fminf(fmaxf(pcy - 0.5f * ph, 0.0f), H);
    float x2 = fminf(fmaxf(pcx + 0.5f * pw, 0.0f), W);
    float y2 = fminf(fmaxf(pcy + 0.5f * ph, 0.0f), H);
    bx[k] = x1; by[k] = y1; bX[k] = x2; bY[k] = y2;
    bar[k] = (x2 - x1) * (y2 - y1);
  }
  __syncthreads();
  const int wave = t >> 6, lane = t & 63;
  for (int i = wave; i < PRE; i += 4) {
    float x1 = bx[i], y1 = by[i], X1 = bX[i], Y1 = bY[i], ai = bar[i];
    for (int g = 0; g < 16; g++) {
      int j = g * 64 + lane;
      bool s = false;
      if (j > i && j < PRE) {
        float ltx = fmaxf(x1, bx[j]);
        float lty = fmaxf(y1, by[j]);
        float rbx = fminf(X1, bX[j]);
        float rby = fminf(Y1, bY[j]);
        float ww = fmaxf(rbx - ltx, 0.0f);
        float hh = fmaxf(rby - lty, 0.0f);
        float inter = ww * hh;
        float iou = inter / ((ai + bar[j]) - inter + 1e-8f);
        s = iou > 0.5f;
      }
      u64 m = __ballot(s);
      if (lane == 0) supm[i * 16 + g] = m;
    }
  }
  __syncthreads();
  if (t < 64) {
    u64 kw = 0ull;
    if (t < 16) {
      for (int b = 0; b < 64; b++) {
        int k = t * 64 + b;
        if (k < PRE && ssc[k] != -INFINITY) kw |= (1ull << b);
      }
    }
    for (int i = 0; i < PRE; i++) {
      u64 ow = __shfl(kw, i >> 6);
      if ((ow >> (i & 63)) & 1ull) {
        if (t < 16) kw &= ~supm[i * 16 + t];
      }
    }
    if (t < 16) keepw[t] = kw;
  }
  __syncthreads();
  if (t == 0) {
    unsigned acc = 0;
    for (int w = 0; w < 16; w++) { wpre[w] = acc; acc += (unsigned)__popcll(keepw[w]); }
    wpre[16] = acc;
  }
  __syncthreads();
  const unsigned total = wpre[16];
  for (int k = t; k < PRE; k += 256) {
    int w = k >> 6, b = k & 63;
    u64 kw = keepw[w];
    if ((kw >> b) & 1ull) {
      unsigned rank = wpre[w] + (unsigned)__popcll(kw & ((1ull << b) - 1ull));
      if (rank < MAXD) {
        int slot = c * MAXD + (int)rank;
        out_s[slot] = ssc[k];
        out_id[slot] = (float)c;
        out_b[slot * 4 + 0] = bx[k];
        out_b[slot * 4 + 1] = by[k];
        out_b[slot * 4 + 2] = bX[k];
        out_b[slot * 4 + 3] = bY[k];
        out_d[slot] = dist[topidx[c * PRE + k]];
      }
    }
  }
  unsigned tk = total < MAXD ? total : MAXD;
  for (int r = (int)tk + t; r < MAXD; r += 256) {
    int slot = c * MAXD + r;
    out_s[slot] = 0.0f;
    out_id[slot] = -1.0f;
    out_b[slot * 4 + 0] = 0.0f; out_b[slot * 4 + 1] = 0.0f;
    out_b[slot * 4 + 2] = 0.0f; out_b[slot * 4 + 3] = 0.0f;
    out_d[slot] = 0.0f;
  }
}

// =====================================================================

static inline size_t align512(size_t x) { return (x + 511) & ~(size_t)511; }

extern "C" void kernel_launch(void* const* d_in, const int* in_sizes, int n_in,
                              void* d_out, int out_size, void* d_ws, size_t ws_size,
                              hipStream_t stream) {
  const float* cls  = (const float*)d_in[0];   // (1, A, 80)
  const float* reg  = (const float*)d_in[1];   // (1, A, 4)
  const float* dist = (const float*)d_in[2];   // (1, A, 1)
  const float* anch = (const float*)d_in[3];   // (1, A, 4)
  const int* img_h  = (const int*)d_in[4];
  const int* img_w  = (const int*)d_in[5];
  const int A = in_sizes[3] / 4;

  float* o = (float*)d_out;
  float* out_s  = o;                      // 8000
  float* out_id = o + NCLS * MAXD;        // 8000
  float* out_b  = o + 2 * NCLS * MAXD;    // 32000
  float* out_d  = o + 6 * NCLS * MAXD;    // 8000

  // big region serves sequentially: part (k1->k2), cand (k3->kAD)
  const size_t sz_part = (size_t)K1B * BINS * sizeof(unsigned short);        // 10.49 MB
  const size_t sz_cand = (size_t)NCLS * SUBS * SUBCAP * sizeof(u64);         // 5.24 MB
  size_t sz_big = sz_part > sz_cand ? sz_part : sz_cand;
  size_t off = align512(sz_big);
  const size_t o_cb    = off; off += align512(NCLS * sizeof(int));
  const size_t o_ccnt  = off; off += align512((size_t)NCLS * SUBS * sizeof(unsigned));
  const size_t needed = off;

  if (ws_size >= needed) {
    char* ws = (char*)d_ws;
    unsigned short* part = (unsigned short*)ws;
    u64* cand = (u64*)ws;
    int* cb = (int*)(ws + o_cb);
    unsigned* ccnt = (unsigned*)(ws + o_ccnt);
    const int total4 = A * 20;  // A*80/4

    k1_hist<<<K1B, 256, 0, stream>>>((const float4*)cls, total4, part);
    k2_cutoff<<<NCLS, 256, 0, stream>>>(part, cb, ccnt);
    k3_collect<<<K3B, 256, 0, stream>>>((const float4*)cls, total4, cb, ccnt, cand);
    kAD_sort_nms<<<NCLS, BT, 0, stream>>>(ccnt, cand, cb, anch, reg, dist,
                                          img_h, img_w, out_s, out_id, out_b, out_d);
  } else {
    // fallback: proven round-1 path (needs only ~0.64 MB)
    float* topscore = (float*)d_ws;
    unsigned* topidx = (unsigned*)((char*)d_ws + NCLS * PRE * sizeof(float));
    select_topk<<<NCLS, 256, 0, stream>>>(cls, A, topscore, topidx);
    nms_out<<<NCLS, 256, 0, stream>>>(anch, reg, dist, topscore, topidx,
                                      img_h, img_w, out_s, out_id, out_b, out_d);
  }
}